// Round 1
// baseline (2076.306 us; speedup 1.0000x reference)
//
#include <hip/hip_runtime.h>
#include <stdint.h>

#define D_    1024
#define BB    4
#define SDEC  1024
#define STXT  512
#define TDEC  4096
#define TTXT  2048
#define NH    16
#define DHD   64
#define NE    8
#define DFF   4096
#define NSLOT 8192

using u16 = unsigned short;
typedef __attribute__((ext_vector_type(8))) short bf16x8;
typedef __attribute__((ext_vector_type(4))) float f32x4;

__device__ __forceinline__ float bf2f(u16 h) {
    union { unsigned int u; float f; } x; x.u = ((unsigned int)h) << 16; return x.f;
}
__device__ __forceinline__ u16 f2bf(float f) {
    union { float f; unsigned int u; } x; x.f = f;
    unsigned int lsb = (x.u >> 16) & 1u;
    return (u16)((x.u + 0x7fffu + lsb) >> 16);
}

constexpr int BM = 128, BN = 128, BK = 32, LDK = 40;  // LDK padded to kill LDS bank conflicts

// ---------------------------------------------------------------------------
// Generic tiled GEMM: C[M,N] = A[M,K] * BT[N,K]^T   (both operands row-major, BT = B transposed)
// NPASS=1: plain bf16 (hi only).  NPASS=4: split emulation (AH+AL)*(BH+BL), fp32-class accuracy.
// EPI: 0 = f32 store, 1 = split store (CH=bf16(v), CL=bf16(v-CH)), 2 = relu+bf16 store.
// ---------------------------------------------------------------------------
template<int NPASS, int EPI>
__global__ __launch_bounds__(256, 2) void gemm_bt(
    const u16* __restrict__ AH, const u16* __restrict__ AL,
    const u16* __restrict__ BH, const u16* __restrict__ BL,
    float* __restrict__ Cf, u16* __restrict__ CH, u16* __restrict__ CL,
    int M, int N, int K, int lda, int ldb, int ldc,
    long strA, long strB, long strC)
{
    constexpr int NTILE = (NPASS > 1) ? 4 : 2;
    __shared__ u16 smem[NTILE * BM * LDK];
    u16* sAH = smem;
    u16* sBH = smem + BM * LDK;
    u16* sAL = smem + 2 * BM * LDK;
    u16* sBL = smem + 3 * BM * LDK;

    const int z = blockIdx.z;
    const long aoff = (long)z * strA, boff = (long)z * strB, coff = (long)z * strC;

    const int tileM = blockIdx.y * BM, tileN = blockIdx.x * BN;
    const int t = threadIdx.x;
    const int srow = t >> 1, scol = (t & 1) << 4;
    const int gra = tileM + srow, grb = tileN + srow;
    const bool va = gra < M, vb = grb < N;
    const u16* pA  = AH + aoff + (long)gra * lda + scol;
    const u16* pB  = BH + boff + (long)grb * ldb + scol;
    const u16* pAl = nullptr; const u16* pBl = nullptr;
    if constexpr (NPASS > 1) {
        pAl = AL + aoff + (long)gra * lda + scol;
        pBl = BL + boff + (long)grb * ldb + scol;
    }

    const int lane = t & 63;
    const int wv = t >> 6;
    const int wr = (wv >> 1) << 6, wc = (wv & 1) << 6;
    const int fr = lane & 15, kg = lane >> 4;

    f32x4 acc[4][4];
    const f32x4 vzero = {0.f, 0.f, 0.f, 0.f};
#pragma unroll
    for (int m = 0; m < 4; ++m)
#pragma unroll
        for (int n = 0; n < 4; ++n) acc[m][n] = vzero;

    const uint4 uz = make_uint4(0u, 0u, 0u, 0u);
    for (int k0 = 0; k0 < K; k0 += BK) {
        uint4 a0 = va ? *(const uint4*)(pA + k0)     : uz;
        uint4 a1 = va ? *(const uint4*)(pA + k0 + 8) : uz;
        uint4 b0 = vb ? *(const uint4*)(pB + k0)     : uz;
        uint4 b1 = vb ? *(const uint4*)(pB + k0 + 8) : uz;
        uint4 c0 = uz, c1 = uz, d0 = uz, d1 = uz;
        if constexpr (NPASS > 1) {
            c0 = va ? *(const uint4*)(pAl + k0)     : uz;
            c1 = va ? *(const uint4*)(pAl + k0 + 8) : uz;
            d0 = vb ? *(const uint4*)(pBl + k0)     : uz;
            d1 = vb ? *(const uint4*)(pBl + k0 + 8) : uz;
        }
        *(uint4*)&sAH[srow * LDK + scol]     = a0;
        *(uint4*)&sAH[srow * LDK + scol + 8] = a1;
        *(uint4*)&sBH[srow * LDK + scol]     = b0;
        *(uint4*)&sBH[srow * LDK + scol + 8] = b1;
        if constexpr (NPASS > 1) {
            *(uint4*)&sAL[srow * LDK + scol]     = c0;
            *(uint4*)&sAL[srow * LDK + scol + 8] = c1;
            *(uint4*)&sBL[srow * LDK + scol]     = d0;
            *(uint4*)&sBL[srow * LDK + scol + 8] = d1;
        }
        __syncthreads();

        bf16x8 fa[4], fb[4], fal[4], fbl[4];
#pragma unroll
        for (int m = 0; m < 4; ++m) {
            fa[m] = *(const bf16x8*)&sAH[(wr + m * 16 + fr) * LDK + (kg << 3)];
            fb[m] = *(const bf16x8*)&sBH[(wc + m * 16 + fr) * LDK + (kg << 3)];
            if constexpr (NPASS > 1) {
                fal[m] = *(const bf16x8*)&sAL[(wr + m * 16 + fr) * LDK + (kg << 3)];
                fbl[m] = *(const bf16x8*)&sBL[(wc + m * 16 + fr) * LDK + (kg << 3)];
            }
        }
#pragma unroll
        for (int m = 0; m < 4; ++m)
#pragma unroll
            for (int n = 0; n < 4; ++n) {
                acc[m][n] = __builtin_amdgcn_mfma_f32_16x16x32_bf16(fa[m], fb[n], acc[m][n], 0, 0, 0);
                if constexpr (NPASS > 1) {
                    acc[m][n] = __builtin_amdgcn_mfma_f32_16x16x32_bf16(fa[m],  fbl[n], acc[m][n], 0, 0, 0);
                    acc[m][n] = __builtin_amdgcn_mfma_f32_16x16x32_bf16(fal[m], fb[n],  acc[m][n], 0, 0, 0);
                }
                if constexpr (NPASS > 3) {
                    acc[m][n] = __builtin_amdgcn_mfma_f32_16x16x32_bf16(fal[m], fbl[n], acc[m][n], 0, 0, 0);
                }
            }
        __syncthreads();
    }

#pragma unroll
    for (int m = 0; m < 4; ++m) {
        const int r0 = tileM + wr + m * 16 + (kg << 2);
#pragma unroll
        for (int n = 0; n < 4; ++n) {
            const int col = tileN + wc + n * 16 + fr;
            if (col >= N) continue;
#pragma unroll
            for (int i = 0; i < 4; ++i) {
                const int r = r0 + i;
                if (r >= M) continue;
                const float v = acc[m][n][i];
                const long off = coff + (long)r * ldc + col;
                if constexpr (EPI == 0) {
                    Cf[off] = v;
                } else if constexpr (EPI == 1) {
                    const u16 h = f2bf(v);
                    CH[off] = h;
                    CL[off] = f2bf(v - bf2f(h));
                } else {
                    CH[off] = f2bf(fmaxf(v, 0.f));
                }
            }
        }
    }
}

// ---------------------------------------------------------------------------
// MoE segmented GEMM: rows are global slot rows within [seg[e], seg[e+1]); B is per-expert.
// lda == K for A, ldb == K for BT (contiguous buffers).  1-pass bf16.
// ---------------------------------------------------------------------------
template<int EPI>
__global__ __launch_bounds__(256, 2) void gemm_moe(
    const u16* __restrict__ Ag, const u16* __restrict__ BTbase,
    float* __restrict__ Cf, u16* __restrict__ CH,
    int N, int K, int ldc, const int* __restrict__ seg, long btStride)
{
    __shared__ u16 smem[2 * BM * LDK];
    u16* sA = smem;
    u16* sB = smem + BM * LDK;

    const int e = blockIdx.z;
    const int s0 = seg[e], s1 = seg[e + 1];
    const int rowbase = s0 + blockIdx.y * BM;
    if (rowbase >= s1) return;
    const u16* BT = BTbase + (long)e * btStride;

    const int tileN = blockIdx.x * BN;
    const int t = threadIdx.x;
    const int srow = t >> 1, scol = (t & 1) << 4;
    const int gra = rowbase + srow;
    const bool va = gra < s1;
    const int grb = tileN + srow;
    const u16* pA = Ag + (long)gra * K + scol;
    const u16* pB = BT + (long)grb * K + scol;

    const int lane = t & 63;
    const int wv = t >> 6;
    const int wr = (wv >> 1) << 6, wc = (wv & 1) << 6;
    const int fr = lane & 15, kg = lane >> 4;

    f32x4 acc[4][4];
    const f32x4 vzero = {0.f, 0.f, 0.f, 0.f};
#pragma unroll
    for (int m = 0; m < 4; ++m)
#pragma unroll
        for (int n = 0; n < 4; ++n) acc[m][n] = vzero;

    const uint4 uz = make_uint4(0u, 0u, 0u, 0u);
    for (int k0 = 0; k0 < K; k0 += BK) {
        uint4 a0 = va ? *(const uint4*)(pA + k0)     : uz;
        uint4 a1 = va ? *(const uint4*)(pA + k0 + 8) : uz;
        uint4 b0 = *(const uint4*)(pB + k0);
        uint4 b1 = *(const uint4*)(pB + k0 + 8);
        *(uint4*)&sA[srow * LDK + scol]     = a0;
        *(uint4*)&sA[srow * LDK + scol + 8] = a1;
        *(uint4*)&sB[srow * LDK + scol]     = b0;
        *(uint4*)&sB[srow * LDK + scol + 8] = b1;
        __syncthreads();
        bf16x8 fa[4], fb[4];
#pragma unroll
        for (int m = 0; m < 4; ++m) {
            fa[m] = *(const bf16x8*)&sA[(wr + m * 16 + fr) * LDK + (kg << 3)];
            fb[m] = *(const bf16x8*)&sB[(wc + m * 16 + fr) * LDK + (kg << 3)];
        }
#pragma unroll
        for (int m = 0; m < 4; ++m)
#pragma unroll
            for (int n = 0; n < 4; ++n)
                acc[m][n] = __builtin_amdgcn_mfma_f32_16x16x32_bf16(fa[m], fb[n], acc[m][n], 0, 0, 0);
        __syncthreads();
    }

#pragma unroll
    for (int m = 0; m < 4; ++m) {
        const int r0 = rowbase + wr + m * 16 + (kg << 2);
#pragma unroll
        for (int n = 0; n < 4; ++n) {
            const int col = tileN + wc + n * 16 + fr;
            if (col >= N) continue;
#pragma unroll
            for (int i = 0; i < 4; ++i) {
                const int r = r0 + i;
                if (r >= s1) continue;
                const float v = acc[m][n][i];
                const long off = (long)r * ldc + col;
                if constexpr (EPI == 0) Cf[off] = v;
                else                    CH[off] = f2bf(fmaxf(v, 0.f));
            }
        }
    }
}

// ---------------------------------------------------------------------------
// f32 -> bf16 hi(/lo) elementwise split. n multiple of 4.
// ---------------------------------------------------------------------------
__global__ __launch_bounds__(256) void split2k(const float* __restrict__ in,
                                               u16* __restrict__ oh, u16* __restrict__ ol, long n)
{
    long i = ((long)blockIdx.x * 256 + threadIdx.x) * 4;
    if (i >= n) return;
    float4 v = *(const float4*)(in + i);
    u16 h0 = f2bf(v.x), h1 = f2bf(v.y), h2 = f2bf(v.z), h3 = f2bf(v.w);
    uint2 oo;
    oo.x = (unsigned)h0 | ((unsigned)h1 << 16);
    oo.y = (unsigned)h2 | ((unsigned)h3 << 16);
    *(uint2*)(oh + i) = oo;
    if (ol) {
        u16 l0 = f2bf(v.x - bf2f(h0)), l1 = f2bf(v.y - bf2f(h1));
        u16 l2 = f2bf(v.z - bf2f(h2)), l3 = f2bf(v.w - bf2f(h3));
        uint2 ll;
        ll.x = (unsigned)l0 | ((unsigned)l1 << 16);
        ll.y = (unsigned)l2 | ((unsigned)l3 << 16);
        *(uint2*)(ol + i) = ll;
    }
}

// ---------------------------------------------------------------------------
// Transpose + split: in[R,C] (ld=ild) per batch z (offset = (z/nb2)*ibs1 + (z%nb2)*ibs2)
//  -> oh/ol [C,R] (ld=old) at z*obs.
// ---------------------------------------------------------------------------
__global__ __launch_bounds__(256) void transpose_split(
    const float* __restrict__ in, u16* __restrict__ oh, u16* __restrict__ ol,
    int R, int C, int ild, long ibs1, long ibs2, int nb2, int old_, long obs)
{
    __shared__ float tile[32][33];
    const int z = blockIdx.z;
    const float* ip = in + (long)(z / nb2) * ibs1 + (long)(z % nb2) * ibs2;
    u16* ohp = oh + (long)z * obs;
    u16* olp = ol ? ol + (long)z * obs : nullptr;
    const int c0 = blockIdx.x * 32, r0 = blockIdx.y * 32;
    const int tx = threadIdx.x & 31, ty = threadIdx.x >> 5;
    for (int i = ty; i < 32; i += 8) {
        int r = r0 + i, c = c0 + tx;
        tile[i][tx] = (r < R && c < C) ? ip[(long)r * ild + c] : 0.f;
    }
    __syncthreads();
    for (int i = ty; i < 32; i += 8) {
        int oc = c0 + i, orr = r0 + tx;
        if (oc < C && orr < R) {
            float v = tile[tx][i];
            u16 h = f2bf(v);
            ohp[(long)oc * old_ + orr] = h;
            if (olp) olp[(long)oc * old_ + orr] = f2bf(v - bf2f(h));
        }
    }
}

// ---------------------------------------------------------------------------
// Row softmax with pre-scale, in place. One block per row. cols in {512,1024}.
// ---------------------------------------------------------------------------
__global__ __launch_bounds__(256) void softmax_rows(float* __restrict__ s, int cols, float scale)
{
    float* p = s + (long)blockIdx.x * cols;
    const int t = threadIdx.x;
    const int vpt = cols >> 8;
    float v[4];
    float mx = -3.4e38f;
    for (int i = 0; i < vpt; ++i) { v[i] = p[t + (i << 8)] * scale; mx = fmaxf(mx, v[i]); }
#pragma unroll
    for (int o = 32; o; o >>= 1) mx = fmaxf(mx, __shfl_xor(mx, o));
    __shared__ float sm[4];
    const int wv = t >> 6, ln = t & 63;
    if (ln == 0) sm[wv] = mx;
    __syncthreads();
    mx = fmaxf(fmaxf(sm[0], sm[1]), fmaxf(sm[2], sm[3]));
    float sum = 0.f;
    for (int i = 0; i < vpt; ++i) { v[i] = expf(v[i] - mx); sum += v[i]; }
#pragma unroll
    for (int o = 32; o; o >>= 1) sum += __shfl_xor(sum, o);
    __shared__ float ss[4];
    if (ln == 0) ss[wv] = sum;
    __syncthreads();
    sum = ss[0] + ss[1] + ss[2] + ss[3];
    const float inv = 1.f / sum;
    for (int i = 0; i < vpt; ++i) p[t + (i << 8)] = v[i] * inv;
}

// ---------------------------------------------------------------------------
// x = rmsnorm(a + b, g); optional bf16 hi/lo split of x. One block per row (d=1024).
// ---------------------------------------------------------------------------
__global__ __launch_bounds__(256) void add_rmsnorm(
    const float* __restrict__ a, const float* __restrict__ b, const float* __restrict__ g,
    float* __restrict__ xo, u16* __restrict__ xh, u16* __restrict__ xl)
{
    const long row = blockIdx.x;
    const int t = threadIdx.x;
    const float* pa = a + row * D_;
    const float* pb = b + row * D_;
    float v[4]; double ssq = 0.0;
#pragma unroll
    for (int i = 0; i < 4; ++i) {
        int c = t + (i << 8);
        v[i] = pa[c] + pb[c];
        ssq += (double)v[i] * v[i];
    }
#pragma unroll
    for (int o = 32; o; o >>= 1) ssq += __shfl_xor(ssq, o);
    __shared__ double sd[4];
    if ((t & 63) == 0) sd[t >> 6] = ssq;
    __syncthreads();
    ssq = sd[0] + sd[1] + sd[2] + sd[3];
    const float rs = (float)(1.0 / sqrt(ssq * (1.0 / 1024.0) + 1e-6));
#pragma unroll
    for (int i = 0; i < 4; ++i) {
        int c = t + (i << 8);
        float o = v[i] * rs * g[c];
        xo[row * D_ + c] = o;
        if (xh) {
            u16 h = f2bf(o);
            xh[row * D_ + c] = h;
            if (xl) xl[row * D_ + c] = f2bf(o - bf2f(h));
        }
    }
}

// ---------------------------------------------------------------------------
// Router: one 64-lane wave per token. fp32 logits from fp32 x2; exact top-2 tie-break
// (lowest index wins, matching jax.lax.top_k).
// ---------------------------------------------------------------------------
__global__ __launch_bounds__(256) void router_topk(
    const float* __restrict__ x2, const float* __restrict__ Wg,
    float* __restrict__ outw, float* __restrict__ outi,
    int* __restrict__ idx, float* __restrict__ tokw, int* __restrict__ counts, int T)
{
    const int wid = (int)((blockIdx.x * 256 + threadIdx.x) >> 6);
    const int lane = threadIdx.x & 63;
    if (wid >= T) return;
    float acc[NE];
#pragma unroll
    for (int e = 0; e < NE; ++e) acc[e] = 0.f;
    const float* xr = x2 + (long)wid * D_;
    for (int i = 0; i < 16; ++i) {
        float xv = xr[i * 64 + lane];
        const float* wr = Wg + (long)(i * 64 + lane) * NE;
#pragma unroll
        for (int e = 0; e < NE; ++e) acc[e] += xv * wr[e];
    }
#pragma unroll
    for (int e = 0; e < NE; ++e)
#pragma unroll
        for (int o = 32; o; o >>= 1) acc[e] += __shfl_xor(acc[e], o);
    if (lane == 0) {
        float m = acc[0];
#pragma unroll
        for (int e = 1; e < NE; ++e) m = fmaxf(m, acc[e]);
        float p[NE], s = 0.f;
#pragma unroll
        for (int e = 0; e < NE; ++e) { p[e] = expf(acc[e] - m); s += p[e]; }
        const float invs = 1.f / s;
#pragma unroll
        for (int e = 0; e < NE; ++e) p[e] *= invs;
        int e0 = 0;
#pragma unroll
        for (int e = 1; e < NE; ++e) if (p[e] > p[e0]) e0 = e;
        int e1 = (e0 == 0) ? 1 : 0;
#pragma unroll
        for (int e = 0; e < NE; ++e) if (e != e0 && e != e1 && p[e] > p[e1]) e1 = e;
        float w0 = p[e0], w1 = p[e1];
        const float sw = 1.f / (w0 + w1);
        w0 *= sw; w1 *= sw;
        outw[2 * wid] = w0;      outw[2 * wid + 1] = w1;
        outi[2 * wid] = (float)e0; outi[2 * wid + 1] = (float)e1;
        idx[2 * wid] = e0;       idx[2 * wid + 1] = e1;
        tokw[2 * wid] = w0;      tokw[2 * wid + 1] = w1;
        atomicAdd(&counts[e0], 1);
        atomicAdd(&counts[e1], 1);
    }
}

__global__ void scan8(const int* __restrict__ counts, int* __restrict__ seg, int* __restrict__ cursor)
{
    if (threadIdx.x == 0 && blockIdx.x == 0) {
        int a = 0;
        for (int e = 0; e < NE; ++e) { seg[e] = a; cursor[e] = a; a += counts[e]; }
        seg[NE] = a;
    }
}

__global__ __launch_bounds__(256) void scatter_slots(
    const int* __restrict__ idx, int* __restrict__ cursor,
    int* __restrict__ row_token, int* __restrict__ slot_of, int T)
{
    const int t = blockIdx.x * 256 + threadIdx.x;
    if (t >= T) return;
#pragma unroll
    for (int k = 0; k < 2; ++k) {
        const int e = idx[2 * t + k];
        const int pos = atomicAdd(&cursor[e], 1);
        row_token[pos] = t;
        slot_of[2 * t + k] = pos;
    }
}

__global__ __launch_bounds__(256) void gather_bf16(
    const float* __restrict__ x2, const int* __restrict__ row_token, u16* __restrict__ Xg)
{
    const int r = blockIdx.x;
    const int t = threadIdx.x;
    const float* src = x2 + (long)row_token[r] * D_ + t * 4;
    float4 v = *(const float4*)src;
    uint2 oo;
    oo.x = (unsigned)f2bf(v.x) | ((unsigned)f2bf(v.y) << 16);
    oo.y = (unsigned)f2bf(v.z) | ((unsigned)f2bf(v.w) << 16);
    *(uint2*)(Xg + (long)r * D_ + t * 4) = oo;
}

// ---------------------------------------------------------------------------
// Final: x = rmsnorm(w0*Y[s0] + w1*Y[s1] + x2, g) -> out
// ---------------------------------------------------------------------------
__global__ __launch_bounds__(256) void combine_rmsnorm(
    const float* __restrict__ Y, const int* __restrict__ slot_of, const float* __restrict__ tokw,
    const float* __restrict__ x2, const float* __restrict__ g, float* __restrict__ out)
{
    const long tr = blockIdx.x;
    const int t = threadIdx.x;
    const int s0 = slot_of[2 * tr], s1 = slot_of[2 * tr + 1];
    const float w0 = tokw[2 * tr], w1 = tokw[2 * tr + 1];
    const float* y0 = Y + (long)s0 * D_;
    const float* y1 = Y + (long)s1 * D_;
    const float* xr = x2 + tr * D_;
    float v[4]; double ssq = 0.0;
#pragma unroll
    for (int i = 0; i < 4; ++i) {
        int c = t + (i << 8);
        v[i] = w0 * y0[c] + w1 * y1[c] + xr[c];
        ssq += (double)v[i] * v[i];
    }
#pragma unroll
    for (int o = 32; o; o >>= 1) ssq += __shfl_xor(ssq, o);
    __shared__ double sd[4];
    if ((t & 63) == 0) sd[t >> 6] = ssq;
    __syncthreads();
    ssq = sd[0] + sd[1] + sd[2] + sd[3];
    const float rs = (float)(1.0 / sqrt(ssq * (1.0 / 1024.0) + 1e-6));
#pragma unroll
    for (int i = 0; i < 4; ++i) {
        int c = t + (i << 8);
        out[tr * D_ + c] = v[i] * rs * g[c];
    }
}

__global__ void sentinel(float* o) { o[0] = 12345.0f; }

// ---------------------------------------------------------------------------
extern "C" void kernel_launch(void* const* d_in, const int* in_sizes, int n_in,
                              void* d_out, int out_size, void* d_ws, size_t ws_size,
                              hipStream_t stream)
{
    const float* dec = (const float*)d_in[0];
    const float* te  = (const float*)d_in[1];
    const float* Win[8] = { (const float*)d_in[2], (const float*)d_in[3], (const float*)d_in[4],
                            (const float*)d_in[5], (const float*)d_in[6], (const float*)d_in[7],
                            (const float*)d_in[8], (const float*)d_in[9] };
    const float* g  = (const float*)d_in[10];
    const float* Wg = (const float*)d_in[11];
    const float* W1 = (const float*)d_in[12];
    const float* W2 = (const float*)d_in[13];
    float* outw = (float*)d_out;                 // [T,2] router weights
    float* outi = outw + 2 * TDEC;               // [T,2] indices as float
    float* outx = outw + 4 * TDEC;               // [T,1024]

    char* ws = (char*)d_ws;
    size_t off = 0;
    auto A = [&](size_t bytes) -> char* {
        char* p = ws + off;
        off += (bytes + 255) & ~(size_t)255;
        return p;
    };

    // ---- persistent region ----
    u16* decH = (u16*)A((size_t)TDEC * D_ * 2);
    u16* decL = (u16*)A((size_t)TDEC * D_ * 2);
    u16* teH  = (u16*)A((size_t)TTXT * D_ * 2);
    u16* teL  = (u16*)A((size_t)TTXT * D_ * 2);
    u16 *wtH[8], *wtL[8];
    for (int i = 0; i < 8; ++i) {
        wtH[i] = (u16*)A((size_t)D_ * D_ * 2);
        wtL[i] = (u16*)A((size_t)D_ * D_ * 2);
    }
    float* x1f = (float*)A((size_t)TDEC * D_ * 4);
    float* x2f = (float*)A((size_t)TDEC * D_ * 4);
    float* tokw = (float*)A(NSLOT * 4);
    int* idx    = (int*)A(NSLOT * 4);
    int* counts = (int*)A(256);
    int* seg    = (int*)A(256);
    int* cursor = (int*)A(256);
    int* row_token = (int*)A(NSLOT * 4);
    int* slot_of   = (int*)A(NSLOT * 4);

    // ---- shared region R: attention view ----
    const size_t Rbase = off;
    float* scores = (float*)A((size_t)NH * SDEC * SDEC * 4);
    u16* PH = (u16*)A((size_t)NH * SDEC * SDEC * 2);
    u16* PL = (u16*)A((size_t)NH * SDEC * SDEC * 2);
    u16* qH  = (u16*)A((size_t)TDEC * D_ * 2);
    u16* qL  = (u16*)A((size_t)TDEC * D_ * 2);
    u16* kH  = (u16*)A((size_t)TDEC * D_ * 2);
    u16* kL  = (u16*)A((size_t)TDEC * D_ * 2);
    u16* vTH = (u16*)A((size_t)TDEC * D_ * 2);
    u16* vTL = (u16*)A((size_t)TDEC * D_ * 2);
    u16* aoH = (u16*)A((size_t)TDEC * D_ * 2);
    u16* aoL = (u16*)A((size_t)TDEC * D_ * 2);
    float* vf = (float*)A((size_t)TDEC * D_ * 4);
    u16* x1H = (u16*)A((size_t)TDEC * D_ * 2);
    u16* x1L = (u16*)A((size_t)TDEC * D_ * 2);
    float* of = (float*)A((size_t)TDEC * D_ * 4);
    const size_t attnEnd = off;

    // ---- shared region R: MoE view (overlays attention view; used strictly later) ----
    off = Rbase;
    u16* W1T  = (u16*)A((size_t)NE * DFF * D_ * 2);
    u16* W2T  = (u16*)A((size_t)NE * D_ * DFF * 2);
    u16* Xg   = (u16*)A((size_t)NSLOT * D_ * 2);
    u16* Hb   = (u16*)A((size_t)NSLOT * DFF * 2);
    float* Yseg = (float*)A((size_t)NSLOT * D_ * 4);
    const size_t needed = (off > attnEnd ? off : attnEnd);

    if (ws_size < needed) {  // distinctive failure signature instead of corruption
        sentinel<<<1, 1, 0, stream>>>(outw);
        return;
    }

    const dim3 blk(256);
    auto g3 = [](int n, int m, int z) { return dim3((n + BN - 1) / BN, (m + BM - 1) / BM, z); };

    // ---- phase 0: input splits + attention weight transposes ----
    split2k<<<dim3((TDEC * D_) / 1024), blk, 0, stream>>>(dec, decH, decL, (long)TDEC * D_);
    split2k<<<dim3((TTXT * D_) / 1024), blk, 0, stream>>>(te, teH, teL, (long)TTXT * D_);
    for (int i = 0; i < 8; ++i)
        transpose_split<<<dim3(32, 32, 1), blk, 0, stream>>>(Win[i], wtH[i], wtL[i],
                                                             D_, D_, D_, 0, 0, 1, D_, 0);

    // ---- phase 1: self-attention ----
    gemm_bt<4, 1><<<g3(D_, TDEC, 1), blk, 0, stream>>>(decH, decL, wtH[0], wtL[0],
        nullptr, qH, qL, TDEC, D_, D_, D_, D_, D_, 0, 0, 0);
    gemm_bt<4, 1><<<g3(D_, TDEC, 1), blk, 0, stream>>>(decH, decL, wtH[1], wtL[1],
        nullptr, kH, kL, TDEC, D_, D_, D_, D_, D_, 0, 0, 0);
    gemm_bt<4, 0><<<g3(D_, TDEC, 1), blk, 0, stream>>>(decH, decL, wtH[2], wtL[2],
        vf, nullptr, nullptr, TDEC, D_, D_, D_, D_, D_, 0, 0, 0);
    transpose_split<<<dim3(2, 32, BB * NH), blk, 0, stream>>>(vf, vTH, vTL,
        SDEC, DHD, D_, (long)SDEC * D_, DHD, NH, SDEC, (long)DHD * SDEC);

    for (int b = 0; b < BB; ++b) {
        const long qo = (long)b * SDEC * D_;
        gemm_bt<4, 0><<<g3(SDEC, SDEC, NH), blk, 0, stream>>>(qH + qo, qL + qo, kH + qo, kL + qo,
            scores, nullptr, nullptr, SDEC, SDEC, DHD, D_, D_, SDEC,
            DHD, DHD, (long)SDEC * SDEC);
        softmax_rows<<<dim3(NH * SDEC), blk, 0, stream>>>(scores, SDEC, 0.125f);
        split2k<<<dim3((NH * SDEC * SDEC) / 1024), blk, 0, stream>>>(scores, PH, PL,
            (long)NH * SDEC * SDEC);
        gemm_bt<4, 1><<<g3(DHD, SDEC, NH), blk, 0, stream>>>(PH, PL,
            vTH + (long)b * NH * DHD * SDEC, vTL + (long)b * NH * DHD * SDEC,
            nullptr, aoH + qo, aoL + qo, SDEC, DHD, SDEC, SDEC, SDEC, D_,
            (long)SDEC * SDEC, (long)DHD * SDEC, DHD);
    }
    gemm_bt<4, 0><<<g3(D_, TDEC, 1), blk, 0, stream>>>(aoH, aoL, wtH[3], wtL[3],
        of, nullptr, nullptr, TDEC, D_, D_, D_, D_, D_, 0, 0, 0);
    add_rmsnorm<<<dim3(TDEC), blk, 0, stream>>>(of, dec, g, x1f, x1H, x1L);

    // ---- phase 2: cross-attention ----
    gemm_bt<4, 1><<<g3(D_, TDEC, 1), blk, 0, stream>>>(x1H, x1L, wtH[4], wtL[4],
        nullptr, qH, qL, TDEC, D_, D_, D_, D_, D_, 0, 0, 0);
    gemm_bt<4, 1><<<g3(D_, TTXT, 1), blk, 0, stream>>>(teH, teL, wtH[5], wtL[5],
        nullptr, kH, kL, TTXT, D_, D_, D_, D_, D_, 0, 0, 0);
    gemm_bt<4, 0><<<g3(D_, TTXT, 1), blk, 0, stream>>>(teH, teL, wtH[6], wtL[6],
        vf, nullptr, nullptr, TTXT, D_, D_, D_, D_, D_, 0, 0, 0);
    transpose_split<<<dim3(2, 16, BB * NH), blk, 0, stream>>>(vf, vTH, vTL,
        STXT, DHD, D_, (long)STXT * D_, DHD, NH, STXT, (long)DHD * STXT);

    for (int b = 0; b < BB; ++b) {
        const long qo = (long)b * SDEC * D_;
        const long ko = (long)b * STXT * D_;
        gemm_bt<4, 0><<<g3(STXT, SDEC, NH), blk, 0, stream>>>(qH + qo, qL + qo, kH + ko, kL + ko,
            scores, nullptr, nullptr, SDEC, STXT, DHD, D_, D_, STXT,
            DHD, DHD, (long)SDEC * STXT);
        softmax_rows<<<dim3(NH * SDEC), blk, 0, stream>>>(scores, STXT, 0.125f);
        split2k<<<dim3((NH * SDEC * STXT) / 1024), blk, 0, stream>>>(scores, PH, PL,
            (long)NH * SDEC * STXT);
        gemm_bt<4, 1><<<g3(DHD, SDEC, NH), blk, 0, stream>>>(PH, PL,
            vTH + (long)b * NH * DHD * STXT, vTL + (long)b * NH * DHD * STXT,
            nullptr, aoH + qo, aoL + qo, SDEC, DHD, STXT, STXT, STXT, D_,
            (long)SDEC * STXT, (long)DHD * STXT, DHD);
    }
    gemm_bt<4, 0><<<g3(D_, TDEC, 1), blk, 0, stream>>>(aoH, aoL, wtH[7], wtL[7],
        of, nullptr, nullptr, TDEC, D_, D_, D_, D_, D_, 0, 0, 0);
    add_rmsnorm<<<dim3(TDEC), blk, 0, stream>>>(of, x1f, g, x2f, nullptr, nullptr);

    // ---- phase 3: router + expert bucketing ----
    hipMemsetAsync(counts, 0, 32, stream);
    router_topk<<<dim3(TDEC / 4), blk, 0, stream>>>(x2f, Wg, outw, outi, idx, tokw, counts, TDEC);
    scan8<<<1, 64, 0, stream>>>(counts, seg, cursor);
    scatter_slots<<<dim3(TDEC / 256), blk, 0, stream>>>(idx, cursor, row_token, slot_of, TDEC);
    gather_bf16<<<dim3(NSLOT), blk, 0, stream>>>(x2f, row_token, Xg);

    // ---- phase 4: MoE FFN (bf16) + final norm ----
    transpose_split<<<dim3(DFF / 32, D_ / 32, NE), blk, 0, stream>>>(W1, W1T, nullptr,
        D_, DFF, DFF, (long)D_ * DFF, 0, 1, D_, (long)DFF * D_);
    transpose_split<<<dim3(D_ / 32, DFF / 32, NE), blk, 0, stream>>>(W2, W2T, nullptr,
        DFF, D_, D_, (long)D_ * DFF, 0, 1, DFF, (long)D_ * DFF);
    gemm_moe<2><<<dim3(DFF / BN, NSLOT / BM, NE), blk, 0, stream>>>(Xg, W1T,
        nullptr, Hb, DFF, D_, DFF, seg, (long)DFF * D_);
    gemm_moe<0><<<dim3(D_ / BN, NSLOT / BM, NE), blk, 0, stream>>>(Hb, W2T,
        Yseg, nullptr, D_, DFF, D_, seg, (long)D_ * DFF);
    combine_rmsnorm<<<dim3(TDEC), blk, 0, stream>>>(Yseg, slot_of, tokw, x2f, g, outx);

    (void)in_sizes; (void)n_in; (void)out_size;
}

// Round 2
// 1710.193 us; speedup vs baseline: 1.2141x; 1.2141x over previous
//
#include <hip/hip_runtime.h>
#include <stdint.h>

#define D_    1024
#define BB    4
#define SDEC  1024
#define STXT  512
#define TDEC  4096
#define TTXT  2048
#define NH    16
#define DHD   64
#define NE    8
#define DFF   4096
#define NSLOT 8192

using u16 = unsigned short;
typedef __attribute__((ext_vector_type(8))) short bf16x8;
typedef __attribute__((ext_vector_type(4))) float f32x4;

__device__ __forceinline__ float bf2f(u16 h) {
    union { unsigned int u; float f; } x; x.u = ((unsigned int)h) << 16; return x.f;
}
__device__ __forceinline__ u16 f2bf(float f) {
    union { float f; unsigned int u; } x; x.f = f;
    unsigned int lsb = (x.u >> 16) & 1u;
    return (u16)((x.u + 0x7fffu + lsb) >> 16);
}

// async global->LDS, 16B per lane, linear LDS dest (wave-uniform base + lane*16)
__device__ __forceinline__ void gld16(const u16* g, u16* l) {
    __builtin_amdgcn_global_load_lds((const __attribute__((address_space(1))) void*)g,
                                     (__attribute__((address_space(3))) void*)l,
                                     16, 0, 0);
}

constexpr int BM = 128, BN = 128, BK = 32;

// ---------------------------------------------------------------------------
// Generic tiled GEMM: C[M,N] = A[M,K] * BT[N,K]^T  (row-major, BT = B transposed).
// SPLIT=0: plain bf16.  SPLIT=1: 3-pass split emulation (AH*BH + AH*BL + AL*BH).
// EPI: 0 = f32 store, 1 = split store (CH=bf16(v), CL=bf16(v-CH)), 2 = relu+bf16.
// Requirements: M,N tiles may overrun rows in GLOBAL memory by <=64 rows on the
// B panel when N<128 — caller pads allocations. K % 32 == 0. M % 128 == 0 for A.
// ---------------------------------------------------------------------------
template<int SPLIT, int EPI>
__global__ __launch_bounds__(256) void gemm_bt(
    const u16* __restrict__ AH, const u16* __restrict__ AL,
    const u16* __restrict__ BH, const u16* __restrict__ BL,
    float* __restrict__ Cf, u16* __restrict__ CH, u16* __restrict__ CL,
    int M, int N, int K, int lda, int ldb, int ldc,
    long strA, long strB, long strC)
{
    constexpr int NT = SPLIT ? 4 : 2;
    __shared__ u16 smem[NT * BM * BK];
    u16* sAH = smem;
    u16* sBH = smem + BM * BK;

    const int z = blockIdx.z;
    const long zA = (long)z * strA, zB = (long)z * strB, zC = (long)z * strC;

    const int tileM = blockIdx.y * BM, tileN = blockIdx.x * BN;
    const int t = threadIdx.x;
    const int sr = t >> 2;          // staging row 0..63
    const int sc = (t & 3) << 3;    // staging col chunk (elements)
    const u16* pA = AH + zA + (long)(tileM + sr) * lda + sc;
    const u16* pB = BH + zB + (long)(tileN + sr) * ldb + sc;
    const u16* pAl = nullptr; const u16* pBl = nullptr;
    u16* sAL = nullptr; u16* sBL = nullptr;
    if constexpr (SPLIT) {
        pAl = AL + zA + (long)(tileM + sr) * lda + sc;
        pBl = BL + zB + (long)(tileN + sr) * ldb + sc;
        sAL = smem + 2 * BM * BK;
        sBL = smem + 3 * BM * BK;
    }
    const long hA = 64L * lda, hB = 64L * ldb;

    const int lane = t & 63;
    const int wv = t >> 6;
    const int wr = (wv >> 1) << 6, wc = (wv & 1) << 6;
    const int fr = lane & 15, kg = lane >> 4;

    f32x4 acc[4][4];
    const f32x4 vzero = {0.f, 0.f, 0.f, 0.f};
#pragma unroll
    for (int m = 0; m < 4; ++m)
#pragma unroll
        for (int n = 0; n < 4; ++n) acc[m][n] = vzero;

    for (int k0 = 0; k0 < K; k0 += BK) {
        gld16(pA + k0,      sAH + t * 8);
        gld16(pA + k0 + hA, sAH + 2048 + t * 8);
        gld16(pB + k0,      sBH + t * 8);
        gld16(pB + k0 + hB, sBH + 2048 + t * 8);
        if constexpr (SPLIT) {
            gld16(pAl + k0,      sAL + t * 8);
            gld16(pAl + k0 + hA, sAL + 2048 + t * 8);
            gld16(pBl + k0,      sBL + t * 8);
            gld16(pBl + k0 + hB, sBL + 2048 + t * 8);
        }
        __syncthreads();

        bf16x8 fa[4], fb[4], fal[4], fbl[4];
#pragma unroll
        for (int m = 0; m < 4; ++m) {
            fa[m] = *(const bf16x8*)&sAH[(wr + m * 16 + fr) * BK + (kg << 3)];
            fb[m] = *(const bf16x8*)&sBH[(wc + m * 16 + fr) * BK + (kg << 3)];
            if constexpr (SPLIT) {
                fal[m] = *(const bf16x8*)&sAL[(wr + m * 16 + fr) * BK + (kg << 3)];
                fbl[m] = *(const bf16x8*)&sBL[(wc + m * 16 + fr) * BK + (kg << 3)];
            }
        }
#pragma unroll
        for (int m = 0; m < 4; ++m)
#pragma unroll
            for (int n = 0; n < 4; ++n) {
                acc[m][n] = __builtin_amdgcn_mfma_f32_16x16x32_bf16(fa[m], fb[n], acc[m][n], 0, 0, 0);
                if constexpr (SPLIT) {
                    acc[m][n] = __builtin_amdgcn_mfma_f32_16x16x32_bf16(fa[m],  fbl[n], acc[m][n], 0, 0, 0);
                    acc[m][n] = __builtin_amdgcn_mfma_f32_16x16x32_bf16(fal[m], fb[n],  acc[m][n], 0, 0, 0);
                }
            }
        __syncthreads();
    }

#pragma unroll
    for (int m = 0; m < 4; ++m) {
        const int r0 = tileM + wr + m * 16 + (kg << 2);
#pragma unroll
        for (int n = 0; n < 4; ++n) {
            const int col = tileN + wc + n * 16 + fr;
            if (col >= N) continue;
#pragma unroll
            for (int i = 0; i < 4; ++i) {
                const int r = r0 + i;
                if (r >= M) continue;
                const float v = acc[m][n][i];
                const long off = zC + (long)r * ldc + col;
                if constexpr (EPI == 0) {
                    Cf[off] = v;
                } else if constexpr (EPI == 1) {
                    const u16 h = f2bf(v);
                    CH[off] = h;
                    CL[off] = f2bf(v - bf2f(h));
                } else {
                    CH[off] = f2bf(fmaxf(v, 0.f));
                }
            }
        }
    }
}

// ---------------------------------------------------------------------------
// MoE segmented GEMM: rows within [seg[e], seg[e+1]); B per-expert; 1-pass bf16.
// A buffer must be padded by >=128 rows beyond NSLOT (overreads discarded).
// ---------------------------------------------------------------------------
template<int EPI>
__global__ __launch_bounds__(256) void gemm_moe(
    const u16* __restrict__ Ag, const u16* __restrict__ BTbase,
    float* __restrict__ Cf, u16* __restrict__ CH,
    int N, int K, int ldc, const int* __restrict__ seg, long btStride)
{
    __shared__ u16 smem[2 * BM * BK];
    u16* sA = smem;
    u16* sB = smem + BM * BK;

    const int e = blockIdx.z;
    const int s0 = seg[e], s1 = seg[e + 1];
    const int rowbase = s0 + blockIdx.y * BM;
    if (rowbase >= s1) return;
    const u16* BT = BTbase + (long)e * btStride;

    const int tileN = blockIdx.x * BN;
    const int t = threadIdx.x;
    const int sr = t >> 2, sc = (t & 3) << 3;
    const u16* pA = Ag + (long)(rowbase + sr) * K + sc;
    const u16* pB = BT + (long)(tileN + sr) * K + sc;
    const long hA = 64L * K, hB = 64L * K;

    const int lane = t & 63;
    const int wv = t >> 6;
    const int wr = (wv >> 1) << 6, wc = (wv & 1) << 6;
    const int fr = lane & 15, kg = lane >> 4;

    f32x4 acc[4][4];
    const f32x4 vzero = {0.f, 0.f, 0.f, 0.f};
#pragma unroll
    for (int m = 0; m < 4; ++m)
#pragma unroll
        for (int n = 0; n < 4; ++n) acc[m][n] = vzero;

    for (int k0 = 0; k0 < K; k0 += BK) {
        gld16(pA + k0,      sA + t * 8);
        gld16(pA + k0 + hA, sA + 2048 + t * 8);
        gld16(pB + k0,      sB + t * 8);
        gld16(pB + k0 + hB, sB + 2048 + t * 8);
        __syncthreads();
        bf16x8 fa[4], fb[4];
#pragma unroll
        for (int m = 0; m < 4; ++m) {
            fa[m] = *(const bf16x8*)&sA[(wr + m * 16 + fr) * BK + (kg << 3)];
            fb[m] = *(const bf16x8*)&sB[(wc + m * 16 + fr) * BK + (kg << 3)];
        }
#pragma unroll
        for (int m = 0; m < 4; ++m)
#pragma unroll
            for (int n = 0; n < 4; ++n)
                acc[m][n] = __builtin_amdgcn_mfma_f32_16x16x32_bf16(fa[m], fb[n], acc[m][n], 0, 0, 0);
        __syncthreads();
    }

#pragma unroll
    for (int m = 0; m < 4; ++m) {
        const int r0 = rowbase + wr + m * 16 + (kg << 2);
#pragma unroll
        for (int n = 0; n < 4; ++n) {
            const int col = tileN + wc + n * 16 + fr;
            if (col >= N) continue;
#pragma unroll
            for (int i = 0; i < 4; ++i) {
                const int r = r0 + i;
                if (r >= s1) continue;
                const float v = acc[m][n][i];
                const long off = (long)r * ldc + col;
                if constexpr (EPI == 0) Cf[off] = v;
                else                    CH[off] = f2bf(fmaxf(v, 0.f));
            }
        }
    }
}

// ---------------------------------------------------------------------------
// f32 -> bf16 hi/lo elementwise split. n multiple of 4.
// ---------------------------------------------------------------------------
__global__ __launch_bounds__(256) void split2k(const float* __restrict__ in,
                                               u16* __restrict__ oh, u16* __restrict__ ol, long n)
{
    long i = ((long)blockIdx.x * 256 + threadIdx.x) * 4;
    if (i >= n) return;
    float4 v = *(const float4*)(in + i);
    u16 h0 = f2bf(v.x), h1 = f2bf(v.y), h2 = f2bf(v.z), h3 = f2bf(v.w);
    uint2 oo;
    oo.x = (unsigned)h0 | ((unsigned)h1 << 16);
    oo.y = (unsigned)h2 | ((unsigned)h3 << 16);
    *(uint2*)(oh + i) = oo;
    if (ol) {
        u16 l0 = f2bf(v.x - bf2f(h0)), l1 = f2bf(v.y - bf2f(h1));
        u16 l2 = f2bf(v.z - bf2f(h2)), l3 = f2bf(v.w - bf2f(h3));
        uint2 ll;
        ll.x = (unsigned)l0 | ((unsigned)l1 << 16);
        ll.y = (unsigned)l2 | ((unsigned)l3 << 16);
        *(uint2*)(ol + i) = ll;
    }
}

// ---------------------------------------------------------------------------
// Transpose + split: in[R,C] (ld=ild) per batch z (offset = (z/nb2)*ibs1 + (z%nb2)*ibs2)
//  -> oh/ol [C,R] (ld=old) at z*obs.
// ---------------------------------------------------------------------------
__global__ __launch_bounds__(256) void transpose_split(
    const float* __restrict__ in, u16* __restrict__ oh, u16* __restrict__ ol,
    int R, int C, int ild, long ibs1, long ibs2, int nb2, int old_, long obs)
{
    __shared__ float tile[32][33];
    const int z = blockIdx.z;
    const float* ip = in + (long)(z / nb2) * ibs1 + (long)(z % nb2) * ibs2;
    u16* ohp = oh + (long)z * obs;
    u16* olp = ol ? ol + (long)z * obs : nullptr;
    const int c0 = blockIdx.x * 32, r0 = blockIdx.y * 32;
    const int tx = threadIdx.x & 31, ty = threadIdx.x >> 5;
    for (int i = ty; i < 32; i += 8) {
        int r = r0 + i, c = c0 + tx;
        tile[i][tx] = (r < R && c < C) ? ip[(long)r * ild + c] : 0.f;
    }
    __syncthreads();
    for (int i = ty; i < 32; i += 8) {
        int oc = c0 + i, orr = r0 + tx;
        if (oc < C && orr < R) {
            float v = tile[tx][i];
            u16 h = f2bf(v);
            ohp[(long)oc * old_ + orr] = h;
            if (olp) olp[(long)oc * old_ + orr] = f2bf(v - bf2f(h));
        }
    }
}

// ---------------------------------------------------------------------------
// Row softmax (pre-scale) fused with bf16 hi/lo split store. One block per row.
// ---------------------------------------------------------------------------
__global__ __launch_bounds__(256) void softmax_split(
    const float* __restrict__ s, u16* __restrict__ ph, u16* __restrict__ pl,
    int cols, float scale)
{
    const float* p = s + (long)blockIdx.x * cols;
    u16* php = ph + (long)blockIdx.x * cols;
    u16* plp = pl + (long)blockIdx.x * cols;
    const int t = threadIdx.x;
    const int vpt = cols >> 8;
    float v[4];
    float mx = -3.4e38f;
    for (int i = 0; i < vpt; ++i) { v[i] = p[t + (i << 8)] * scale; mx = fmaxf(mx, v[i]); }
#pragma unroll
    for (int o = 32; o; o >>= 1) mx = fmaxf(mx, __shfl_xor(mx, o));
    __shared__ float sm[4];
    const int wv = t >> 6, ln = t & 63;
    if (ln == 0) sm[wv] = mx;
    __syncthreads();
    mx = fmaxf(fmaxf(sm[0], sm[1]), fmaxf(sm[2], sm[3]));
    float sum = 0.f;
    for (int i = 0; i < vpt; ++i) { v[i] = expf(v[i] - mx); sum += v[i]; }
#pragma unroll
    for (int o = 32; o; o >>= 1) sum += __shfl_xor(sum, o);
    __shared__ float ss[4];
    if (ln == 0) ss[wv] = sum;
    __syncthreads();
    sum = ss[0] + ss[1] + ss[2] + ss[3];
    const float inv = 1.f / sum;
    for (int i = 0; i < vpt; ++i) {
        const int c = t + (i << 8);
        const float q = v[i] * inv;
        const u16 h = f2bf(q);
        php[c] = h;
        plp[c] = f2bf(q - bf2f(h));
    }
}

// ---------------------------------------------------------------------------
// x = rmsnorm(a + b, g); optional bf16 hi/lo split of x. One block per row (d=1024).
// ---------------------------------------------------------------------------
__global__ __launch_bounds__(256) void add_rmsnorm(
    const float* __restrict__ a, const float* __restrict__ b, const float* __restrict__ g,
    float* __restrict__ xo, u16* __restrict__ xh, u16* __restrict__ xl)
{
    const long row = blockIdx.x;
    const int t = threadIdx.x;
    const float* pa = a + row * D_;
    const float* pb = b + row * D_;
    float v[4]; double ssq = 0.0;
#pragma unroll
    for (int i = 0; i < 4; ++i) {
        int c = t + (i << 8);
        v[i] = pa[c] + pb[c];
        ssq += (double)v[i] * v[i];
    }
#pragma unroll
    for (int o = 32; o; o >>= 1) ssq += __shfl_xor(ssq, o);
    __shared__ double sd[4];
    if ((t & 63) == 0) sd[t >> 6] = ssq;
    __syncthreads();
    ssq = sd[0] + sd[1] + sd[2] + sd[3];
    const float rs = (float)(1.0 / sqrt(ssq * (1.0 / 1024.0) + 1e-6));
#pragma unroll
    for (int i = 0; i < 4; ++i) {
        int c = t + (i << 8);
        float o = v[i] * rs * g[c];
        xo[row * D_ + c] = o;
        if (xh) {
            u16 h = f2bf(o);
            xh[row * D_ + c] = h;
            if (xl) xl[row * D_ + c] = f2bf(o - bf2f(h));
        }
    }
}

// ---------------------------------------------------------------------------
// Router: one 64-lane wave per token; fp32 logits; exact top-2 (lowest index wins ties).
// ---------------------------------------------------------------------------
__global__ __launch_bounds__(256) void router_topk(
    const float* __restrict__ x2, const float* __restrict__ Wg,
    float* __restrict__ outw, float* __restrict__ outi,
    int* __restrict__ idx, float* __restrict__ tokw, int* __restrict__ counts, int T)
{
    const int wid = (int)((blockIdx.x * 256 + threadIdx.x) >> 6);
    const int lane = threadIdx.x & 63;
    if (wid >= T) return;
    float acc[NE];
#pragma unroll
    for (int e = 0; e < NE; ++e) acc[e] = 0.f;
    const float* xr = x2 + (long)wid * D_;
    for (int i = 0; i < 16; ++i) {
        float xv = xr[i * 64 + lane];
        const float* wr = Wg + (long)(i * 64 + lane) * NE;
#pragma unroll
        for (int e = 0; e < NE; ++e) acc[e] += xv * wr[e];
    }
#pragma unroll
    for (int e = 0; e < NE; ++e)
#pragma unroll
        for (int o = 32; o; o >>= 1) acc[e] += __shfl_xor(acc[e], o);
    if (lane == 0) {
        float m = acc[0];
#pragma unroll
        for (int e = 1; e < NE; ++e) m = fmaxf(m, acc[e]);
        float p[NE], s = 0.f;
#pragma unroll
        for (int e = 0; e < NE; ++e) { p[e] = expf(acc[e] - m); s += p[e]; }
        const float invs = 1.f / s;
#pragma unroll
        for (int e = 0; e < NE; ++e) p[e] *= invs;
        int e0 = 0;
#pragma unroll
        for (int e = 1; e < NE; ++e) if (p[e] > p[e0]) e0 = e;
        int e1 = (e0 == 0) ? 1 : 0;
#pragma unroll
        for (int e = 0; e < NE; ++e) if (e != e0 && e != e1 && p[e] > p[e1]) e1 = e;
        float w0 = p[e0], w1 = p[e1];
        const float sw = 1.f / (w0 + w1);
        w0 *= sw; w1 *= sw;
        outw[2 * wid] = w0;      outw[2 * wid + 1] = w1;
        outi[2 * wid] = (float)e0; outi[2 * wid + 1] = (float)e1;
        idx[2 * wid] = e0;       idx[2 * wid + 1] = e1;
        tokw[2 * wid] = w0;      tokw[2 * wid + 1] = w1;
        atomicAdd(&counts[e0], 1);
        atomicAdd(&counts[e1], 1);
    }
}

__global__ void scan8(const int* __restrict__ counts, int* __restrict__ seg, int* __restrict__ cursor)
{
    if (threadIdx.x == 0 && blockIdx.x == 0) {
        int a = 0;
        for (int e = 0; e < NE; ++e) { seg[e] = a; cursor[e] = a; a += counts[e]; }
        seg[NE] = a;
    }
}

__global__ __launch_bounds__(256) void scatter_slots(
    const int* __restrict__ idx, int* __restrict__ cursor,
    int* __restrict__ row_token, int* __restrict__ slot_of, int T)
{
    const int t = blockIdx.x * 256 + threadIdx.x;
    if (t >= T) return;
#pragma unroll
    for (int k = 0; k < 2; ++k) {
        const int e = idx[2 * t + k];
        const int pos = atomicAdd(&cursor[e], 1);
        row_token[pos] = t;
        slot_of[2 * t + k] = pos;
    }
}

__global__ __launch_bounds__(256) void gather_bf16(
    const float* __restrict__ x2, const int* __restrict__ row_token, u16* __restrict__ Xg)
{
    const int r = blockIdx.x;
    const int t = threadIdx.x;
    const float* src = x2 + (long)row_token[r] * D_ + t * 4;
    float4 v = *(const float4*)src;
    uint2 oo;
    oo.x = (unsigned)f2bf(v.x) | ((unsigned)f2bf(v.y) << 16);
    oo.y = (unsigned)f2bf(v.z) | ((unsigned)f2bf(v.w) << 16);
    *(uint2*)(Xg + (long)r * D_ + t * 4) = oo;
}

// ---------------------------------------------------------------------------
// Final: x = rmsnorm(w0*Y[s0] + w1*Y[s1] + x2, g) -> out
// ---------------------------------------------------------------------------
__global__ __launch_bounds__(256) void combine_rmsnorm(
    const float* __restrict__ Y, const int* __restrict__ slot_of, const float* __restrict__ tokw,
    const float* __restrict__ x2, const float* __restrict__ g, float* __restrict__ out)
{
    const long tr = blockIdx.x;
    const int t = threadIdx.x;
    const int s0 = slot_of[2 * tr], s1 = slot_of[2 * tr + 1];
    const float w0 = tokw[2 * tr], w1 = tokw[2 * tr + 1];
    const float* y0 = Y + (long)s0 * D_;
    const float* y1 = Y + (long)s1 * D_;
    const float* xr = x2 + tr * D_;
    float v[4]; double ssq = 0.0;
#pragma unroll
    for (int i = 0; i < 4; ++i) {
        int c = t + (i << 8);
        v[i] = w0 * y0[c] + w1 * y1[c] + xr[c];
        ssq += (double)v[i] * v[i];
    }
#pragma unroll
    for (int o = 32; o; o >>= 1) ssq += __shfl_xor(ssq, o);
    __shared__ double sd[4];
    if ((t & 63) == 0) sd[t >> 6] = ssq;
    __syncthreads();
    ssq = sd[0] + sd[1] + sd[2] + sd[3];
    const float rs = (float)(1.0 / sqrt(ssq * (1.0 / 1024.0) + 1e-6));
#pragma unroll
    for (int i = 0; i < 4; ++i) {
        int c = t + (i << 8);
        out[tr * D_ + c] = v[i] * rs * g[c];
    }
}

__global__ void sentinel(float* o) { o[0] = 12345.0f; }

// ---------------------------------------------------------------------------
extern "C" void kernel_launch(void* const* d_in, const int* in_sizes, int n_in,
                              void* d_out, int out_size, void* d_ws, size_t ws_size,
                              hipStream_t stream)
{
    const float* dec = (const float*)d_in[0];
    const float* te  = (const float*)d_in[1];
    const float* Win[8] = { (const float*)d_in[2], (const float*)d_in[3], (const float*)d_in[4],
                            (const float*)d_in[5], (const float*)d_in[6], (const float*)d_in[7],
                            (const float*)d_in[8], (const float*)d_in[9] };
    const float* g  = (const float*)d_in[10];
    const float* Wg = (const float*)d_in[11];
    const float* W1 = (const float*)d_in[12];
    const float* W2 = (const float*)d_in[13];
    float* outw = (float*)d_out;                 // [T,2] router weights
    float* outi = outw + 2 * TDEC;               // [T,2] indices as float
    float* outx = outw + 4 * TDEC;               // [T,1024]

    char* ws = (char*)d_ws;
    size_t off = 0;
    auto A = [&](size_t bytes) -> char* {
        char* p = ws + off;
        off += (bytes + 255) & ~(size_t)255;
        return p;
    };

    // ---- persistent region ----
    u16* decH = (u16*)A((size_t)TDEC * D_ * 2);
    u16* decL = (u16*)A((size_t)TDEC * D_ * 2);
    u16* teH  = (u16*)A((size_t)TTXT * D_ * 2);
    u16* teL  = (u16*)A((size_t)TTXT * D_ * 2);
    u16 *wtH[8], *wtL[8];
    for (int i = 0; i < 8; ++i) {
        wtH[i] = (u16*)A((size_t)D_ * D_ * 2);
        wtL[i] = (u16*)A((size_t)D_ * D_ * 2);
    }
    float* x1f = (float*)A((size_t)TDEC * D_ * 4);
    float* x2f = (float*)A((size_t)TDEC * D_ * 4);
    float* tokw = (float*)A(NSLOT * 4);
    int* idx    = (int*)A(NSLOT * 4);
    int* counts = (int*)A(256);
    int* seg    = (int*)A(256);
    int* cursor = (int*)A(256);
    int* row_token = (int*)A(NSLOT * 4);
    int* slot_of   = (int*)A(NSLOT * 4);

    // ---- shared region R: attention view ----
    const size_t Rbase = off;
    float* scores = (float*)A((size_t)NH * SDEC * SDEC * 4);
    u16* PH = (u16*)A((size_t)NH * SDEC * SDEC * 2);
    u16* PL = (u16*)A((size_t)NH * SDEC * SDEC * 2);
    u16* qH  = (u16*)A((size_t)TDEC * D_ * 2);
    u16* qL  = (u16*)A((size_t)TDEC * D_ * 2);
    u16* kH  = (u16*)A((size_t)TDEC * D_ * 2);
    u16* kL  = (u16*)A((size_t)TDEC * D_ * 2);
    u16* vTH = (u16*)A(((size_t)TDEC * D_ + 128 * SDEC) * 2);  // +128-row pad (N=64 B-panel overread)
    u16* vTL = (u16*)A(((size_t)TDEC * D_ + 128 * SDEC) * 2);
    u16* aoH = (u16*)A((size_t)TDEC * D_ * 2);
    u16* aoL = (u16*)A((size_t)TDEC * D_ * 2);
    float* vf = (float*)A((size_t)TDEC * D_ * 4);
    u16* x1H = (u16*)A((size_t)TDEC * D_ * 2);
    u16* x1L = (u16*)A((size_t)TDEC * D_ * 2);
    float* of = (float*)A((size_t)TDEC * D_ * 4);
    const size_t attnEnd = off;

    // ---- shared region R: MoE view (overlays attention view; used strictly later) ----
    off = Rbase;
    u16* W1T  = (u16*)A((size_t)NE * DFF * D_ * 2);
    u16* W2T  = (u16*)A((size_t)NE * D_ * DFF * 2);
    u16* Xg   = (u16*)A((size_t)(NSLOT + 128) * D_ * 2);       // +128-row pad (segment-tail overread)
    u16* Hb   = (u16*)A((size_t)(NSLOT + 128) * DFF * 2);
    float* Yseg = (float*)A((size_t)NSLOT * D_ * 4);
    const size_t needed = (off > attnEnd ? off : attnEnd);

    if (ws_size < needed) {  // distinctive failure signature instead of corruption
        sentinel<<<1, 1, 0, stream>>>(outw);
        return;
    }

    const dim3 blk(256);
    auto g3 = [](int n, int m, int z) { return dim3((n + BN - 1) / BN, (m + BM - 1) / BM, z); };

    // ---- phase 0: input splits + attention weight transposes ----
    split2k<<<dim3((TDEC * D_) / 1024), blk, 0, stream>>>(dec, decH, decL, (long)TDEC * D_);
    split2k<<<dim3((TTXT * D_) / 1024), blk, 0, stream>>>(te, teH, teL, (long)TTXT * D_);
    for (int i = 0; i < 8; ++i)
        transpose_split<<<dim3(32, 32, 1), blk, 0, stream>>>(Win[i], wtH[i], wtL[i],
                                                             D_, D_, D_, 0, 0, 1, D_, 0);

    // ---- phase 1: self-attention ----
    gemm_bt<1, 1><<<g3(D_, TDEC, 1), blk, 0, stream>>>(decH, decL, wtH[0], wtL[0],
        nullptr, qH, qL, TDEC, D_, D_, D_, D_, D_, 0, 0, 0);
    gemm_bt<1, 1><<<g3(D_, TDEC, 1), blk, 0, stream>>>(decH, decL, wtH[1], wtL[1],
        nullptr, kH, kL, TDEC, D_, D_, D_, D_, D_, 0, 0, 0);
    gemm_bt<1, 0><<<g3(D_, TDEC, 1), blk, 0, stream>>>(decH, decL, wtH[2], wtL[2],
        vf, nullptr, nullptr, TDEC, D_, D_, D_, D_, D_, 0, 0, 0);
    transpose_split<<<dim3(2, 32, BB * NH), blk, 0, stream>>>(vf, vTH, vTL,
        SDEC, DHD, D_, (long)SDEC * D_, DHD, NH, SDEC, (long)DHD * SDEC);

    for (int b = 0; b < BB; ++b) {
        const long qo = (long)b * SDEC * D_;
        gemm_bt<1, 0><<<g3(SDEC, SDEC, NH), blk, 0, stream>>>(qH + qo, qL + qo, kH + qo, kL + qo,
            scores, nullptr, nullptr, SDEC, SDEC, DHD, D_, D_, SDEC,
            DHD, DHD, (long)SDEC * SDEC);
        softmax_split<<<dim3(NH * SDEC), blk, 0, stream>>>(scores, PH, PL, SDEC, 0.125f);
        gemm_bt<1, 1><<<g3(DHD, SDEC, NH), blk, 0, stream>>>(PH, PL,
            vTH + (long)b * NH * DHD * SDEC, vTL + (long)b * NH * DHD * SDEC,
            nullptr, aoH + qo, aoL + qo, SDEC, DHD, SDEC, SDEC, SDEC, D_,
            (long)SDEC * SDEC, (long)DHD * SDEC, DHD);
    }
    gemm_bt<1, 0><<<g3(D_, TDEC, 1), blk, 0, stream>>>(aoH, aoL, wtH[3], wtL[3],
        of, nullptr, nullptr, TDEC, D_, D_, D_, D_, D_, 0, 0, 0);
    add_rmsnorm<<<dim3(TDEC), blk, 0, stream>>>(of, dec, g, x1f, x1H, x1L);

    // ---- phase 2: cross-attention ----
    gemm_bt<1, 1><<<g3(D_, TDEC, 1), blk, 0, stream>>>(x1H, x1L, wtH[4], wtL[4],
        nullptr, qH, qL, TDEC, D_, D_, D_, D_, D_, 0, 0, 0);
    gemm_bt<1, 1><<<g3(D_, TTXT, 1), blk, 0, stream>>>(teH, teL, wtH[5], wtL[5],
        nullptr, kH, kL, TTXT, D_, D_, D_, D_, D_, 0, 0, 0);
    gemm_bt<1, 0><<<g3(D_, TTXT, 1), blk, 0, stream>>>(teH, teL, wtH[6], wtL[6],
        vf, nullptr, nullptr, TTXT, D_, D_, D_, D_, D_, 0, 0, 0);
    transpose_split<<<dim3(2, 16, BB * NH), blk, 0, stream>>>(vf, vTH, vTL,
        STXT, DHD, D_, (long)STXT * D_, DHD, NH, STXT, (long)DHD * STXT);

    for (int b = 0; b < BB; ++b) {
        const long qo = (long)b * SDEC * D_;
        const long ko = (long)b * STXT * D_;
        gemm_bt<1, 0><<<g3(STXT, SDEC, NH), blk, 0, stream>>>(qH + qo, qL + qo, kH + ko, kL + ko,
            scores, nullptr, nullptr, SDEC, STXT, DHD, D_, D_, STXT,
            DHD, DHD, (long)SDEC * STXT);
        softmax_split<<<dim3(NH * SDEC), blk, 0, stream>>>(scores, PH, PL, STXT, 0.125f);
        gemm_bt<1, 1><<<g3(DHD, SDEC, NH), blk, 0, stream>>>(PH, PL,
            vTH + (long)b * NH * DHD * STXT, vTL + (long)b * NH * DHD * STXT,
            nullptr, aoH + qo, aoL + qo, SDEC, DHD, STXT, STXT, STXT, D_,
            (long)SDEC * STXT, (long)DHD * STXT, DHD);
    }
    gemm_bt<1, 0><<<g3(D_, TDEC, 1), blk, 0, stream>>>(aoH, aoL, wtH[7], wtL[7],
        of, nullptr, nullptr, TDEC, D_, D_, D_, D_, D_, 0, 0, 0);
    add_rmsnorm<<<dim3(TDEC), blk, 0, stream>>>(of, x1f, g, x2f, nullptr, nullptr);

    // ---- phase 3: router + expert bucketing ----
    hipMemsetAsync(counts, 0, 32, stream);
    router_topk<<<dim3(TDEC / 4), blk, 0, stream>>>(x2f, Wg, outw, outi, idx, tokw, counts, TDEC);
    scan8<<<1, 64, 0, stream>>>(counts, seg, cursor);
    scatter_slots<<<dim3(TDEC / 256), blk, 0, stream>>>(idx, cursor, row_token, slot_of, TDEC);
    gather_bf16<<<dim3(NSLOT), blk, 0, stream>>>(x2f, row_token, Xg);

    // ---- phase 4: MoE FFN (bf16) + final norm ----
    transpose_split<<<dim3(DFF / 32, D_ / 32, NE), blk, 0, stream>>>(W1, W1T, nullptr,
        D_, DFF, DFF, (long)D_ * DFF, 0, 1, D_, (long)DFF * D_);
    transpose_split<<<dim3(D_ / 32, DFF / 32, NE), blk, 0, stream>>>(W2, W2T, nullptr,
        DFF, D_, D_, (long)D_ * DFF, 0, 1, DFF, (long)D_ * DFF);
    gemm_moe<2><<<dim3(DFF / BN, NSLOT / BM, NE), blk, 0, stream>>>(Xg, W1T,
        nullptr, Hb, DFF, D_, DFF, seg, (long)DFF * D_);
    gemm_moe<0><<<dim3(D_ / BN, NSLOT / BM, NE), blk, 0, stream>>>(Hb, W2T,
        Yseg, nullptr, D_, DFF, D_, seg, (long)D_ * DFF);
    combine_rmsnorm<<<dim3(TDEC), blk, 0, stream>>>(Yseg, slot_of, tokw, x2f, g, outx);

    (void)in_sizes; (void)n_in; (void)out_size;
}

// Round 3
// 1488.029 us; speedup vs baseline: 1.3953x; 1.1493x over previous
//
#include <hip/hip_runtime.h>
#include <stdint.h>

#define D_    1024
#define BB    4
#define SDEC  1024
#define STXT  512
#define TDEC  4096
#define TTXT  2048
#define NH    16
#define DHD   64
#define NE    8
#define DFF   4096
#define NSLOT 8192
#define MAXYT 24   // max 128-row tiles per expert (3072 slots; ~34 sigma above mean 1024)

using u16 = unsigned short;
typedef __attribute__((ext_vector_type(8))) short bf16x8;
typedef __attribute__((ext_vector_type(4))) float f32x4;

__device__ __forceinline__ float bf2f(u16 h) {
    union { unsigned int u; float f; } x; x.u = ((unsigned int)h) << 16; return x.f;
}
__device__ __forceinline__ u16 f2bf(float f) {
    union { float f; unsigned int u; } x; x.f = f;
    unsigned int lsb = (x.u >> 16) & 1u;
    return (u16)((x.u + 0x7fffu + lsb) >> 16);
}

// async global->LDS, 16B per lane, linear LDS dest (wave-uniform base + lane*16)
__device__ __forceinline__ void gld16(const u16* g, u16* l) {
    __builtin_amdgcn_global_load_lds((const __attribute__((address_space(1))) void*)g,
                                     (__attribute__((address_space(3))) void*)l,
                                     16, 0, 0);
}

constexpr int BM = 128, BK = 32;

// ---------------------------------------------------------------------------
// Generic tiled GEMM: C[M,N] = A[M,K] * BT[N,K]^T  (row-major, BT = B transposed).
// SPLIT=0: plain bf16.  SPLIT=1: 3-pass split emulation (AH*BH + AH*BL + AL*BH).
// EPI: 0 = f32 store, 1 = split store, 2 = relu+bf16.
// BROWS: B-tile rows. 128 -> 2x2 waves (BN=128). 64 -> 4x1 waves (BN=64, for PV).
// K % 32 == 0; M % 128 == 0; B panel rows must allow reading tileN..tileN+BROWS-1.
// ---------------------------------------------------------------------------
template<int SPLIT, int EPI, int BROWS>
__global__ __launch_bounds__(256) void gemm_bt(
    const u16* __restrict__ AH, const u16* __restrict__ AL,
    const u16* __restrict__ BH, const u16* __restrict__ BL,
    float* __restrict__ Cf, u16* __restrict__ CH, u16* __restrict__ CL,
    int M, int N, int K, int lda, int ldb, int ldc,
    long strA, long strB, long strC)
{
    constexpr int WM = (BROWS == 64) ? 2 : 4;   // m-fragments per wave
    constexpr int ASZ = BM * BK, BSZ = BROWS * BK;
    __shared__ u16 smem[(SPLIT ? 2 : 1) * (ASZ + BSZ)];
    u16* sAH = smem;
    u16* sBH = smem + ASZ;
    u16* sAL = SPLIT ? smem + ASZ + BSZ : nullptr;
    u16* sBL = SPLIT ? smem + 2 * ASZ + BSZ : nullptr;

    const int z = blockIdx.z;
    const long zA = (long)z * strA, zB = (long)z * strB, zC = (long)z * strC;

    const int tileM = blockIdx.y * BM, tileN = blockIdx.x * BROWS;
    const int t = threadIdx.x;
    const int sr = t >> 2;          // staging row 0..63
    const int sc = (t & 3) << 3;    // staging col chunk (elements)
    const u16* pA = AH + zA + (long)(tileM + sr) * lda + sc;
    const u16* pB = BH + zB + (long)(tileN + sr) * ldb + sc;
    const u16* pAl = nullptr; const u16* pBl = nullptr;
    if constexpr (SPLIT) {
        pAl = AL + zA + (long)(tileM + sr) * lda + sc;
        pBl = BL + zB + (long)(tileN + sr) * ldb + sc;
    }
    const long hA = 64L * lda, hB = 64L * ldb;

    const int lane = t & 63;
    const int wv = t >> 6;
    const int wr = (BROWS == 64) ? (wv << 5) : ((wv >> 1) << 6);
    const int wc = (BROWS == 64) ? 0 : ((wv & 1) << 6);
    const int fr = lane & 15, kg = lane >> 4;

    f32x4 acc[WM][4];
    const f32x4 vzero = {0.f, 0.f, 0.f, 0.f};
#pragma unroll
    for (int m = 0; m < WM; ++m)
#pragma unroll
        for (int n = 0; n < 4; ++n) acc[m][n] = vzero;

    for (int k0 = 0; k0 < K; k0 += BK) {
        gld16(pA + k0,      sAH + t * 8);
        gld16(pA + k0 + hA, sAH + 2048 + t * 8);
        gld16(pB + k0,      sBH + t * 8);
        if constexpr (BROWS == 128) gld16(pB + k0 + hB, sBH + 2048 + t * 8);
        if constexpr (SPLIT) {
            gld16(pAl + k0,      sAL + t * 8);
            gld16(pAl + k0 + hA, sAL + 2048 + t * 8);
            gld16(pBl + k0,      sBL + t * 8);
            if constexpr (BROWS == 128) gld16(pBl + k0 + hB, sBL + 2048 + t * 8);
        }
        __syncthreads();

        bf16x8 fa[WM], fb[4], fal[WM], fbl[4];
#pragma unroll
        for (int m = 0; m < WM; ++m) {
            fa[m] = *(const bf16x8*)&sAH[(wr + m * 16 + fr) * BK + (kg << 3)];
            if constexpr (SPLIT) fal[m] = *(const bf16x8*)&sAL[(wr + m * 16 + fr) * BK + (kg << 3)];
        }
#pragma unroll
        for (int n = 0; n < 4; ++n) {
            fb[n] = *(const bf16x8*)&sBH[(wc + n * 16 + fr) * BK + (kg << 3)];
            if constexpr (SPLIT) fbl[n] = *(const bf16x8*)&sBL[(wc + n * 16 + fr) * BK + (kg << 3)];
        }
#pragma unroll
        for (int m = 0; m < WM; ++m)
#pragma unroll
            for (int n = 0; n < 4; ++n) {
                acc[m][n] = __builtin_amdgcn_mfma_f32_16x16x32_bf16(fa[m], fb[n], acc[m][n], 0, 0, 0);
                if constexpr (SPLIT) {
                    acc[m][n] = __builtin_amdgcn_mfma_f32_16x16x32_bf16(fa[m],  fbl[n], acc[m][n], 0, 0, 0);
                    acc[m][n] = __builtin_amdgcn_mfma_f32_16x16x32_bf16(fal[m], fb[n],  acc[m][n], 0, 0, 0);
                }
            }
        __syncthreads();
    }

#pragma unroll
    for (int m = 0; m < WM; ++m) {
        const int r0 = tileM + wr + m * 16 + (kg << 2);
#pragma unroll
        for (int n = 0; n < 4; ++n) {
            const int col = tileN + wc + n * 16 + fr;
            if (col >= N) continue;
#pragma unroll
            for (int i = 0; i < 4; ++i) {
                const int r = r0 + i;
                if (r >= M) continue;
                const float v = acc[m][n][i];
                const long off = zC + (long)r * ldc + col;
                if constexpr (EPI == 0) {
                    Cf[off] = v;
                } else if constexpr (EPI == 1) {
                    const u16 h = f2bf(v);
                    CH[off] = h;
                    CL[off] = f2bf(v - bf2f(h));
                } else {
                    CH[off] = f2bf(fmaxf(v, 0.f));
                }
            }
        }
    }
}

// ---------------------------------------------------------------------------
// MoE segmented GEMM with expert->XCD affinity. 1-D grid = 8 * MAXYT * ntx.
// Decode: e = bid%8 (XCD round-robin), yt fastest within XCD (B-slice reuse).
// A buffer padded >=128 rows beyond NSLOT.
// ---------------------------------------------------------------------------
template<int EPI>
__global__ __launch_bounds__(256) void gemm_moe(
    const u16* __restrict__ Ag, const u16* __restrict__ BTbase,
    float* __restrict__ Cf, u16* __restrict__ CH,
    int N, int K, int ldc, const int* __restrict__ seg, long btStride, int ntx)
{
    const int bid = blockIdx.x;
    const int e = bid & 7;
    const int rem = bid >> 3;
    const int yt = rem % MAXYT;
    const int xt = rem / MAXYT;
    (void)ntx;

    const int s0 = seg[e], s1 = seg[e + 1];
    const int rowbase = s0 + yt * BM;
    if (rowbase >= s1) return;
    const u16* BT = BTbase + (long)e * btStride;

    __shared__ u16 smem[2 * BM * BK];
    u16* sA = smem;
    u16* sB = smem + BM * BK;

    const int tileN = xt * 128;
    const int t = threadIdx.x;
    const int sr = t >> 2, sc = (t & 3) << 3;
    const u16* pA = Ag + (long)(rowbase + sr) * K + sc;
    const u16* pB = BT + (long)(tileN + sr) * K + sc;
    const long hA = 64L * K, hB = 64L * K;

    const int lane = t & 63;
    const int wv = t >> 6;
    const int wr = (wv >> 1) << 6, wc = (wv & 1) << 6;
    const int fr = lane & 15, kg = lane >> 4;

    f32x4 acc[4][4];
    const f32x4 vzero = {0.f, 0.f, 0.f, 0.f};
#pragma unroll
    for (int m = 0; m < 4; ++m)
#pragma unroll
        for (int n = 0; n < 4; ++n) acc[m][n] = vzero;

    for (int k0 = 0; k0 < K; k0 += BK) {
        gld16(pA + k0,      sA + t * 8);
        gld16(pA + k0 + hA, sA + 2048 + t * 8);
        gld16(pB + k0,      sB + t * 8);
        gld16(pB + k0 + hB, sB + 2048 + t * 8);
        __syncthreads();
        bf16x8 fa[4], fb[4];
#pragma unroll
        for (int m = 0; m < 4; ++m) {
            fa[m] = *(const bf16x8*)&sA[(wr + m * 16 + fr) * BK + (kg << 3)];
            fb[m] = *(const bf16x8*)&sB[(wc + m * 16 + fr) * BK + (kg << 3)];
        }
#pragma unroll
        for (int m = 0; m < 4; ++m)
#pragma unroll
            for (int n = 0; n < 4; ++n)
                acc[m][n] = __builtin_amdgcn_mfma_f32_16x16x32_bf16(fa[m], fb[n], acc[m][n], 0, 0, 0);
        __syncthreads();
    }

#pragma unroll
    for (int m = 0; m < 4; ++m) {
        const int r0 = rowbase + wr + m * 16 + (kg << 2);
#pragma unroll
        for (int n = 0; n < 4; ++n) {
            const int col = tileN + wc + n * 16 + fr;
            if (col >= N) continue;
#pragma unroll
            for (int i = 0; i < 4; ++i) {
                const int r = r0 + i;
                if (r >= s1) continue;
                const float v = acc[m][n][i];
                const long off = (long)r * ldc + col;
                if constexpr (EPI == 0) Cf[off] = v;
                else                    CH[off] = f2bf(fmaxf(v, 0.f));
            }
        }
    }
}

// ---------------------------------------------------------------------------
__global__ __launch_bounds__(256) void split2k(const float* __restrict__ in,
                                               u16* __restrict__ oh, u16* __restrict__ ol, long n)
{
    long i = ((long)blockIdx.x * 256 + threadIdx.x) * 4;
    if (i >= n) return;
    float4 v = *(const float4*)(in + i);
    u16 h0 = f2bf(v.x), h1 = f2bf(v.y), h2 = f2bf(v.z), h3 = f2bf(v.w);
    uint2 oo;
    oo.x = (unsigned)h0 | ((unsigned)h1 << 16);
    oo.y = (unsigned)h2 | ((unsigned)h3 << 16);
    *(uint2*)(oh + i) = oo;
    if (ol) {
        u16 l0 = f2bf(v.x - bf2f(h0)), l1 = f2bf(v.y - bf2f(h1));
        u16 l2 = f2bf(v.z - bf2f(h2)), l3 = f2bf(v.w - bf2f(h3));
        uint2 ll;
        ll.x = (unsigned)l0 | ((unsigned)l1 << 16);
        ll.y = (unsigned)l2 | ((unsigned)l3 << 16);
        *(uint2*)(ol + i) = ll;
    }
}

// ---------------------------------------------------------------------------
// Transpose + split from f32 input (weights).
// ---------------------------------------------------------------------------
__global__ __launch_bounds__(256) void transpose_split(
    const float* __restrict__ in, u16* __restrict__ oh, u16* __restrict__ ol,
    int R, int C, int ild, long ibs1, long ibs2, int nb2, int old_, long obs)
{
    __shared__ float tile[32][33];
    const int z = blockIdx.z;
    const float* ip = in + (long)(z / nb2) * ibs1 + (long)(z % nb2) * ibs2;
    u16* ohp = oh + (long)z * obs;
    u16* olp = ol ? ol + (long)z * obs : nullptr;
    const int c0 = blockIdx.x * 32, r0 = blockIdx.y * 32;
    const int tx = threadIdx.x & 31, ty = threadIdx.x >> 5;
    for (int i = ty; i < 32; i += 8) {
        int r = r0 + i, c = c0 + tx;
        tile[i][tx] = (r < R && c < C) ? ip[(long)r * ild + c] : 0.f;
    }
    __syncthreads();
    for (int i = ty; i < 32; i += 8) {
        int oc = c0 + i, orr = r0 + tx;
        if (oc < C && orr < R) {
            float v = tile[tx][i];
            u16 h = f2bf(v);
            ohp[(long)oc * old_ + orr] = h;
            if (olp) olp[(long)oc * old_ + orr] = f2bf(v - bf2f(h));
        }
    }
}

// ---------------------------------------------------------------------------
// Transpose + re-split from bf16 hi/lo input pair (V extraction from merged proj).
// ---------------------------------------------------------------------------
__global__ __launch_bounds__(256) void transpose_split_hl(
    const u16* __restrict__ inH, const u16* __restrict__ inL,
    u16* __restrict__ oh, u16* __restrict__ ol,
    int R, int C, int ild, long ibs1, long ibs2, int nb2, int old_, long obs)
{
    __shared__ float tile[32][33];
    const int z = blockIdx.z;
    const long base = (long)(z / nb2) * ibs1 + (long)(z % nb2) * ibs2;
    u16* ohp = oh + (long)z * obs;
    u16* olp = ol + (long)z * obs;
    const int c0 = blockIdx.x * 32, r0 = blockIdx.y * 32;
    const int tx = threadIdx.x & 31, ty = threadIdx.x >> 5;
    for (int i = ty; i < 32; i += 8) {
        int r = r0 + i, c = c0 + tx;
        float v = 0.f;
        if (r < R && c < C) {
            const long o = base + (long)r * ild + c;
            v = bf2f(inH[o]) + bf2f(inL[o]);
        }
        tile[i][tx] = v;
    }
    __syncthreads();
    for (int i = ty; i < 32; i += 8) {
        int oc = c0 + i, orr = r0 + tx;
        if (oc < C && orr < R) {
            float v = tile[tx][i];
            u16 h = f2bf(v);
            ohp[(long)oc * old_ + orr] = h;
            olp[(long)oc * old_ + orr] = f2bf(v - bf2f(h));
        }
    }
}

// ---------------------------------------------------------------------------
// Row softmax (pre-scale) fused with bf16 hi/lo split store. One block per row.
// Vectorized: cols=1024 -> float4/lane, cols=512 -> float2/lane.
// ---------------------------------------------------------------------------
__global__ __launch_bounds__(256) void softmax_split(
    const float* __restrict__ s, u16* __restrict__ ph, u16* __restrict__ pl,
    int cols, float scale)
{
    const float* p = s + (long)blockIdx.x * cols;
    u16* php = ph + (long)blockIdx.x * cols;
    u16* plp = pl + (long)blockIdx.x * cols;
    const int t = threadIdx.x;
    float v[4];
    int vpt;
    if (cols == 1024) {
        vpt = 4;
        float4 x = ((const float4*)p)[t];
        v[0] = x.x * scale; v[1] = x.y * scale; v[2] = x.z * scale; v[3] = x.w * scale;
    } else {
        vpt = 2;
        float2 x = ((const float2*)p)[t];
        v[0] = x.x * scale; v[1] = x.y * scale; v[2] = -3.4e38f; v[3] = -3.4e38f;
    }
    float mx = fmaxf(fmaxf(v[0], v[1]), fmaxf(v[2], v[3]));
#pragma unroll
    for (int o = 32; o; o >>= 1) mx = fmaxf(mx, __shfl_xor(mx, o));
    __shared__ float sm[4];
    const int wv = t >> 6, ln = t & 63;
    if (ln == 0) sm[wv] = mx;
    __syncthreads();
    mx = fmaxf(fmaxf(sm[0], sm[1]), fmaxf(sm[2], sm[3]));
    float sum = 0.f;
    for (int i = 0; i < vpt; ++i) { v[i] = expf(v[i] - mx); sum += v[i]; }
#pragma unroll
    for (int o = 32; o; o >>= 1) sum += __shfl_xor(sum, o);
    __shared__ float ss[4];
    if (ln == 0) ss[wv] = sum;
    __syncthreads();
    sum = ss[0] + ss[1] + ss[2] + ss[3];
    const float inv = 1.f / sum;
    if (cols == 1024) {
        float q0 = v[0] * inv, q1 = v[1] * inv, q2 = v[2] * inv, q3 = v[3] * inv;
        u16 h0 = f2bf(q0), h1 = f2bf(q1), h2 = f2bf(q2), h3 = f2bf(q3);
        uint2 hh; hh.x = (unsigned)h0 | ((unsigned)h1 << 16); hh.y = (unsigned)h2 | ((unsigned)h3 << 16);
        ((uint2*)php)[t] = hh;
        u16 l0 = f2bf(q0 - bf2f(h0)), l1 = f2bf(q1 - bf2f(h1));
        u16 l2 = f2bf(q2 - bf2f(h2)), l3 = f2bf(q3 - bf2f(h3));
        uint2 ll; ll.x = (unsigned)l0 | ((unsigned)l1 << 16); ll.y = (unsigned)l2 | ((unsigned)l3 << 16);
        ((uint2*)plp)[t] = ll;
    } else {
        float q0 = v[0] * inv, q1 = v[1] * inv;
        u16 h0 = f2bf(q0), h1 = f2bf(q1);
        ((unsigned*)php)[t] = (unsigned)h0 | ((unsigned)h1 << 16);
        u16 l0 = f2bf(q0 - bf2f(h0)), l1 = f2bf(q1 - bf2f(h1));
        ((unsigned*)plp)[t] = (unsigned)l0 | ((unsigned)l1 << 16);
    }
}

// ---------------------------------------------------------------------------
__global__ __launch_bounds__(256) void add_rmsnorm(
    const float* __restrict__ a, const float* __restrict__ b, const float* __restrict__ g,
    float* __restrict__ xo, u16* __restrict__ xh, u16* __restrict__ xl)
{
    const long row = blockIdx.x;
    const int t = threadIdx.x;
    const float* pa = a + row * D_;
    const float* pb = b + row * D_;
    float v[4]; double ssq = 0.0;
#pragma unroll
    for (int i = 0; i < 4; ++i) {
        int c = t + (i << 8);
        v[i] = pa[c] + pb[c];
        ssq += (double)v[i] * v[i];
    }
#pragma unroll
    for (int o = 32; o; o >>= 1) ssq += __shfl_xor(ssq, o);
    __shared__ double sd[4];
    if ((t & 63) == 0) sd[t >> 6] = ssq;
    __syncthreads();
    ssq = sd[0] + sd[1] + sd[2] + sd[3];
    const float rs = (float)(1.0 / sqrt(ssq * (1.0 / 1024.0) + 1e-6));
#pragma unroll
    for (int i = 0; i < 4; ++i) {
        int c = t + (i << 8);
        float o = v[i] * rs * g[c];
        xo[row * D_ + c] = o;
        if (xh) {
            u16 h = f2bf(o);
            xh[row * D_ + c] = h;
            if (xl) xl[row * D_ + c] = f2bf(o - bf2f(h));
        }
    }
}

// ---------------------------------------------------------------------------
__global__ __launch_bounds__(256) void router_topk(
    const float* __restrict__ x2, const float* __restrict__ Wg,
    float* __restrict__ outw, float* __restrict__ outi,
    int* __restrict__ idx, float* __restrict__ tokw, int* __restrict__ counts, int T)
{
    const int wid = (int)((blockIdx.x * 256 + threadIdx.x) >> 6);
    const int lane = threadIdx.x & 63;
    if (wid >= T) return;
    float acc[NE];
#pragma unroll
    for (int e = 0; e < NE; ++e) acc[e] = 0.f;
    const float* xr = x2 + (long)wid * D_;
    for (int i = 0; i < 16; ++i) {
        float xv = xr[i * 64 + lane];
        const float* wr = Wg + (long)(i * 64 + lane) * NE;
#pragma unroll
        for (int e = 0; e < NE; ++e) acc[e] += xv * wr[e];
    }
#pragma unroll
    for (int e = 0; e < NE; ++e)
#pragma unroll
        for (int o = 32; o; o >>= 1) acc[e] += __shfl_xor(acc[e], o);
    if (lane == 0) {
        float m = acc[0];
#pragma unroll
        for (int e = 1; e < NE; ++e) m = fmaxf(m, acc[e]);
        float p[NE], s = 0.f;
#pragma unroll
        for (int e = 0; e < NE; ++e) { p[e] = expf(acc[e] - m); s += p[e]; }
        const float invs = 1.f / s;
#pragma unroll
        for (int e = 0; e < NE; ++e) p[e] *= invs;
        int e0 = 0;
#pragma unroll
        for (int e = 1; e < NE; ++e) if (p[e] > p[e0]) e0 = e;
        int e1 = (e0 == 0) ? 1 : 0;
#pragma unroll
        for (int e = 0; e < NE; ++e) if (e != e0 && e != e1 && p[e] > p[e1]) e1 = e;
        float w0 = p[e0], w1 = p[e1];
        const float sw = 1.f / (w0 + w1);
        w0 *= sw; w1 *= sw;
        outw[2 * wid] = w0;      outw[2 * wid + 1] = w1;
        outi[2 * wid] = (float)e0; outi[2 * wid + 1] = (float)e1;
        idx[2 * wid] = e0;       idx[2 * wid + 1] = e1;
        tokw[2 * wid] = w0;      tokw[2 * wid + 1] = w1;
        atomicAdd(&counts[e0], 1);
        atomicAdd(&counts[e1], 1);
    }
}

__global__ void scan8(const int* __restrict__ counts, int* __restrict__ seg, int* __restrict__ cursor)
{
    if (threadIdx.x == 0 && blockIdx.x == 0) {
        int a = 0;
        for (int e = 0; e < NE; ++e) { seg[e] = a; cursor[e] = a; a += counts[e]; }
        seg[NE] = a;
    }
}

__global__ __launch_bounds__(256) void scatter_slots(
    const int* __restrict__ idx, int* __restrict__ cursor,
    int* __restrict__ row_token, int* __restrict__ slot_of, int T)
{
    const int t = blockIdx.x * 256 + threadIdx.x;
    if (t >= T) return;
#pragma unroll
    for (int k = 0; k < 2; ++k) {
        const int e = idx[2 * t + k];
        const int pos = atomicAdd(&cursor[e], 1);
        row_token[pos] = t;
        slot_of[2 * t + k] = pos;
    }
}

__global__ __launch_bounds__(256) void gather_bf16(
    const float* __restrict__ x2, const int* __restrict__ row_token, u16* __restrict__ Xg)
{
    const int r = blockIdx.x;
    const int t = threadIdx.x;
    const float* src = x2 + (long)row_token[r] * D_ + t * 4;
    float4 v = *(const float4*)src;
    uint2 oo;
    oo.x = (unsigned)f2bf(v.x) | ((unsigned)f2bf(v.y) << 16);
    oo.y = (unsigned)f2bf(v.z) | ((unsigned)f2bf(v.w) << 16);
    *(uint2*)(Xg + (long)r * D_ + t * 4) = oo;
}

// ---------------------------------------------------------------------------
__global__ __launch_bounds__(256) void combine_rmsnorm(
    const float* __restrict__ Y, const int* __restrict__ slot_of, const float* __restrict__ tokw,
    const float* __restrict__ x2, const float* __restrict__ g, float* __restrict__ out)
{
    const long tr = blockIdx.x;
    const int t = threadIdx.x;
    const int s0 = slot_of[2 * tr], s1 = slot_of[2 * tr + 1];
    const float w0 = tokw[2 * tr], w1 = tokw[2 * tr + 1];
    const float* y0 = Y + (long)s0 * D_;
    const float* y1 = Y + (long)s1 * D_;
    const float* xr = x2 + tr * D_;
    float v[4]; double ssq = 0.0;
#pragma unroll
    for (int i = 0; i < 4; ++i) {
        int c = t + (i << 8);
        v[i] = w0 * y0[c] + w1 * y1[c] + xr[c];
        ssq += (double)v[i] * v[i];
    }
#pragma unroll
    for (int o = 32; o; o >>= 1) ssq += __shfl_xor(ssq, o);
    __shared__ double sd[4];
    if ((t & 63) == 0) sd[t >> 6] = ssq;
    __syncthreads();
    ssq = sd[0] + sd[1] + sd[2] + sd[3];
    const float rs = (float)(1.0 / sqrt(ssq * (1.0 / 1024.0) + 1e-6));
#pragma unroll
    for (int i = 0; i < 4; ++i) {
        int c = t + (i << 8);
        out[tr * D_ + c] = v[i] * rs * g[c];
    }
}

__global__ void sentinel(float* o) { o[0] = 12345.0f; }

// ---------------------------------------------------------------------------
extern "C" void kernel_launch(void* const* d_in, const int* in_sizes, int n_in,
                              void* d_out, int out_size, void* d_ws, size_t ws_size,
                              hipStream_t stream)
{
    const float* dec = (const float*)d_in[0];
    const float* te  = (const float*)d_in[1];
    const float* Win[8] = { (const float*)d_in[2], (const float*)d_in[3], (const float*)d_in[4],
                            (const float*)d_in[5], (const float*)d_in[6], (const float*)d_in[7],
                            (const float*)d_in[8], (const float*)d_in[9] };
    const float* g  = (const float*)d_in[10];
    const float* Wg = (const float*)d_in[11];
    const float* W1 = (const float*)d_in[12];
    const float* W2 = (const float*)d_in[13];
    float* outw = (float*)d_out;
    float* outi = outw + 2 * TDEC;
    float* outx = outw + 4 * TDEC;

    char* ws = (char*)d_ws;
    size_t off = 0;
    auto A = [&](size_t bytes) -> char* {
        char* p = ws + off;
        off += (bytes + 255) & ~(size_t)255;
        return p;
    };

    // ---- persistent region ----
    u16* decH = (u16*)A((size_t)TDEC * D_ * 2);
    u16* decL = (u16*)A((size_t)TDEC * D_ * 2);
    u16* teH  = (u16*)A((size_t)TTXT * D_ * 2);
    u16* teL  = (u16*)A((size_t)TTXT * D_ * 2);
    u16* wtHall = (u16*)A((size_t)8 * D_ * D_ * 2);   // 8 slabs: Wq1,Wk1,Wv1,Wo1,Wq2,Wk2,Wv2,Wo2 (transposed)
    u16* wtLall = (u16*)A((size_t)8 * D_ * D_ * 2);
    float* x1f = (float*)A((size_t)TDEC * D_ * 4);
    float* x2f = (float*)A((size_t)TDEC * D_ * 4);
    float* tokw = (float*)A(NSLOT * 4);
    int* idx    = (int*)A(NSLOT * 4);
    int* counts = (int*)A(256);
    int* seg    = (int*)A(256);
    int* cursor = (int*)A(256);
    int* row_token = (int*)A(NSLOT * 4);
    int* slot_of   = (int*)A(NSLOT * 4);

    // ---- shared region R: attention view ----
    const size_t Rbase = off;
    float* scores = (float*)A((size_t)NH * SDEC * SDEC * 4);
    u16* PH = (u16*)A((size_t)NH * SDEC * SDEC * 2);
    u16* PL = (u16*)A((size_t)NH * SDEC * SDEC * 2);
    u16* qkvH = (u16*)A((size_t)TDEC * 3 * D_ * 2);   // [4096][3072] Q|K|V
    u16* qkvL = (u16*)A((size_t)TDEC * 3 * D_ * 2);
    u16* q2H  = (u16*)A((size_t)TDEC * D_ * 2);
    u16* q2L  = (u16*)A((size_t)TDEC * D_ * 2);
    u16* kv2H = (u16*)A((size_t)TTXT * 2 * D_ * 2);   // [2048][2048] K|V
    u16* kv2L = (u16*)A((size_t)TTXT * 2 * D_ * 2);
    u16* vTH = (u16*)A((size_t)TDEC * D_ * 2);
    u16* vTL = (u16*)A((size_t)TDEC * D_ * 2);
    u16* aoH = (u16*)A((size_t)TDEC * D_ * 2);
    u16* aoL = (u16*)A((size_t)TDEC * D_ * 2);
    u16* x1H = (u16*)A((size_t)TDEC * D_ * 2);
    u16* x1L = (u16*)A((size_t)TDEC * D_ * 2);
    float* of = (float*)A((size_t)TDEC * D_ * 4);
    const size_t attnEnd = off;

    // ---- shared region R: MoE view (overlays attention view) ----
    off = Rbase;
    u16* W1T  = (u16*)A((size_t)NE * DFF * D_ * 2);
    u16* W2T  = (u16*)A((size_t)NE * D_ * DFF * 2);
    u16* Xg   = (u16*)A((size_t)(NSLOT + 128) * D_ * 2);
    u16* Hb   = (u16*)A((size_t)(NSLOT + 128) * DFF * 2);
    float* Yseg = (float*)A((size_t)NSLOT * D_ * 4);
    const size_t needed = (off > attnEnd ? off : attnEnd);

    if (ws_size < needed) {
        sentinel<<<1, 1, 0, stream>>>(outw);
        return;
    }

    const dim3 blk(256);

    // ---- phase 0: input splits + attention weight transposes ----
    split2k<<<dim3((TDEC * D_) / 1024), blk, 0, stream>>>(dec, decH, decL, (long)TDEC * D_);
    split2k<<<dim3((TTXT * D_) / 1024), blk, 0, stream>>>(te, teH, teL, (long)TTXT * D_);
    for (int i = 0; i < 8; ++i)
        transpose_split<<<dim3(32, 32, 1), blk, 0, stream>>>(Win[i],
            wtHall + (size_t)i * D_ * D_, wtLall + (size_t)i * D_ * D_,
            D_, D_, D_, 0, 0, 1, D_, 0);

    // ---- phase 1: self-attention ----
    // merged QKV: [4096,3072] = dec x [Wq1|Wk1|Wv1]
    gemm_bt<1, 1, 128><<<dim3(24, 32, 1), blk, 0, stream>>>(decH, decL, wtHall, wtLall,
        nullptr, qkvH, qkvL, TDEC, 3 * D_, D_, D_, D_, 3 * D_, 0, 0, 0);
    transpose_split_hl<<<dim3(2, 32, BB * NH), blk, 0, stream>>>(qkvH + 2 * D_, qkvL + 2 * D_,
        vTH, vTL, SDEC, DHD, 3 * D_, (long)SDEC * 3 * D_, DHD, NH, SDEC, (long)DHD * SDEC);

    for (int b = 0; b < BB; ++b) {
        const long qo3 = (long)b * SDEC * 3 * D_;
        const long qo  = (long)b * SDEC * D_;
        gemm_bt<1, 0, 128><<<dim3(8, 8, NH), blk, 0, stream>>>(
            qkvH + qo3, qkvL + qo3, qkvH + qo3 + D_, qkvL + qo3 + D_,
            scores, nullptr, nullptr, SDEC, SDEC, DHD, 3 * D_, 3 * D_, SDEC,
            DHD, DHD, (long)SDEC * SDEC);
        softmax_split<<<dim3(NH * SDEC), blk, 0, stream>>>(scores, PH, PL, SDEC, 0.125f);
        gemm_bt<1, 1, 64><<<dim3(1, 8, NH), blk, 0, stream>>>(PH, PL,
            vTH + (long)b * NH * DHD * SDEC, vTL + (long)b * NH * DHD * SDEC,
            nullptr, aoH + qo, aoL + qo, SDEC, DHD, SDEC, SDEC, SDEC, D_,
            (long)SDEC * SDEC, (long)DHD * SDEC, DHD);
    }
    gemm_bt<1, 0, 128><<<dim3(8, 32, 1), blk, 0, stream>>>(aoH, aoL,
        wtHall + (size_t)3 * D_ * D_, wtLall + (size_t)3 * D_ * D_,
        of, nullptr, nullptr, TDEC, D_, D_, D_, D_, D_, 0, 0, 0);
    add_rmsnorm<<<dim3(TDEC), blk, 0, stream>>>(of, dec, g, x1f, x1H, x1L);

    // ---- phase 2: cross-attention ----
    gemm_bt<1, 1, 128><<<dim3(8, 32, 1), blk, 0, stream>>>(x1H, x1L,
        wtHall + (size_t)4 * D_ * D_, wtLall + (size_t)4 * D_ * D_,
        nullptr, q2H, q2L, TDEC, D_, D_, D_, D_, D_, 0, 0, 0);
    // merged KV: [2048,2048] = te x [Wk2|Wv2]
    gemm_bt<1, 1, 128><<<dim3(16, 16, 1), blk, 0, stream>>>(teH, teL,
        wtHall + (size_t)5 * D_ * D_, wtLall + (size_t)5 * D_ * D_,
        nullptr, kv2H, kv2L, TTXT, 2 * D_, D_, D_, D_, 2 * D_, 0, 0, 0);
    transpose_split_hl<<<dim3(2, 16, BB * NH), blk, 0, stream>>>(kv2H + D_, kv2L + D_,
        vTH, vTL, STXT, DHD, 2 * D_, (long)STXT * 2 * D_, DHD, NH, STXT, (long)DHD * STXT);

    for (int b = 0; b < BB; ++b) {
        const long qo  = (long)b * SDEC * D_;
        const long ko2 = (long)b * STXT * 2 * D_;
        gemm_bt<1, 0, 128><<<dim3(4, 8, NH), blk, 0, stream>>>(
            q2H + qo, q2L + qo, kv2H + ko2, kv2L + ko2,
            scores, nullptr, nullptr, SDEC, STXT, DHD, D_, 2 * D_, STXT,
            DHD, DHD, (long)SDEC * STXT);
        softmax_split<<<dim3(NH * SDEC), blk, 0, stream>>>(scores, PH, PL, STXT, 0.125f);
        gemm_bt<1, 1, 64><<<dim3(1, 8, NH), blk, 0, stream>>>(PH, PL,
            vTH + (long)b * NH * DHD * STXT, vTL + (long)b * NH * DHD * STXT,
            nullptr, aoH + qo, aoL + qo, SDEC, DHD, STXT, STXT, STXT, D_,
            (long)SDEC * STXT, (long)DHD * STXT, DHD);
    }
    gemm_bt<1, 0, 128><<<dim3(8, 32, 1), blk, 0, stream>>>(aoH, aoL,
        wtHall + (size_t)7 * D_ * D_, wtLall + (size_t)7 * D_ * D_,
        of, nullptr, nullptr, TDEC, D_, D_, D_, D_, D_, 0, 0, 0);
    add_rmsnorm<<<dim3(TDEC), blk, 0, stream>>>(of, x1f, g, x2f, nullptr, nullptr);

    // ---- phase 3: router + expert bucketing ----
    hipMemsetAsync(counts, 0, 32, stream);
    router_topk<<<dim3(TDEC / 4), blk, 0, stream>>>(x2f, Wg, outw, outi, idx, tokw, counts, TDEC);
    scan8<<<1, 64, 0, stream>>>(counts, seg, cursor);
    scatter_slots<<<dim3(TDEC / 256), blk, 0, stream>>>(idx, cursor, row_token, slot_of, TDEC);
    gather_bf16<<<dim3(NSLOT), blk, 0, stream>>>(x2f, row_token, Xg);

    // ---- phase 4: MoE FFN (bf16, expert->XCD affinity) + final norm ----
    transpose_split<<<dim3(DFF / 32, D_ / 32, NE), blk, 0, stream>>>(W1, W1T, nullptr,
        D_, DFF, DFF, (long)D_ * DFF, 0, 1, D_, (long)DFF * D_);
    transpose_split<<<dim3(D_ / 32, DFF / 32, NE), blk, 0, stream>>>(W2, W2T, nullptr,
        DFF, D_, D_, (long)D_ * DFF, 0, 1, DFF, (long)D_ * DFF);
    gemm_moe<2><<<dim3(8 * MAXYT * (DFF / 128)), blk, 0, stream>>>(Xg, W1T,
        nullptr, Hb, DFF, D_, DFF, seg, (long)DFF * D_, DFF / 128);
    gemm_moe<0><<<dim3(8 * MAXYT * (D_ / 128)), blk, 0, stream>>>(Hb, W2T,
        Yseg, nullptr, D_, DFF, D_, seg, (long)D_ * DFF, D_ / 128);
    combine_rmsnorm<<<dim3(TDEC), blk, 0, stream>>>(Yseg, slot_of, tokw, x2f, g, outx);

    (void)in_sizes; (void)n_in; (void)out_size;
}

// Round 4
// 1471.692 us; speedup vs baseline: 1.4108x; 1.0111x over previous
//
#include <hip/hip_runtime.h>
#include <stdint.h>

#define D_    1024
#define BB    4
#define SDEC  1024
#define STXT  512
#define TDEC  4096
#define TTXT  2048
#define NH    16
#define DHD   64
#define NE    8
#define DFF   4096
#define NSLOT 8192
#define MAXYT2 16   // 256-row tiles per expert; covers worst case (4096 slots)

using u16 = unsigned short;
typedef __attribute__((ext_vector_type(8))) short bf16x8;
typedef __attribute__((ext_vector_type(4))) float f32x4;

__device__ __forceinline__ float bf2f(u16 h) {
    union { unsigned int u; float f; } x; x.u = ((unsigned int)h) << 16; return x.f;
}
__device__ __forceinline__ u16 f2bf(float f) {
    union { float f; unsigned int u; } x; x.f = f;
    unsigned int lsb = (x.u >> 16) & 1u;
    return (u16)((x.u + 0x7fffu + lsb) >> 16);
}

// async global->LDS, 16B per lane, linear LDS dest (wave-uniform base + lane*16)
__device__ __forceinline__ void gld16(const u16* g, u16* l) {
    __builtin_amdgcn_global_load_lds((const __attribute__((address_space(1))) void*)g,
                                     (__attribute__((address_space(3))) void*)l,
                                     16, 0, 0);
}

constexpr int BM = 128, BK = 32;

// ---------------------------------------------------------------------------
// Generic tiled GEMM (128-tile, 2-barrier): C[M,N] = A[M,K] * BT[N,K]^T.
// SPLIT=1: 3-pass split emulation. EPI: 0=f32, 1=split store, 2=relu+bf16.
// ---------------------------------------------------------------------------
template<int SPLIT, int EPI, int BROWS>
__global__ __launch_bounds__(256) void gemm_bt(
    const u16* __restrict__ AH, const u16* __restrict__ AL,
    const u16* __restrict__ BH, const u16* __restrict__ BL,
    float* __restrict__ Cf, u16* __restrict__ CH, u16* __restrict__ CL,
    int M, int N, int K, int lda, int ldb, int ldc,
    long strA, long strB, long strC)
{
    constexpr int WM = (BROWS == 64) ? 2 : 4;
    constexpr int ASZ = BM * BK, BSZ = BROWS * BK;
    __shared__ u16 smem[(SPLIT ? 2 : 1) * (ASZ + BSZ)];
    u16* sAH = smem;
    u16* sBH = smem + ASZ;
    u16* sAL = SPLIT ? smem + ASZ + BSZ : nullptr;
    u16* sBL = SPLIT ? smem + 2 * ASZ + BSZ : nullptr;

    const int z = blockIdx.z;
    const long zA = (long)z * strA, zB = (long)z * strB, zC = (long)z * strC;

    const int tileM = blockIdx.y * BM, tileN = blockIdx.x * BROWS;
    const int t = threadIdx.x;
    const int sr = t >> 2;
    const int sc = (t & 3) << 3;
    const u16* pA = AH + zA + (long)(tileM + sr) * lda + sc;
    const u16* pB = BH + zB + (long)(tileN + sr) * ldb + sc;
    const u16* pAl = nullptr; const u16* pBl = nullptr;
    if constexpr (SPLIT) {
        pAl = AL + zA + (long)(tileM + sr) * lda + sc;
        pBl = BL + zB + (long)(tileN + sr) * ldb + sc;
    }
    const long hA = 64L * lda, hB = 64L * ldb;

    const int lane = t & 63;
    const int wv = t >> 6;
    const int wr = (BROWS == 64) ? (wv << 5) : ((wv >> 1) << 6);
    const int wc = (BROWS == 64) ? 0 : ((wv & 1) << 6);
    const int fr = lane & 15, kg = lane >> 4;

    f32x4 acc[WM][4];
    const f32x4 vzero = {0.f, 0.f, 0.f, 0.f};
#pragma unroll
    for (int m = 0; m < WM; ++m)
#pragma unroll
        for (int n = 0; n < 4; ++n) acc[m][n] = vzero;

    for (int k0 = 0; k0 < K; k0 += BK) {
        gld16(pA + k0,      sAH + t * 8);
        gld16(pA + k0 + hA, sAH + 2048 + t * 8);
        gld16(pB + k0,      sBH + t * 8);
        if constexpr (BROWS == 128) gld16(pB + k0 + hB, sBH + 2048 + t * 8);
        if constexpr (SPLIT) {
            gld16(pAl + k0,      sAL + t * 8);
            gld16(pAl + k0 + hA, sAL + 2048 + t * 8);
            gld16(pBl + k0,      sBL + t * 8);
            if constexpr (BROWS == 128) gld16(pBl + k0 + hB, sBL + 2048 + t * 8);
        }
        __syncthreads();

        bf16x8 fa[WM], fb[4], fal[WM], fbl[4];
#pragma unroll
        for (int m = 0; m < WM; ++m) {
            fa[m] = *(const bf16x8*)&sAH[(wr + m * 16 + fr) * BK + (kg << 3)];
            if constexpr (SPLIT) fal[m] = *(const bf16x8*)&sAL[(wr + m * 16 + fr) * BK + (kg << 3)];
        }
#pragma unroll
        for (int n = 0; n < 4; ++n) {
            fb[n] = *(const bf16x8*)&sBH[(wc + n * 16 + fr) * BK + (kg << 3)];
            if constexpr (SPLIT) fbl[n] = *(const bf16x8*)&sBL[(wc + n * 16 + fr) * BK + (kg << 3)];
        }
#pragma unroll
        for (int m = 0; m < WM; ++m)
#pragma unroll
            for (int n = 0; n < 4; ++n) {
                acc[m][n] = __builtin_amdgcn_mfma_f32_16x16x32_bf16(fa[m], fb[n], acc[m][n], 0, 0, 0);
                if constexpr (SPLIT) {
                    acc[m][n] = __builtin_amdgcn_mfma_f32_16x16x32_bf16(fa[m],  fbl[n], acc[m][n], 0, 0, 0);
                    acc[m][n] = __builtin_amdgcn_mfma_f32_16x16x32_bf16(fal[m], fb[n],  acc[m][n], 0, 0, 0);
                }
            }
        __syncthreads();
    }

#pragma unroll
    for (int m = 0; m < WM; ++m) {
        const int r0 = tileM + wr + m * 16 + (kg << 2);
#pragma unroll
        for (int n = 0; n < 4; ++n) {
            const int col = tileN + wc + n * 16 + fr;
            if (col >= N) continue;
#pragma unroll
            for (int i = 0; i < 4; ++i) {
                const int r = r0 + i;
                if (r >= M) continue;
                const float v = acc[m][n][i];
                const long off = zC + (long)r * ldc + col;
                if constexpr (EPI == 0) {
                    Cf[off] = v;
                } else if constexpr (EPI == 1) {
                    const u16 h = f2bf(v);
                    CH[off] = h;
                    CL[off] = f2bf(v - bf2f(h));
                } else {
                    CH[off] = f2bf(fmaxf(v, 0.f));
                }
            }
        }
    }
}

// ---------------------------------------------------------------------------
// MoE 256x256 pipelined GEMM (counted-vmcnt 4-slot LDS ring, XOR-swizzled).
//   - BK=32, 512 threads = 8 waves (2M x 4N), per-wave 128x64 output.
//   - LDS: A ring 4 x 16KB + B ring 4 x 16KB = 128KB. Slot = 256 rows x 32 cols.
//   - Swizzle (G4): element offset ^= (row&3)<<3, applied on ds_read AND inverse
//     on the global source of global_load_lds (linear LDS dest) -> uniform banks.
//   - Pipeline: iter t: stage K(t+3); ds_read K(t+1) frags; MFMA K(t) (regs);
//     lgkmcnt(0); vmcnt(4) [tail: 0]; s_barrier.  Slot reuse distance = 4.
//   - Expert segmentation: rows in [seg[e], seg[e+1]); A padded >=256 rows.
//   - XCD affinity: e = blockIdx.x & 7.
// ---------------------------------------------------------------------------
template<int EPI>
__global__ __launch_bounds__(512, 2) void gemm256_moe(
    const u16* __restrict__ Ag, const u16* __restrict__ BTbase,
    float* __restrict__ Cf, u16* __restrict__ CH,
    int N, int K, int ldc, const int* __restrict__ seg, long btStride)
{
    __shared__ u16 smem[65536];   // 128 KiB

    const int bid = blockIdx.x;
    const int e = bid & 7;
    const int rem = bid >> 3;
    const int yt = rem % MAXYT2;
    const int xt = rem / MAXYT2;

    const int s0 = seg[e], s1 = seg[e + 1];
    const int rowbase = s0 + yt * 256;
    if (rowbase >= s1) return;
    const u16* BT = BTbase + (long)e * btStride;
    const int tileN = xt * 256;

    const int t = threadIdx.x;
    const int lane = t & 63;
    const int wv = t >> 6;
    const int wmr = wv >> 2;        // 0..1 (M half)
    const int wnc = wv & 3;         // 0..3 (N quarter)
    const int fr = lane & 15, kg = lane >> 4;
    const int kk8 = ((kg ^ (fr & 3)) << 3);   // swizzled k-chunk byte-group (elems)

    // staging source decode (inverse swizzle): thread t stages chunks {t, t+512}
    const int q0 = t ^ ((t >> 2) & 3);
    const int q1 = (t + 512) ^ (((t + 512) >> 2) & 3);
    const long ofsA0 = (long)(q0 >> 2) * K + (q0 & 3) * 8;
    const long ofsA1 = (long)(q1 >> 2) * K + (q1 & 3) * 8;
    const long ofsB0 = ofsA0, ofsB1 = ofsA1;   // same geometry
    const u16* pAs = Ag + (long)rowbase * K;
    const u16* pBs = BT + (long)tileN * K;

#define STAGE4(ks) { const int s_ = (ks) & 3; const long k0_ = (long)(ks) * 32; \
    gld16(pAs + k0_ + ofsA0, smem + s_ * 8192 + t * 8); \
    gld16(pAs + k0_ + ofsA1, smem + s_ * 8192 + 4096 + t * 8); \
    gld16(pBs + k0_ + ofsB0, smem + 32768 + s_ * 8192 + t * 8); \
    gld16(pBs + k0_ + ofsB1, smem + 32768 + s_ * 8192 + 4096 + t * 8); }

#define READF(AA, BB, ks) { const int s_ = (ks) & 3; \
    const u16* sa_ = smem + s_ * 8192; \
    const u16* sb_ = smem + 32768 + s_ * 8192; \
    _Pragma("unroll") \
    for (int m_ = 0; m_ < 8; ++m_) \
        AA[m_] = *(const bf16x8*)&sa_[(wmr * 128 + m_ * 16 + fr) * 32 + kk8]; \
    _Pragma("unroll") \
    for (int n_ = 0; n_ < 4; ++n_) \
        BB[n_] = *(const bf16x8*)&sb_[(wnc * 64 + n_ * 16 + fr) * 32 + kk8]; }

#define MFMAS(AA, BB) { __builtin_amdgcn_s_setprio(1); \
    _Pragma("unroll") \
    for (int m_ = 0; m_ < 8; ++m_) \
    _Pragma("unroll") \
    for (int n_ = 0; n_ < 4; ++n_) \
        acc[m_][n_] = __builtin_amdgcn_mfma_f32_16x16x32_bf16(AA[m_], BB[n_], acc[m_][n_], 0, 0, 0); \
    __builtin_amdgcn_s_setprio(0); }

#define ENDBAR(tt_) { asm volatile("s_waitcnt lgkmcnt(0)" ::: "memory"); \
    if ((tt_) >= NT - 3) { asm volatile("s_waitcnt vmcnt(0)" ::: "memory"); } \
    else                 { asm volatile("s_waitcnt vmcnt(4)" ::: "memory"); } \
    __builtin_amdgcn_s_barrier(); }

    f32x4 acc[8][4];
    const f32x4 vzero = {0.f, 0.f, 0.f, 0.f};
#pragma unroll
    for (int m = 0; m < 8; ++m)
#pragma unroll
        for (int n = 0; n < 4; ++n) acc[m][n] = vzero;

    const int NT = K >> 5;   // K-steps of 32; NT even, >= 4

    // prologue: stage K0..K2; wait K0,K1 resident; read K0 frags
    STAGE4(0); STAGE4(1); STAGE4(2);
    asm volatile("s_waitcnt vmcnt(4)" ::: "memory");
    __builtin_amdgcn_s_barrier();

    bf16x8 a0[8], b0[4], a1[8], b1[4];
    READF(a0, b0, 0);

    for (int tt = 0; tt < NT; tt += 2) {
        // even step: compute K(tt) from set0; read K(tt+1) into set1; stage K(tt+3)
        if (tt + 3 < NT) STAGE4(tt + 3);
        if (tt + 1 < NT) READF(a1, b1, tt + 1);
        MFMAS(a0, b0);
        ENDBAR(tt);
        // odd step
        const int tu = tt + 1;
        if (tu + 3 < NT) STAGE4(tu + 3);
        if (tu + 1 < NT) READF(a0, b0, tu + 1);
        MFMAS(a1, b1);
        ENDBAR(tu);
    }

#undef STAGE4
#undef READF
#undef MFMAS
#undef ENDBAR

    // epilogue: C/D layout col=lane&15, row=kg*4+i per 16x16 fragment
#pragma unroll
    for (int m = 0; m < 8; ++m) {
        const int r0 = rowbase + wmr * 128 + m * 16 + (kg << 2);
#pragma unroll
        for (int n = 0; n < 4; ++n) {
            const int col = tileN + wnc * 64 + n * 16 + fr;
#pragma unroll
            for (int i = 0; i < 4; ++i) {
                const int r = r0 + i;
                if (r >= s1) continue;
                const float v = acc[m][n][i];
                const long off = (long)r * ldc + col;
                if constexpr (EPI == 0) Cf[off] = v;
                else                    CH[off] = f2bf(fmaxf(v, 0.f));
            }
        }
    }
}

// ---------------------------------------------------------------------------
__global__ __launch_bounds__(256) void split2k(const float* __restrict__ in,
                                               u16* __restrict__ oh, u16* __restrict__ ol, long n)
{
    long i = ((long)blockIdx.x * 256 + threadIdx.x) * 4;
    if (i >= n) return;
    float4 v = *(const float4*)(in + i);
    u16 h0 = f2bf(v.x), h1 = f2bf(v.y), h2 = f2bf(v.z), h3 = f2bf(v.w);
    uint2 oo;
    oo.x = (unsigned)h0 | ((unsigned)h1 << 16);
    oo.y = (unsigned)h2 | ((unsigned)h3 << 16);
    *(uint2*)(oh + i) = oo;
    if (ol) {
        u16 l0 = f2bf(v.x - bf2f(h0)), l1 = f2bf(v.y - bf2f(h1));
        u16 l2 = f2bf(v.z - bf2f(h2)), l3 = f2bf(v.w - bf2f(h3));
        uint2 ll;
        ll.x = (unsigned)l0 | ((unsigned)l1 << 16);
        ll.y = (unsigned)l2 | ((unsigned)l3 << 16);
        *(uint2*)(ol + i) = ll;
    }
}

// ---------------------------------------------------------------------------
__global__ __launch_bounds__(256) void transpose_split(
    const float* __restrict__ in, u16* __restrict__ oh, u16* __restrict__ ol,
    int R, int C, int ild, long ibs1, long ibs2, int nb2, int old_, long obs)
{
    __shared__ float tile[32][33];
    const int z = blockIdx.z;
    const float* ip = in + (long)(z / nb2) * ibs1 + (long)(z % nb2) * ibs2;
    u16* ohp = oh + (long)z * obs;
    u16* olp = ol ? ol + (long)z * obs : nullptr;
    const int c0 = blockIdx.x * 32, r0 = blockIdx.y * 32;
    const int tx = threadIdx.x & 31, ty = threadIdx.x >> 5;
    for (int i = ty; i < 32; i += 8) {
        int r = r0 + i, c = c0 + tx;
        tile[i][tx] = (r < R && c < C) ? ip[(long)r * ild + c] : 0.f;
    }
    __syncthreads();
    for (int i = ty; i < 32; i += 8) {
        int oc = c0 + i, orr = r0 + tx;
        if (oc < C && orr < R) {
            float v = tile[tx][i];
            u16 h = f2bf(v);
            ohp[(long)oc * old_ + orr] = h;
            if (olp) olp[(long)oc * old_ + orr] = f2bf(v - bf2f(h));
        }
    }
}

// ---------------------------------------------------------------------------
__global__ __launch_bounds__(256) void transpose_split_hl(
    const u16* __restrict__ inH, const u16* __restrict__ inL,
    u16* __restrict__ oh, u16* __restrict__ ol,
    int R, int C, int ild, long ibs1, long ibs2, int nb2, int old_, long obs)
{
    __shared__ float tile[32][33];
    const int z = blockIdx.z;
    const long base = (long)(z / nb2) * ibs1 + (long)(z % nb2) * ibs2;
    u16* ohp = oh + (long)z * obs;
    u16* olp = ol + (long)z * obs;
    const int c0 = blockIdx.x * 32, r0 = blockIdx.y * 32;
    const int tx = threadIdx.x & 31, ty = threadIdx.x >> 5;
    for (int i = ty; i < 32; i += 8) {
        int r = r0 + i, c = c0 + tx;
        float v = 0.f;
        if (r < R && c < C) {
            const long o = base + (long)r * ild + c;
            v = bf2f(inH[o]) + bf2f(inL[o]);
        }
        tile[i][tx] = v;
    }
    __syncthreads();
    for (int i = ty; i < 32; i += 8) {
        int oc = c0 + i, orr = r0 + tx;
        if (oc < C && orr < R) {
            float v = tile[tx][i];
            u16 h = f2bf(v);
            ohp[(long)oc * old_ + orr] = h;
            olp[(long)oc * old_ + orr] = f2bf(v - bf2f(h));
        }
    }
}

// ---------------------------------------------------------------------------
__global__ __launch_bounds__(256) void softmax_split(
    const float* __restrict__ s, u16* __restrict__ ph, u16* __restrict__ pl,
    int cols, float scale)
{
    const float* p = s + (long)blockIdx.x * cols;
    u16* php = ph + (long)blockIdx.x * cols;
    u16* plp = pl + (long)blockIdx.x * cols;
    const int t = threadIdx.x;
    float v[4];
    int vpt;
    if (cols == 1024) {
        vpt = 4;
        float4 x = ((const float4*)p)[t];
        v[0] = x.x * scale; v[1] = x.y * scale; v[2] = x.z * scale; v[3] = x.w * scale;
    } else {
        vpt = 2;
        float2 x = ((const float2*)p)[t];
        v[0] = x.x * scale; v[1] = x.y * scale; v[2] = -3.4e38f; v[3] = -3.4e38f;
    }
    float mx = fmaxf(fmaxf(v[0], v[1]), fmaxf(v[2], v[3]));
#pragma unroll
    for (int o = 32; o; o >>= 1) mx = fmaxf(mx, __shfl_xor(mx, o));
    __shared__ float sm[4];
    const int wv = t >> 6, ln = t & 63;
    if (ln == 0) sm[wv] = mx;
    __syncthreads();
    mx = fmaxf(fmaxf(sm[0], sm[1]), fmaxf(sm[2], sm[3]));
    float sum = 0.f;
    for (int i = 0; i < vpt; ++i) { v[i] = expf(v[i] - mx); sum += v[i]; }
#pragma unroll
    for (int o = 32; o; o >>= 1) sum += __shfl_xor(sum, o);
    __shared__ float ss[4];
    if (ln == 0) ss[wv] = sum;
    __syncthreads();
    sum = ss[0] + ss[1] + ss[2] + ss[3];
    const float inv = 1.f / sum;
    if (cols == 1024) {
        float q0 = v[0] * inv, q1 = v[1] * inv, q2 = v[2] * inv, q3 = v[3] * inv;
        u16 h0 = f2bf(q0), h1 = f2bf(q1), h2 = f2bf(q2), h3 = f2bf(q3);
        uint2 hh; hh.x = (unsigned)h0 | ((unsigned)h1 << 16); hh.y = (unsigned)h2 | ((unsigned)h3 << 16);
        ((uint2*)php)[t] = hh;
        u16 l0 = f2bf(q0 - bf2f(h0)), l1 = f2bf(q1 - bf2f(h1));
        u16 l2 = f2bf(q2 - bf2f(h2)), l3 = f2bf(q3 - bf2f(h3));
        uint2 ll; ll.x = (unsigned)l0 | ((unsigned)l1 << 16); ll.y = (unsigned)l2 | ((unsigned)l3 << 16);
        ((uint2*)plp)[t] = ll;
    } else {
        float q0 = v[0] * inv, q1 = v[1] * inv;
        u16 h0 = f2bf(q0), h1 = f2bf(q1);
        ((unsigned*)php)[t] = (unsigned)h0 | ((unsigned)h1 << 16);
        u16 l0 = f2bf(q0 - bf2f(h0)), l1 = f2bf(q1 - bf2f(h1));
        ((unsigned*)plp)[t] = (unsigned)l0 | ((unsigned)l1 << 16);
    }
}

// ---------------------------------------------------------------------------
__global__ __launch_bounds__(256) void add_rmsnorm(
    const float* __restrict__ a, const float* __restrict__ b, const float* __restrict__ g,
    float* __restrict__ xo, u16* __restrict__ xh, u16* __restrict__ xl)
{
    const long row = blockIdx.x;
    const int t = threadIdx.x;
    const float* pa = a + row * D_;
    const float* pb = b + row * D_;
    float v[4]; double ssq = 0.0;
#pragma unroll
    for (int i = 0; i < 4; ++i) {
        int c = t + (i << 8);
        v[i] = pa[c] + pb[c];
        ssq += (double)v[i] * v[i];
    }
#pragma unroll
    for (int o = 32; o; o >>= 1) ssq += __shfl_xor(ssq, o);
    __shared__ double sd[4];
    if ((t & 63) == 0) sd[t >> 6] = ssq;
    __syncthreads();
    ssq = sd[0] + sd[1] + sd[2] + sd[3];
    const float rs = (float)(1.0 / sqrt(ssq * (1.0 / 1024.0) + 1e-6));
#pragma unroll
    for (int i = 0; i < 4; ++i) {
        int c = t + (i << 8);
        float o = v[i] * rs * g[c];
        xo[row * D_ + c] = o;
        if (xh) {
            u16 h = f2bf(o);
            xh[row * D_ + c] = h;
            if (xl) xl[row * D_ + c] = f2bf(o - bf2f(h));
        }
    }
}

// ---------------------------------------------------------------------------
__global__ __launch_bounds__(256) void router_topk(
    const float* __restrict__ x2, const float* __restrict__ Wg,
    float* __restrict__ outw, float* __restrict__ outi,
    int* __restrict__ idx, float* __restrict__ tokw, int* __restrict__ counts, int T)
{
    const int wid = (int)((blockIdx.x * 256 + threadIdx.x) >> 6);
    const int lane = threadIdx.x & 63;
    if (wid >= T) return;
    float acc[NE];
#pragma unroll
    for (int e = 0; e < NE; ++e) acc[e] = 0.f;
    const float* xr = x2 + (long)wid * D_;
    for (int i = 0; i < 16; ++i) {
        float xv = xr[i * 64 + lane];
        const float* wr = Wg + (long)(i * 64 + lane) * NE;
#pragma unroll
        for (int e = 0; e < NE; ++e) acc[e] += xv * wr[e];
    }
#pragma unroll
    for (int e = 0; e < NE; ++e)
#pragma unroll
        for (int o = 32; o; o >>= 1) acc[e] += __shfl_xor(acc[e], o);
    if (lane == 0) {
        float m = acc[0];
#pragma unroll
        for (int e = 1; e < NE; ++e) m = fmaxf(m, acc[e]);
        float p[NE], s = 0.f;
#pragma unroll
        for (int e = 0; e < NE; ++e) { p[e] = expf(acc[e] - m); s += p[e]; }
        const float invs = 1.f / s;
#pragma unroll
        for (int e = 0; e < NE; ++e) p[e] *= invs;
        int e0 = 0;
#pragma unroll
        for (int e = 1; e < NE; ++e) if (p[e] > p[e0]) e0 = e;
        int e1 = (e0 == 0) ? 1 : 0;
#pragma unroll
        for (int e = 0; e < NE; ++e) if (e != e0 && e != e1 && p[e] > p[e1]) e1 = e;
        float w0 = p[e0], w1 = p[e1];
        const float sw = 1.f / (w0 + w1);
        w0 *= sw; w1 *= sw;
        outw[2 * wid] = w0;      outw[2 * wid + 1] = w1;
        outi[2 * wid] = (float)e0; outi[2 * wid + 1] = (float)e1;
        idx[2 * wid] = e0;       idx[2 * wid + 1] = e1;
        tokw[2 * wid] = w0;      tokw[2 * wid + 1] = w1;
        atomicAdd(&counts[e0], 1);
        atomicAdd(&counts[e1], 1);
    }
}

__global__ void scan8(const int* __restrict__ counts, int* __restrict__ seg, int* __restrict__ cursor)
{
    if (threadIdx.x == 0 && blockIdx.x == 0) {
        int a = 0;
        for (int e = 0; e < NE; ++e) { seg[e] = a; cursor[e] = a; a += counts[e]; }
        seg[NE] = a;
    }
}

__global__ __launch_bounds__(256) void scatter_slots(
    const int* __restrict__ idx, int* __restrict__ cursor,
    int* __restrict__ row_token, int* __restrict__ slot_of, int T)
{
    const int t = blockIdx.x * 256 + threadIdx.x;
    if (t >= T) return;
#pragma unroll
    for (int k = 0; k < 2; ++k) {
        const int e = idx[2 * t + k];
        const int pos = atomicAdd(&cursor[e], 1);
        row_token[pos] = t;
        slot_of[2 * t + k] = pos;
    }
}

__global__ __launch_bounds__(256) void gather_bf16(
    const float* __restrict__ x2, const int* __restrict__ row_token, u16* __restrict__ Xg)
{
    const int r = blockIdx.x;
    const int t = threadIdx.x;
    const float* src = x2 + (long)row_token[r] * D_ + t * 4;
    float4 v = *(const float4*)src;
    uint2 oo;
    oo.x = (unsigned)f2bf(v.x) | ((unsigned)f2bf(v.y) << 16);
    oo.y = (unsigned)f2bf(v.z) | ((unsigned)f2bf(v.w) << 16);
    *(uint2*)(Xg + (long)r * D_ + t * 4) = oo;
}

// ---------------------------------------------------------------------------
__global__ __launch_bounds__(256) void combine_rmsnorm(
    const float* __restrict__ Y, const int* __restrict__ slot_of, const float* __restrict__ tokw,
    const float* __restrict__ x2, const float* __restrict__ g, float* __restrict__ out)
{
    const long tr = blockIdx.x;
    const int t = threadIdx.x;
    const int s0 = slot_of[2 * tr], s1 = slot_of[2 * tr + 1];
    const float w0 = tokw[2 * tr], w1 = tokw[2 * tr + 1];
    const float* y0 = Y + (long)s0 * D_;
    const float* y1 = Y + (long)s1 * D_;
    const float* xr = x2 + tr * D_;
    float v[4]; double ssq = 0.0;
#pragma unroll
    for (int i = 0; i < 4; ++i) {
        int c = t + (i << 8);
        v[i] = w0 * y0[c] + w1 * y1[c] + xr[c];
        ssq += (double)v[i] * v[i];
    }
#pragma unroll
    for (int o = 32; o; o >>= 1) ssq += __shfl_xor(ssq, o);
    __shared__ double sd[4];
    if ((t & 63) == 0) sd[t >> 6] = ssq;
    __syncthreads();
    ssq = sd[0] + sd[1] + sd[2] + sd[3];
    const float rs = (float)(1.0 / sqrt(ssq * (1.0 / 1024.0) + 1e-6));
#pragma unroll
    for (int i = 0; i < 4; ++i) {
        int c = t + (i << 8);
        out[tr * D_ + c] = v[i] * rs * g[c];
    }
}

__global__ void sentinel(float* o) { o[0] = 12345.0f; }

// ---------------------------------------------------------------------------
extern "C" void kernel_launch(void* const* d_in, const int* in_sizes, int n_in,
                              void* d_out, int out_size, void* d_ws, size_t ws_size,
                              hipStream_t stream)
{
    const float* dec = (const float*)d_in[0];
    const float* te  = (const float*)d_in[1];
    const float* Win[8] = { (const float*)d_in[2], (const float*)d_in[3], (const float*)d_in[4],
                            (const float*)d_in[5], (const float*)d_in[6], (const float*)d_in[7],
                            (const float*)d_in[8], (const float*)d_in[9] };
    const float* g  = (const float*)d_in[10];
    const float* Wg = (const float*)d_in[11];
    const float* W1 = (const float*)d_in[12];
    const float* W2 = (const float*)d_in[13];
    float* outw = (float*)d_out;
    float* outi = outw + 2 * TDEC;
    float* outx = outw + 4 * TDEC;

    char* ws = (char*)d_ws;
    size_t off = 0;
    auto A = [&](size_t bytes) -> char* {
        char* p = ws + off;
        off += (bytes + 255) & ~(size_t)255;
        return p;
    };

    // ---- persistent region ----
    u16* decH = (u16*)A((size_t)TDEC * D_ * 2);
    u16* decL = (u16*)A((size_t)TDEC * D_ * 2);
    u16* teH  = (u16*)A((size_t)TTXT * D_ * 2);
    u16* teL  = (u16*)A((size_t)TTXT * D_ * 2);
    u16* wtHall = (u16*)A((size_t)8 * D_ * D_ * 2);
    u16* wtLall = (u16*)A((size_t)8 * D_ * D_ * 2);
    float* x1f = (float*)A((size_t)TDEC * D_ * 4);
    float* x2f = (float*)A((size_t)TDEC * D_ * 4);
    float* tokw = (float*)A(NSLOT * 4);
    int* idx    = (int*)A(NSLOT * 4);
    int* counts = (int*)A(256);
    int* seg    = (int*)A(256);
    int* cursor = (int*)A(256);
    int* row_token = (int*)A(NSLOT * 4);
    int* slot_of   = (int*)A(NSLOT * 4);

    // ---- shared region R: attention view ----
    const size_t Rbase = off;
    float* scores = (float*)A((size_t)NH * SDEC * SDEC * 4);
    u16* PH = (u16*)A((size_t)NH * SDEC * SDEC * 2);
    u16* PL = (u16*)A((size_t)NH * SDEC * SDEC * 2);
    u16* qkvH = (u16*)A((size_t)TDEC * 3 * D_ * 2);
    u16* qkvL = (u16*)A((size_t)TDEC * 3 * D_ * 2);
    u16* q2H  = (u16*)A((size_t)TDEC * D_ * 2);
    u16* q2L  = (u16*)A((size_t)TDEC * D_ * 2);
    u16* kv2H = (u16*)A((size_t)TTXT * 2 * D_ * 2);
    u16* kv2L = (u16*)A((size_t)TTXT * 2 * D_ * 2);
    u16* vTH = (u16*)A((size_t)TDEC * D_ * 2);
    u16* vTL = (u16*)A((size_t)TDEC * D_ * 2);
    u16* aoH = (u16*)A((size_t)TDEC * D_ * 2);
    u16* aoL = (u16*)A((size_t)TDEC * D_ * 2);
    u16* x1H = (u16*)A((size_t)TDEC * D_ * 2);
    u16* x1L = (u16*)A((size_t)TDEC * D_ * 2);
    float* of = (float*)A((size_t)TDEC * D_ * 4);
    const size_t attnEnd = off;

    // ---- shared region R: MoE view (overlays attention view) ----
    off = Rbase;
    u16* W1T  = (u16*)A((size_t)NE * DFF * D_ * 2);
    u16* W2T  = (u16*)A((size_t)NE * D_ * DFF * 2);
    u16* Xg   = (u16*)A((size_t)(NSLOT + 256) * D_ * 2);   // +256-row pad (256-tile overread)
    u16* Hb   = (u16*)A((size_t)(NSLOT + 256) * DFF * 2);
    float* Yseg = (float*)A((size_t)NSLOT * D_ * 4);
    const size_t needed = (off > attnEnd ? off : attnEnd);

    if (ws_size < needed) {
        sentinel<<<1, 1, 0, stream>>>(outw);
        return;
    }

    const dim3 blk(256);

    // ---- phase 0: input splits + attention weight transposes ----
    split2k<<<dim3((TDEC * D_) / 1024), blk, 0, stream>>>(dec, decH, decL, (long)TDEC * D_);
    split2k<<<dim3((TTXT * D_) / 1024), blk, 0, stream>>>(te, teH, teL, (long)TTXT * D_);
    for (int i = 0; i < 8; ++i)
        transpose_split<<<dim3(32, 32, 1), blk, 0, stream>>>(Win[i],
            wtHall + (size_t)i * D_ * D_, wtLall + (size_t)i * D_ * D_,
            D_, D_, D_, 0, 0, 1, D_, 0);

    // ---- phase 1: self-attention ----
    gemm_bt<1, 1, 128><<<dim3(24, 32, 1), blk, 0, stream>>>(decH, decL, wtHall, wtLall,
        nullptr, qkvH, qkvL, TDEC, 3 * D_, D_, D_, D_, 3 * D_, 0, 0, 0);
    transpose_split_hl<<<dim3(2, 32, BB * NH), blk, 0, stream>>>(qkvH + 2 * D_, qkvL + 2 * D_,
        vTH, vTL, SDEC, DHD, 3 * D_, (long)SDEC * 3 * D_, DHD, NH, SDEC, (long)DHD * SDEC);

    for (int b = 0; b < BB; ++b) {
        const long qo3 = (long)b * SDEC * 3 * D_;
        const long qo  = (long)b * SDEC * D_;
        gemm_bt<1, 0, 128><<<dim3(8, 8, NH), blk, 0, stream>>>(
            qkvH + qo3, qkvL + qo3, qkvH + qo3 + D_, qkvL + qo3 + D_,
            scores, nullptr, nullptr, SDEC, SDEC, DHD, 3 * D_, 3 * D_, SDEC,
            DHD, DHD, (long)SDEC * SDEC);
        softmax_split<<<dim3(NH * SDEC), blk, 0, stream>>>(scores, PH, PL, SDEC, 0.125f);
        gemm_bt<1, 1, 64><<<dim3(1, 8, NH), blk, 0, stream>>>(PH, PL,
            vTH + (long)b * NH * DHD * SDEC, vTL + (long)b * NH * DHD * SDEC,
            nullptr, aoH + qo, aoL + qo, SDEC, DHD, SDEC, SDEC, SDEC, D_,
            (long)SDEC * SDEC, (long)DHD * SDEC, DHD);
    }
    gemm_bt<1, 0, 128><<<dim3(8, 32, 1), blk, 0, stream>>>(aoH, aoL,
        wtHall + (size_t)3 * D_ * D_, wtLall + (size_t)3 * D_ * D_,
        of, nullptr, nullptr, TDEC, D_, D_, D_, D_, D_, 0, 0, 0);
    add_rmsnorm<<<dim3(TDEC), blk, 0, stream>>>(of, dec, g, x1f, x1H, x1L);

    // ---- phase 2: cross-attention ----
    gemm_bt<1, 1, 128><<<dim3(8, 32, 1), blk, 0, stream>>>(x1H, x1L,
        wtHall + (size_t)4 * D_ * D_, wtLall + (size_t)4 * D_ * D_,
        nullptr, q2H, q2L, TDEC, D_, D_, D_, D_, D_, 0, 0, 0);
    gemm_bt<1, 1, 128><<<dim3(16, 16, 1), blk, 0, stream>>>(teH, teL,
        wtHall + (size_t)5 * D_ * D_, wtLall + (size_t)5 * D_ * D_,
        nullptr, kv2H, kv2L, TTXT, 2 * D_, D_, D_, D_, 2 * D_, 0, 0, 0);
    transpose_split_hl<<<dim3(2, 16, BB * NH), blk, 0, stream>>>(kv2H + D_, kv2L + D_,
        vTH, vTL, STXT, DHD, 2 * D_, (long)STXT * 2 * D_, DHD, NH, STXT, (long)DHD * STXT);

    for (int b = 0; b < BB; ++b) {
        const long qo  = (long)b * SDEC * D_;
        const long ko2 = (long)b * STXT * 2 * D_;
        gemm_bt<1, 0, 128><<<dim3(4, 8, NH), blk, 0, stream>>>(
            q2H + qo, q2L + qo, kv2H + ko2, kv2L + ko2,
            scores, nullptr, nullptr, SDEC, STXT, DHD, D_, 2 * D_, STXT,
            DHD, DHD, (long)SDEC * STXT);
        softmax_split<<<dim3(NH * SDEC), blk, 0, stream>>>(scores, PH, PL, STXT, 0.125f);
        gemm_bt<1, 1, 64><<<dim3(1, 8, NH), blk, 0, stream>>>(PH, PL,
            vTH + (long)b * NH * DHD * STXT, vTL + (long)b * NH * DHD * STXT,
            nullptr, aoH + qo, aoL + qo, SDEC, DHD, STXT, STXT, STXT, D_,
            (long)SDEC * STXT, (long)DHD * STXT, DHD);
    }
    gemm_bt<1, 0, 128><<<dim3(8, 32, 1), blk, 0, stream>>>(aoH, aoL,
        wtHall + (size_t)7 * D_ * D_, wtLall + (size_t)7 * D_ * D_,
        of, nullptr, nullptr, TDEC, D_, D_, D_, D_, D_, 0, 0, 0);
    add_rmsnorm<<<dim3(TDEC), blk, 0, stream>>>(of, x1f, g, x2f, nullptr, nullptr);

    // ---- phase 3: router + expert bucketing ----
    hipMemsetAsync(counts, 0, 32, stream);
    router_topk<<<dim3(TDEC / 4), blk, 0, stream>>>(x2f, Wg, outw, outi, idx, tokw, counts, TDEC);
    scan8<<<1, 64, 0, stream>>>(counts, seg, cursor);
    scatter_slots<<<dim3(TDEC / 256), blk, 0, stream>>>(idx, cursor, row_token, slot_of, TDEC);
    gather_bf16<<<dim3(NSLOT), blk, 0, stream>>>(x2f, row_token, Xg);

    // ---- phase 4: MoE FFN (bf16, pipelined 256x256, expert->XCD affinity) ----
    transpose_split<<<dim3(DFF / 32, D_ / 32, NE), blk, 0, stream>>>(W1, W1T, nullptr,
        D_, DFF, DFF, (long)D_ * DFF, 0, 1, D_, (long)DFF * D_);
    transpose_split<<<dim3(D_ / 32, DFF / 32, NE), blk, 0, stream>>>(W2, W2T, nullptr,
        DFF, D_, D_, (long)D_ * DFF, 0, 1, DFF, (long)D_ * DFF);
    gemm256_moe<2><<<dim3(8 * MAXYT2 * (DFF / 256)), dim3(512), 0, stream>>>(Xg, W1T,
        nullptr, Hb, DFF, D_, DFF, seg, (long)DFF * D_);
    gemm256_moe<0><<<dim3(8 * MAXYT2 * (D_ / 256)), dim3(512), 0, stream>>>(Hb, W2T,
        Yseg, nullptr, D_, DFF, D_, seg, (long)D_ * DFF);
    combine_rmsnorm<<<dim3(TDEC), blk, 0, stream>>>(Yseg, slot_of, tokw, x2f, g, outx);

    (void)in_sizes; (void)n_in; (void)out_size;
}

// Round 5
// 1452.781 us; speedup vs baseline: 1.4292x; 1.0130x over previous
//
#include <hip/hip_runtime.h>
#include <stdint.h>

#define D_    1024
#define BB    4
#define SDEC  1024
#define STXT  512
#define TDEC  4096
#define TTXT  2048
#define NH    16
#define DHD   64
#define NE    8
#define DFF   4096
#define NSLOT 8192
#define ND1   8192   // FFN1 desc slots (worst case: one expert owns all tokens)
#define ND2   4096   // FFN2 desc slots
#define MOEGRID 1024

using u16 = unsigned short;
typedef __attribute__((ext_vector_type(8))) short bf16x8;
typedef __attribute__((ext_vector_type(4))) float f32x4;

__device__ __forceinline__ float bf2f(u16 h) {
    union { unsigned int u; float f; } x; x.u = ((unsigned int)h) << 16; return x.f;
}
__device__ __forceinline__ u16 f2bf(float f) {
    union { float f; unsigned int u; } x; x.f = f;
    unsigned int lsb = (x.u >> 16) & 1u;
    return (u16)((x.u + 0x7fffu + lsb) >> 16);
}

// async global->LDS, 16B per lane, linear LDS dest (wave-uniform base + lane*16)
__device__ __forceinline__ void gld16(const u16* g, u16* l) {
    __builtin_amdgcn_global_load_lds((const __attribute__((address_space(1))) void*)g,
                                     (__attribute__((address_space(3))) void*)l,
                                     16, 0, 0);
}

constexpr int BM = 128, BK = 32;

// ---------------------------------------------------------------------------
// Generic tiled GEMM (128-tile, 2-barrier): C[M,N] = A[M,K] * BT[N,K]^T.
// SPLIT=1: 3-pass split emulation. EPI: 0=f32, 1=split store, 2=relu+bf16.
// ---------------------------------------------------------------------------
template<int SPLIT, int EPI, int BROWS>
__global__ __launch_bounds__(256) void gemm_bt(
    const u16* __restrict__ AH, const u16* __restrict__ AL,
    const u16* __restrict__ BH, const u16* __restrict__ BL,
    float* __restrict__ Cf, u16* __restrict__ CH, u16* __restrict__ CL,
    int M, int N, int K, int lda, int ldb, int ldc,
    long strA, long strB, long strC)
{
    constexpr int WM = (BROWS == 64) ? 2 : 4;
    constexpr int ASZ = BM * BK, BSZ = BROWS * BK;
    __shared__ u16 smem[(SPLIT ? 2 : 1) * (ASZ + BSZ)];
    u16* sAH = smem;
    u16* sBH = smem + ASZ;
    u16* sAL = SPLIT ? smem + ASZ + BSZ : nullptr;
    u16* sBL = SPLIT ? smem + 2 * ASZ + BSZ : nullptr;

    const int z = blockIdx.z;
    const long zA = (long)z * strA, zB = (long)z * strB, zC = (long)z * strC;

    const int tileM = blockIdx.y * BM, tileN = blockIdx.x * BROWS;
    const int t = threadIdx.x;
    const int sr = t >> 2;
    const int sc = (t & 3) << 3;
    const u16* pA = AH + zA + (long)(tileM + sr) * lda + sc;
    const u16* pB = BH + zB + (long)(tileN + sr) * ldb + sc;
    const u16* pAl = nullptr; const u16* pBl = nullptr;
    if constexpr (SPLIT) {
        pAl = AL + zA + (long)(tileM + sr) * lda + sc;
        pBl = BL + zB + (long)(tileN + sr) * ldb + sc;
    }
    const long hA = 64L * lda, hB = 64L * ldb;

    const int lane = t & 63;
    const int wv = t >> 6;
    const int wr = (BROWS == 64) ? (wv << 5) : ((wv >> 1) << 6);
    const int wc = (BROWS == 64) ? 0 : ((wv & 1) << 6);
    const int fr = lane & 15, kg = lane >> 4;

    f32x4 acc[WM][4];
    const f32x4 vzero = {0.f, 0.f, 0.f, 0.f};
#pragma unroll
    for (int m = 0; m < WM; ++m)
#pragma unroll
        for (int n = 0; n < 4; ++n) acc[m][n] = vzero;

    for (int k0 = 0; k0 < K; k0 += BK) {
        gld16(pA + k0,      sAH + t * 8);
        gld16(pA + k0 + hA, sAH + 2048 + t * 8);
        gld16(pB + k0,      sBH + t * 8);
        if constexpr (BROWS == 128) gld16(pB + k0 + hB, sBH + 2048 + t * 8);
        if constexpr (SPLIT) {
            gld16(pAl + k0,      sAL + t * 8);
            gld16(pAl + k0 + hA, sAL + 2048 + t * 8);
            gld16(pBl + k0,      sBL + t * 8);
            if constexpr (BROWS == 128) gld16(pBl + k0 + hB, sBL + 2048 + t * 8);
        }
        __syncthreads();

        bf16x8 fa[WM], fb[4], fal[WM], fbl[4];
#pragma unroll
        for (int m = 0; m < WM; ++m) {
            fa[m] = *(const bf16x8*)&sAH[(wr + m * 16 + fr) * BK + (kg << 3)];
            if constexpr (SPLIT) fal[m] = *(const bf16x8*)&sAL[(wr + m * 16 + fr) * BK + (kg << 3)];
        }
#pragma unroll
        for (int n = 0; n < 4; ++n) {
            fb[n] = *(const bf16x8*)&sBH[(wc + n * 16 + fr) * BK + (kg << 3)];
            if constexpr (SPLIT) fbl[n] = *(const bf16x8*)&sBL[(wc + n * 16 + fr) * BK + (kg << 3)];
        }
#pragma unroll
        for (int m = 0; m < WM; ++m)
#pragma unroll
            for (int n = 0; n < 4; ++n) {
                acc[m][n] = __builtin_amdgcn_mfma_f32_16x16x32_bf16(fa[m], fb[n], acc[m][n], 0, 0, 0);
                if constexpr (SPLIT) {
                    acc[m][n] = __builtin_amdgcn_mfma_f32_16x16x32_bf16(fa[m],  fbl[n], acc[m][n], 0, 0, 0);
                    acc[m][n] = __builtin_amdgcn_mfma_f32_16x16x32_bf16(fal[m], fb[n],  acc[m][n], 0, 0, 0);
                }
            }
        __syncthreads();
    }

#pragma unroll
    for (int m = 0; m < WM; ++m) {
        const int r0 = tileM + wr + m * 16 + (kg << 2);
#pragma unroll
        for (int n = 0; n < 4; ++n) {
            const int col = tileN + wc + n * 16 + fr;
            if (col >= N) continue;
#pragma unroll
            for (int i = 0; i < 4; ++i) {
                const int r = r0 + i;
                if (r >= M) continue;
                const float v = acc[m][n][i];
                const long off = zC + (long)r * ldc + col;
                if constexpr (EPI == 0) {
                    Cf[off] = v;
                } else if constexpr (EPI == 1) {
                    const u16 h = f2bf(v);
                    CH[off] = h;
                    CL[off] = f2bf(v - bf2f(h));
                } else {
                    CH[off] = f2bf(fmaxf(v, 0.f));
                }
            }
        }
    }
}

// ---------------------------------------------------------------------------
// MoE persistent GEMM: 128x128 tiles from a device-built work list.
//   - 256 threads = 4 waves (2x2), per-wave 64x64, BK=32, double-buffered LDS
//     (2 x 32KB ring halves = 32 KB total) -> 4 blocks/CU (TLP hides latency).
//   - XOR swizzle chunk = kg ^ ((row>>1)&3): 2-way max bank aliasing (free).
//     Inverse swizzle applied on the global source (rule: both-sides-or-neither).
//   - desc int4: x=rowbase, y=colbase|(e<<16), z=kbase, w=s1(row bound).
//     Invalid entries have x<0. Position p handled by block p%grid; grid%8==0
//     keeps p%8==e on XCD e (round-robin dispatch heuristic).
//   - EPI: 0 = f32 store to (kbase?Cf1:Cf0)  [FFN2 split-K], 2 = relu+bf16 [FFN1].
// ---------------------------------------------------------------------------
template<int EPI>
__global__ __launch_bounds__(256, 4) void moe_gemm2(
    const u16* __restrict__ Ag, int lda,
    const u16* __restrict__ BTbase, int ldb, long btStride,
    float* __restrict__ Cf0, float* __restrict__ Cf1, u16* __restrict__ CH, int ldc,
    const int4* __restrict__ desc, int ndesc, int Kiter)
{
    __shared__ u16 smem[16384];   // 32 KB: [2 bufs][A 4096 | B 4096] elems
    const int t = threadIdx.x;
    const int lane = t & 63, wv = t >> 6;
    const int wr = (wv >> 1) << 6, wc = (wv & 1) << 6;
    const int fr = lane & 15, kg = lane >> 4;
    const int nks = Kiter >> 5;

    // staging decode (uniform per thread): chunks t and t+256; both share col swizzle
    const int rS = t >> 2;                         // rows 0..63 (chunk0) / +64 (chunk1)
    const int cS = ((t & 3) ^ ((t >> 3) & 3)) << 3; // swizzled global col offset (elems)

    // fragment LDS offsets (elems), swizzled
    int ldsA[4], ldsB[4];
#pragma unroll
    for (int m = 0; m < 4; ++m) {
        const int ra = wr + m * 16 + fr;
        ldsA[m] = ra * 32 + ((kg ^ ((ra >> 1) & 3)) << 3);
        const int rb = wc + m * 16 + fr;
        ldsB[m] = rb * 32 + ((kg ^ ((rb >> 1) & 3)) << 3);
    }

    for (int p = blockIdx.x; p < ndesc; p += MOEGRID) {
        const int4 d = desc[p];
        if (d.x < 0) continue;
        const int rowbase = d.x, colbase = d.y & 0xFFFF, e = d.y >> 16;
        const int kbase = d.z, s1 = d.w;
        const u16* paS = Ag + (long)(rowbase + rS) * lda + kbase + cS;
        const u16* pbS = BTbase + (long)e * btStride + (long)(colbase + rS) * ldb + kbase + cS;
        const long hA = 64L * lda, hB = 64L * ldb;

        f32x4 acc[4][4];
        const f32x4 vzero = {0.f, 0.f, 0.f, 0.f};
#pragma unroll
        for (int m = 0; m < 4; ++m)
#pragma unroll
            for (int n = 0; n < 4; ++n) acc[m][n] = vzero;

#define STG(ks, buf) { const long k0_ = (long)(ks) << 5; \
        u16* sA_ = smem + (buf) * 8192; \
        gld16(paS + k0_,      sA_ + t * 8); \
        gld16(paS + k0_ + hA, sA_ + 2048 + t * 8); \
        gld16(pbS + k0_,      sA_ + 4096 + t * 8); \
        gld16(pbS + k0_ + hB, sA_ + 6144 + t * 8); }

        STG(0, 0);
        asm volatile("s_waitcnt vmcnt(0)" ::: "memory");
        __builtin_amdgcn_s_barrier();

        for (int ks = 0; ks < nks; ++ks) {
            const int cur = ks & 1;
            if (ks + 1 < nks) STG(ks + 1, cur ^ 1);
            const u16* sA = smem + cur * 8192;
            const u16* sB = sA + 4096;
            bf16x8 fa[4], fb[4];
#pragma unroll
            for (int m = 0; m < 4; ++m) fa[m] = *(const bf16x8*)&sA[ldsA[m]];
#pragma unroll
            for (int n = 0; n < 4; ++n) fb[n] = *(const bf16x8*)&sB[ldsB[n]];
#pragma unroll
            for (int m = 0; m < 4; ++m)
#pragma unroll
                for (int n = 0; n < 4; ++n)
                    acc[m][n] = __builtin_amdgcn_mfma_f32_16x16x32_bf16(fa[m], fb[n], acc[m][n], 0, 0, 0);
            asm volatile("s_waitcnt vmcnt(0)" ::: "memory");
            __builtin_amdgcn_s_barrier();
        }
#undef STG

        float* __restrict__ C = (EPI == 0) ? ((kbase == 0) ? Cf0 : Cf1) : nullptr;
#pragma unroll
        for (int m = 0; m < 4; ++m) {
            const int r0 = rowbase + wr + m * 16 + (kg << 2);
#pragma unroll
            for (int n = 0; n < 4; ++n) {
                const int col = colbase + wc + n * 16 + fr;
#pragma unroll
                for (int i = 0; i < 4; ++i) {
                    const int r = r0 + i;
                    if (r >= s1) continue;
                    const float v = acc[m][n][i];
                    const long off = (long)r * ldc + col;
                    if constexpr (EPI == 0) C[off] = v;
                    else                    CH[off] = f2bf(fmaxf(v, 0.f));
                }
            }
        }
    }
}

// ---------------------------------------------------------------------------
__global__ __launch_bounds__(256) void split2k(const float* __restrict__ in,
                                               u16* __restrict__ oh, u16* __restrict__ ol, long n)
{
    long i = ((long)blockIdx.x * 256 + threadIdx.x) * 4;
    if (i >= n) return;
    float4 v = *(const float4*)(in + i);
    u16 h0 = f2bf(v.x), h1 = f2bf(v.y), h2 = f2bf(v.z), h3 = f2bf(v.w);
    uint2 oo;
    oo.x = (unsigned)h0 | ((unsigned)h1 << 16);
    oo.y = (unsigned)h2 | ((unsigned)h3 << 16);
    *(uint2*)(oh + i) = oo;
    if (ol) {
        u16 l0 = f2bf(v.x - bf2f(h0)), l1 = f2bf(v.y - bf2f(h1));
        u16 l2 = f2bf(v.z - bf2f(h2)), l3 = f2bf(v.w - bf2f(h3));
        uint2 ll;
        ll.x = (unsigned)l0 | ((unsigned)l1 << 16);
        ll.y = (unsigned)l2 | ((unsigned)l3 << 16);
        *(uint2*)(ol + i) = ll;
    }
}

// ---------------------------------------------------------------------------
__global__ __launch_bounds__(256) void transpose_split(
    const float* __restrict__ in, u16* __restrict__ oh, u16* __restrict__ ol,
    int R, int C, int ild, long ibs1, long ibs2, int nb2, int old_, long obs)
{
    __shared__ float tile[32][33];
    const int z = blockIdx.z;
    const float* ip = in + (long)(z / nb2) * ibs1 + (long)(z % nb2) * ibs2;
    u16* ohp = oh + (long)z * obs;
    u16* olp = ol ? ol + (long)z * obs : nullptr;
    const int c0 = blockIdx.x * 32, r0 = blockIdx.y * 32;
    const int tx = threadIdx.x & 31, ty = threadIdx.x >> 5;
    for (int i = ty; i < 32; i += 8) {
        int r = r0 + i, c = c0 + tx;
        tile[i][tx] = (r < R && c < C) ? ip[(long)r * ild + c] : 0.f;
    }
    __syncthreads();
    for (int i = ty; i < 32; i += 8) {
        int oc = c0 + i, orr = r0 + tx;
        if (oc < C && orr < R) {
            float v = tile[tx][i];
            u16 h = f2bf(v);
            ohp[(long)oc * old_ + orr] = h;
            if (olp) olp[(long)oc * old_ + orr] = f2bf(v - bf2f(h));
        }
    }
}

// ---------------------------------------------------------------------------
__global__ __launch_bounds__(256) void transpose_split_hl(
    const u16* __restrict__ inH, const u16* __restrict__ inL,
    u16* __restrict__ oh, u16* __restrict__ ol,
    int R, int C, int ild, long ibs1, long ibs2, int nb2, int old_, long obs)
{
    __shared__ float tile[32][33];
    const int z = blockIdx.z;
    const long base = (long)(z / nb2) * ibs1 + (long)(z % nb2) * ibs2;
    u16* ohp = oh + (long)z * obs;
    u16* olp = ol + (long)z * obs;
    const int c0 = blockIdx.x * 32, r0 = blockIdx.y * 32;
    const int tx = threadIdx.x & 31, ty = threadIdx.x >> 5;
    for (int i = ty; i < 32; i += 8) {
        int r = r0 + i, c = c0 + tx;
        float v = 0.f;
        if (r < R && c < C) {
            const long o = base + (long)r * ild + c;
            v = bf2f(inH[o]) + bf2f(inL[o]);
        }
        tile[i][tx] = v;
    }
    __syncthreads();
    for (int i = ty; i < 32; i += 8) {
        int oc = c0 + i, orr = r0 + tx;
        if (oc < C && orr < R) {
            float v = tile[tx][i];
            u16 h = f2bf(v);
            ohp[(long)oc * old_ + orr] = h;
            olp[(long)oc * old_ + orr] = f2bf(v - bf2f(h));
        }
    }
}

// ---------------------------------------------------------------------------
__global__ __launch_bounds__(256) void softmax_split(
    const float* __restrict__ s, u16* __restrict__ ph, u16* __restrict__ pl,
    int cols, float scale)
{
    const float* p = s + (long)blockIdx.x * cols;
    u16* php = ph + (long)blockIdx.x * cols;
    u16* plp = pl + (long)blockIdx.x * cols;
    const int t = threadIdx.x;
    float v[4];
    int vpt;
    if (cols == 1024) {
        vpt = 4;
        float4 x = ((const float4*)p)[t];
        v[0] = x.x * scale; v[1] = x.y * scale; v[2] = x.z * scale; v[3] = x.w * scale;
    } else {
        vpt = 2;
        float2 x = ((const float2*)p)[t];
        v[0] = x.x * scale; v[1] = x.y * scale; v[2] = -3.4e38f; v[3] = -3.4e38f;
    }
    float mx = fmaxf(fmaxf(v[0], v[1]), fmaxf(v[2], v[3]));
#pragma unroll
    for (int o = 32; o; o >>= 1) mx = fmaxf(mx, __shfl_xor(mx, o));
    __shared__ float sm[4];
    const int wv = t >> 6, ln = t & 63;
    if (ln == 0) sm[wv] = mx;
    __syncthreads();
    mx = fmaxf(fmaxf(sm[0], sm[1]), fmaxf(sm[2], sm[3]));
    float sum = 0.f;
    for (int i = 0; i < vpt; ++i) { v[i] = expf(v[i] - mx); sum += v[i]; }
#pragma unroll
    for (int o = 32; o; o >>= 1) sum += __shfl_xor(sum, o);
    __shared__ float ss[4];
    if (ln == 0) ss[wv] = sum;
    __syncthreads();
    sum = ss[0] + ss[1] + ss[2] + ss[3];
    const float inv = 1.f / sum;
    if (cols == 1024) {
        float q0 = v[0] * inv, q1 = v[1] * inv, q2 = v[2] * inv, q3 = v[3] * inv;
        u16 h0 = f2bf(q0), h1 = f2bf(q1), h2 = f2bf(q2), h3 = f2bf(q3);
        uint2 hh; hh.x = (unsigned)h0 | ((unsigned)h1 << 16); hh.y = (unsigned)h2 | ((unsigned)h3 << 16);
        ((uint2*)php)[t] = hh;
        u16 l0 = f2bf(q0 - bf2f(h0)), l1 = f2bf(q1 - bf2f(h1));
        u16 l2 = f2bf(q2 - bf2f(h2)), l3 = f2bf(q3 - bf2f(h3));
        uint2 ll; ll.x = (unsigned)l0 | ((unsigned)l1 << 16); ll.y = (unsigned)l2 | ((unsigned)l3 << 16);
        ((uint2*)plp)[t] = ll;
    } else {
        float q0 = v[0] * inv, q1 = v[1] * inv;
        u16 h0 = f2bf(q0), h1 = f2bf(q1);
        ((unsigned*)php)[t] = (unsigned)h0 | ((unsigned)h1 << 16);
        u16 l0 = f2bf(q0 - bf2f(h0)), l1 = f2bf(q1 - bf2f(h1));
        ((unsigned*)plp)[t] = (unsigned)l0 | ((unsigned)l1 << 16);
    }
}

// ---------------------------------------------------------------------------
__global__ __launch_bounds__(256) void add_rmsnorm(
    const float* __restrict__ a, const float* __restrict__ b, const float* __restrict__ g,
    float* __restrict__ xo, u16* __restrict__ xh, u16* __restrict__ xl)
{
    const long row = blockIdx.x;
    const int t = threadIdx.x;
    const float* pa = a + row * D_;
    const float* pb = b + row * D_;
    float v[4]; double ssq = 0.0;
#pragma unroll
    for (int i = 0; i < 4; ++i) {
        int c = t + (i << 8);
        v[i] = pa[c] + pb[c];
        ssq += (double)v[i] * v[i];
    }
#pragma unroll
    for (int o = 32; o; o >>= 1) ssq += __shfl_xor(ssq, o);
    __shared__ double sd[4];
    if ((t & 63) == 0) sd[t >> 6] = ssq;
    __syncthreads();
    ssq = sd[0] + sd[1] + sd[2] + sd[3];
    const float rs = (float)(1.0 / sqrt(ssq * (1.0 / 1024.0) + 1e-6));
#pragma unroll
    for (int i = 0; i < 4; ++i) {
        int c = t + (i << 8);
        float o = v[i] * rs * g[c];
        xo[row * D_ + c] = o;
        if (xh) {
            u16 h = f2bf(o);
            xh[row * D_ + c] = h;
            if (xl) xl[row * D_ + c] = f2bf(o - bf2f(h));
        }
    }
}

// ---------------------------------------------------------------------------
__global__ __launch_bounds__(256) void router_topk(
    const float* __restrict__ x2, const float* __restrict__ Wg,
    float* __restrict__ outw, float* __restrict__ outi,
    int* __restrict__ idx, float* __restrict__ tokw, int* __restrict__ counts, int T)
{
    const int wid = (int)((blockIdx.x * 256 + threadIdx.x) >> 6);
    const int lane = threadIdx.x & 63;
    if (wid >= T) return;
    float acc[NE];
#pragma unroll
    for (int e = 0; e < NE; ++e) acc[e] = 0.f;
    const float* xr = x2 + (long)wid * D_;
    for (int i = 0; i < 16; ++i) {
        float xv = xr[i * 64 + lane];
        const float* wr = Wg + (long)(i * 64 + lane) * NE;
#pragma unroll
        for (int e = 0; e < NE; ++e) acc[e] += xv * wr[e];
    }
#pragma unroll
    for (int e = 0; e < NE; ++e)
#pragma unroll
        for (int o = 32; o; o >>= 1) acc[e] += __shfl_xor(acc[e], o);
    if (lane == 0) {
        float m = acc[0];
#pragma unroll
        for (int e = 1; e < NE; ++e) m = fmaxf(m, acc[e]);
        float p[NE], s = 0.f;
#pragma unroll
        for (int e = 0; e < NE; ++e) { p[e] = expf(acc[e] - m); s += p[e]; }
        const float invs = 1.f / s;
#pragma unroll
        for (int e = 0; e < NE; ++e) p[e] *= invs;
        int e0 = 0;
#pragma unroll
        for (int e = 1; e < NE; ++e) if (p[e] > p[e0]) e0 = e;
        int e1 = (e0 == 0) ? 1 : 0;
#pragma unroll
        for (int e = 0; e < NE; ++e) if (e != e0 && e != e1 && p[e] > p[e1]) e1 = e;
        float w0 = p[e0], w1 = p[e1];
        const float sw = 1.f / (w0 + w1);
        w0 *= sw; w1 *= sw;
        outw[2 * wid] = w0;      outw[2 * wid + 1] = w1;
        outi[2 * wid] = (float)e0; outi[2 * wid + 1] = (float)e1;
        idx[2 * wid] = e0;       idx[2 * wid + 1] = e1;
        tokw[2 * wid] = w0;      tokw[2 * wid + 1] = w1;
        atomicAdd(&counts[e0], 1);
        atomicAdd(&counts[e1], 1);
    }
}

// ---------------------------------------------------------------------------
// Prefix-scan + MoE tile work-list builder. 1 block x 64 threads.
// desc order per expert: xt-major, yt-inner (keeps B slice L2-hot); position
// p = e + 8*j keeps expert e's tiles on XCD e under round-robin dispatch.
// ---------------------------------------------------------------------------
__global__ void scan_desc(const int* __restrict__ counts, int* __restrict__ cursor,
                          int4* __restrict__ d1, int4* __restrict__ d2)
{
    __shared__ int sseg[NE + 1];
    if (threadIdx.x == 0) {
        int a = 0;
        for (int e = 0; e < NE; ++e) { sseg[e] = a; cursor[e] = a; a += counts[e]; }
        sseg[NE] = a;
    }
    __syncthreads();
    const int e = threadIdx.x;
    if (e < NE) {
        const int s0 = sseg[e], s1 = sseg[e + 1];
        const int nyt = (s1 - s0 + 127) >> 7;
        // FFN1: N=4096 -> 32 xt tiles of 128
        for (int xt = 0; xt < 32; ++xt)
            for (int yt = 0; yt < nyt; ++yt)
                d1[e + 8 * (xt * nyt + yt)] =
                    make_int4(s0 + yt * 128, (xt * 128) | (e << 16), 0, s1);
        // FFN2: N=1024 -> 8 xt tiles; split-K 2 halves of 2048
        for (int kh = 0; kh < 2; ++kh)
            for (int xt = 0; xt < 8; ++xt)
                for (int yt = 0; yt < nyt; ++yt)
                    d2[e + 8 * ((kh * 8 + xt) * nyt + yt)] =
                        make_int4(s0 + yt * 128, (xt * 128) | (e << 16), kh * 2048, s1);
    }
}

__global__ __launch_bounds__(256) void scatter_slots(
    const int* __restrict__ idx, int* __restrict__ cursor,
    int* __restrict__ row_token, int* __restrict__ slot_of, int T)
{
    const int t = blockIdx.x * 256 + threadIdx.x;
    if (t >= T) return;
#pragma unroll
    for (int k = 0; k < 2; ++k) {
        const int e = idx[2 * t + k];
        const int pos = atomicAdd(&cursor[e], 1);
        row_token[pos] = t;
        slot_of[2 * t + k] = pos;
    }
}

__global__ __launch_bounds__(256) void gather_bf16(
    const float* __restrict__ x2, const int* __restrict__ row_token, u16* __restrict__ Xg)
{
    const int r = blockIdx.x;
    const int t = threadIdx.x;
    const float* src = x2 + (long)row_token[r] * D_ + t * 4;
    float4 v = *(const float4*)src;
    uint2 oo;
    oo.x = (unsigned)f2bf(v.x) | ((unsigned)f2bf(v.y) << 16);
    oo.y = (unsigned)f2bf(v.z) | ((unsigned)f2bf(v.w) << 16);
    *(uint2*)(Xg + (long)r * D_ + t * 4) = oo;
}

// ---------------------------------------------------------------------------
// Final: x = rmsnorm(w0*(Y0+Y1)[s0] + w1*(Y0+Y1)[s1] + x2, g) -> out
// ---------------------------------------------------------------------------
__global__ __launch_bounds__(256) void combine_rmsnorm(
    const float* __restrict__ Y0, const float* __restrict__ Y1,
    const int* __restrict__ slot_of, const float* __restrict__ tokw,
    const float* __restrict__ x2, const float* __restrict__ g, float* __restrict__ out)
{
    const long tr = blockIdx.x;
    const int t = threadIdx.x;
    const int s0 = slot_of[2 * tr], s1 = slot_of[2 * tr + 1];
    const float w0 = tokw[2 * tr], w1 = tokw[2 * tr + 1];
    const float* ya0 = Y0 + (long)s0 * D_;
    const float* yb0 = Y1 + (long)s0 * D_;
    const float* ya1 = Y0 + (long)s1 * D_;
    const float* yb1 = Y1 + (long)s1 * D_;
    const float* xr = x2 + tr * D_;
    float v[4]; double ssq = 0.0;
#pragma unroll
    for (int i = 0; i < 4; ++i) {
        int c = t + (i << 8);
        v[i] = w0 * (ya0[c] + yb0[c]) + w1 * (ya1[c] + yb1[c]) + xr[c];
        ssq += (double)v[i] * v[i];
    }
#pragma unroll
    for (int o = 32; o; o >>= 1) ssq += __shfl_xor(ssq, o);
    __shared__ double sd[4];
    if ((t & 63) == 0) sd[t >> 6] = ssq;
    __syncthreads();
    ssq = sd[0] + sd[1] + sd[2] + sd[3];
    const float rs = (float)(1.0 / sqrt(ssq * (1.0 / 1024.0) + 1e-6));
#pragma unroll
    for (int i = 0; i < 4; ++i) {
        int c = t + (i << 8);
        out[tr * D_ + c] = v[i] * rs * g[c];
    }
}

__global__ void sentinel(float* o) { o[0] = 12345.0f; }

// ---------------------------------------------------------------------------
extern "C" void kernel_launch(void* const* d_in, const int* in_sizes, int n_in,
                              void* d_out, int out_size, void* d_ws, size_t ws_size,
                              hipStream_t stream)
{
    const float* dec = (const float*)d_in[0];
    const float* te  = (const float*)d_in[1];
    const float* Win[8] = { (const float*)d_in[2], (const float*)d_in[3], (const float*)d_in[4],
                            (const float*)d_in[5], (const float*)d_in[6], (const float*)d_in[7],
                            (const float*)d_in[8], (const float*)d_in[9] };
    const float* g  = (const float*)d_in[10];
    const float* Wg = (const float*)d_in[11];
    const float* W1 = (const float*)d_in[12];
    const float* W2 = (const float*)d_in[13];
    float* outw = (float*)d_out;
    float* outi = outw + 2 * TDEC;
    float* outx = outw + 4 * TDEC;

    char* ws = (char*)d_ws;
    size_t off = 0;
    auto A = [&](size_t bytes) -> char* {
        char* p = ws + off;
        off += (bytes + 255) & ~(size_t)255;
        return p;
    };

    // ---- persistent region ----
    u16* decH = (u16*)A((size_t)TDEC * D_ * 2);
    u16* decL = (u16*)A((size_t)TDEC * D_ * 2);
    u16* teH  = (u16*)A((size_t)TTXT * D_ * 2);
    u16* teL  = (u16*)A((size_t)TTXT * D_ * 2);
    u16* wtHall = (u16*)A((size_t)8 * D_ * D_ * 2);
    u16* wtLall = (u16*)A((size_t)8 * D_ * D_ * 2);
    float* x1f = (float*)A((size_t)TDEC * D_ * 4);
    float* x2f = (float*)A((size_t)TDEC * D_ * 4);
    float* tokw = (float*)A(NSLOT * 4);
    int* idx    = (int*)A(NSLOT * 4);
    int* counts = (int*)A(256);
    int* cursor = (int*)A(256);
    int* row_token = (int*)A(NSLOT * 4);
    int* slot_of   = (int*)A(NSLOT * 4);
    int4* desc1 = (int4*)A((size_t)ND1 * 16);
    int4* desc2 = (int4*)A((size_t)ND2 * 16);

    // ---- shared region R: attention view ----
    const size_t Rbase = off;
    float* scores = (float*)A((size_t)NH * SDEC * SDEC * 4);
    u16* PH = (u16*)A((size_t)NH * SDEC * SDEC * 2);
    u16* PL = (u16*)A((size_t)NH * SDEC * SDEC * 2);
    u16* qkvH = (u16*)A((size_t)TDEC * 3 * D_ * 2);
    u16* qkvL = (u16*)A((size_t)TDEC * 3 * D_ * 2);
    u16* q2H  = (u16*)A((size_t)TDEC * D_ * 2);
    u16* q2L  = (u16*)A((size_t)TDEC * D_ * 2);
    u16* kv2H = (u16*)A((size_t)TTXT * 2 * D_ * 2);
    u16* kv2L = (u16*)A((size_t)TTXT * 2 * D_ * 2);
    u16* vTH = (u16*)A((size_t)TDEC * D_ * 2);
    u16* vTL = (u16*)A((size_t)TDEC * D_ * 2);
    u16* aoH = (u16*)A((size_t)TDEC * D_ * 2);
    u16* aoL = (u16*)A((size_t)TDEC * D_ * 2);
    u16* x1H = (u16*)A((size_t)TDEC * D_ * 2);
    u16* x1L = (u16*)A((size_t)TDEC * D_ * 2);
    float* of = (float*)A((size_t)TDEC * D_ * 4);
    const size_t attnEnd = off;

    // ---- shared region R: MoE view (overlays attention view) ----
    off = Rbase;
    u16* W1T  = (u16*)A((size_t)NE * DFF * D_ * 2);   // dead after FFN1; reused as Ypart1
    u16* W2T  = (u16*)A((size_t)NE * D_ * DFF * 2);
    u16* Xg   = (u16*)A((size_t)(NSLOT + 256) * D_ * 2);
    u16* Hb   = (u16*)A((size_t)(NSLOT + 256) * DFF * 2);
    float* Yseg = (float*)A((size_t)NSLOT * D_ * 4);
    float* Ypart1 = (float*)W1T;                      // split-K second partial (33.5MB <= 67MB)
    const size_t needed = (off > attnEnd ? off : attnEnd);

    if (ws_size < needed) {
        sentinel<<<1, 1, 0, stream>>>(outw);
        return;
    }

    const dim3 blk(256);

    // ---- phase 0: input splits + attention weight transposes ----
    split2k<<<dim3((TDEC * D_) / 1024), blk, 0, stream>>>(dec, decH, decL, (long)TDEC * D_);
    split2k<<<dim3((TTXT * D_) / 1024), blk, 0, stream>>>(te, teH, teL, (long)TTXT * D_);
    for (int i = 0; i < 8; ++i)
        transpose_split<<<dim3(32, 32, 1), blk, 0, stream>>>(Win[i],
            wtHall + (size_t)i * D_ * D_, wtLall + (size_t)i * D_ * D_,
            D_, D_, D_, 0, 0, 1, D_, 0);

    // ---- phase 1: self-attention ----
    gemm_bt<1, 1, 128><<<dim3(24, 32, 1), blk, 0, stream>>>(decH, decL, wtHall, wtLall,
        nullptr, qkvH, qkvL, TDEC, 3 * D_, D_, D_, D_, 3 * D_, 0, 0, 0);
    transpose_split_hl<<<dim3(2, 32, BB * NH), blk, 0, stream>>>(qkvH + 2 * D_, qkvL + 2 * D_,
        vTH, vTL, SDEC, DHD, 3 * D_, (long)SDEC * 3 * D_, DHD, NH, SDEC, (long)DHD * SDEC);

    for (int b = 0; b < BB; ++b) {
        const long qo3 = (long)b * SDEC * 3 * D_;
        const long qo  = (long)b * SDEC * D_;
        gemm_bt<1, 0, 128><<<dim3(8, 8, NH), blk, 0, stream>>>(
            qkvH + qo3, qkvL + qo3, qkvH + qo3 + D_, qkvL + qo3 + D_,
            scores, nullptr, nullptr, SDEC, SDEC, DHD, 3 * D_, 3 * D_, SDEC,
            DHD, DHD, (long)SDEC * SDEC);
        softmax_split<<<dim3(NH * SDEC), blk, 0, stream>>>(scores, PH, PL, SDEC, 0.125f);
        gemm_bt<1, 1, 64><<<dim3(1, 8, NH), blk, 0, stream>>>(PH, PL,
            vTH + (long)b * NH * DHD * SDEC, vTL + (long)b * NH * DHD * SDEC,
            nullptr, aoH + qo, aoL + qo, SDEC, DHD, SDEC, SDEC, SDEC, D_,
            (long)SDEC * SDEC, (long)DHD * SDEC, DHD);
    }
    gemm_bt<1, 0, 128><<<dim3(8, 32, 1), blk, 0, stream>>>(aoH, aoL,
        wtHall + (size_t)3 * D_ * D_, wtLall + (size_t)3 * D_ * D_,
        of, nullptr, nullptr, TDEC, D_, D_, D_, D_, D_, 0, 0, 0);
    add_rmsnorm<<<dim3(TDEC), blk, 0, stream>>>(of, dec, g, x1f, x1H, x1L);

    // ---- phase 2: cross-attention ----
    gemm_bt<1, 1, 128><<<dim3(8, 32, 1), blk, 0, stream>>>(x1H, x1L,
        wtHall + (size_t)4 * D_ * D_, wtLall + (size_t)4 * D_ * D_,
        nullptr, q2H, q2L, TDEC, D_, D_, D_, D_, D_, 0, 0, 0);
    gemm_bt<1, 1, 128><<<dim3(16, 16, 1), blk, 0, stream>>>(teH, teL,
        wtHall + (size_t)5 * D_ * D_, wtLall + (size_t)5 * D_ * D_,
        nullptr, kv2H, kv2L, TTXT, 2 * D_, D_, D_, D_, 2 * D_, 0, 0, 0);
    transpose_split_hl<<<dim3(2, 16, BB * NH), blk, 0, stream>>>(kv2H + D_, kv2L + D_,
        vTH, vTL, STXT, DHD, 2 * D_, (long)STXT * 2 * D_, DHD, NH, STXT, (long)DHD * STXT);

    for (int b = 0; b < BB; ++b) {
        const long qo  = (long)b * SDEC * D_;
        const long ko2 = (long)b * STXT * 2 * D_;
        gemm_bt<1, 0, 128><<<dim3(4, 8, NH), blk, 0, stream>>>(
            q2H + qo, q2L + qo, kv2H + ko2, kv2L + ko2,
            scores, nullptr, nullptr, SDEC, STXT, DHD, D_, 2 * D_, STXT,
            DHD, DHD, (long)SDEC * STXT);
        softmax_split<<<dim3(NH * SDEC), blk, 0, stream>>>(scores, PH, PL, STXT, 0.125f);
        gemm_bt<1, 1, 64><<<dim3(1, 8, NH), blk, 0, stream>>>(PH, PL,
            vTH + (long)b * NH * DHD * STXT, vTL + (long)b * NH * DHD * STXT,
            nullptr, aoH + qo, aoL + qo, SDEC, DHD, STXT, STXT, STXT, D_,
            (long)SDEC * STXT, (long)DHD * STXT, DHD);
    }
    gemm_bt<1, 0, 128><<<dim3(8, 32, 1), blk, 0, stream>>>(aoH, aoL,
        wtHall + (size_t)7 * D_ * D_, wtLall + (size_t)7 * D_ * D_,
        of, nullptr, nullptr, TDEC, D_, D_, D_, D_, D_, 0, 0, 0);
    add_rmsnorm<<<dim3(TDEC), blk, 0, stream>>>(of, x1f, g, x2f, nullptr, nullptr);

    // ---- phase 3: router + expert bucketing + work lists ----
    hipMemsetAsync(counts, 0, 32, stream);
    hipMemsetAsync(desc1, 0xFF, (size_t)ND1 * 16, stream);
    hipMemsetAsync(desc2, 0xFF, (size_t)ND2 * 16, stream);
    router_topk<<<dim3(TDEC / 4), blk, 0, stream>>>(x2f, Wg, outw, outi, idx, tokw, counts, TDEC);
    scan_desc<<<1, 64, 0, stream>>>(counts, cursor, desc1, desc2);
    scatter_slots<<<dim3(TDEC / 256), blk, 0, stream>>>(idx, cursor, row_token, slot_of, TDEC);
    gather_bf16<<<dim3(NSLOT), blk, 0, stream>>>(x2f, row_token, Xg);

    // ---- phase 4: MoE FFN (persistent 128x128, split-K FFN2) + final norm ----
    transpose_split<<<dim3(DFF / 32, D_ / 32, NE), blk, 0, stream>>>(W1, W1T, nullptr,
        D_, DFF, DFF, (long)D_ * DFF, 0, 1, D_, (long)DFF * D_);
    transpose_split<<<dim3(D_ / 32, DFF / 32, NE), blk, 0, stream>>>(W2, W2T, nullptr,
        DFF, D_, D_, (long)D_ * DFF, 0, 1, DFF, (long)D_ * DFF);
    moe_gemm2<2><<<dim3(MOEGRID), blk, 0, stream>>>(Xg, D_, W1T, D_, (long)DFF * D_,
        nullptr, nullptr, Hb, DFF, desc1, ND1, 1024);
    moe_gemm2<0><<<dim3(MOEGRID), blk, 0, stream>>>(Hb, DFF, W2T, DFF, (long)D_ * DFF,
        Yseg, Ypart1, nullptr, D_, desc2, ND2, 2048);
    combine_rmsnorm<<<dim3(TDEC), blk, 0, stream>>>(Yseg, Ypart1, slot_of, tokw, x2f, g, outx);

    (void)in_sizes; (void)n_in; (void)out_size;
}

// Round 6
// 1400.677 us; speedup vs baseline: 1.4824x; 1.0372x over previous
//
#include <hip/hip_runtime.h>
#include <stdint.h>

#define D_    1024
#define BB    4
#define SDEC  1024
#define STXT  512
#define TDEC  4096
#define TTXT  2048
#define NH    16
#define DHD   64
#define NE    8
#define DFF   4096
#define NSLOT 8192
#define ND1   8192
#define ND2   4096
#define MOEGRID 1024

using u16 = unsigned short;
typedef __attribute__((ext_vector_type(8))) short bf16x8;
typedef __attribute__((ext_vector_type(4))) float f32x4;

__device__ __forceinline__ float bf2f(u16 h) {
    union { unsigned int u; float f; } x; x.u = ((unsigned int)h) << 16; return x.f;
}
__device__ __forceinline__ u16 f2bf(float f) {
    union { float f; unsigned int u; } x; x.f = f;
    unsigned int lsb = (x.u >> 16) & 1u;
    return (u16)((x.u + 0x7fffu + lsb) >> 16);
}

// async global->LDS, 16B per lane, linear LDS dest (wave-uniform base + lane*16)
__device__ __forceinline__ void gld16(const u16* g, u16* l) {
    __builtin_amdgcn_global_load_lds((const __attribute__((address_space(1))) void*)g,
                                     (__attribute__((address_space(3))) void*)l,
                                     16, 0, 0);
}

constexpr int BM = 128, BK = 32;

// ---------------------------------------------------------------------------
// Generic tiled GEMM (128-tile, 2-barrier): C[M,N] = A[M,K] * BT[N,K]^T.
// SPLIT=1: 3-pass split emulation. EPI: 0=f32, 1=split store, 2=relu+bf16.
// ---------------------------------------------------------------------------
template<int SPLIT, int EPI, int BROWS>
__global__ __launch_bounds__(256) void gemm_bt(
    const u16* __restrict__ AH, const u16* __restrict__ AL,
    const u16* __restrict__ BH, const u16* __restrict__ BL,
    float* __restrict__ Cf, u16* __restrict__ CH, u16* __restrict__ CL,
    int M, int N, int K, int lda, int ldb, int ldc,
    long strA, long strB, long strC)
{
    constexpr int WM = (BROWS == 64) ? 2 : 4;
    constexpr int ASZ = BM * BK, BSZ = BROWS * BK;
    __shared__ u16 smem[(SPLIT ? 2 : 1) * (ASZ + BSZ)];
    u16* sAH = smem;
    u16* sBH = smem + ASZ;
    u16* sAL = SPLIT ? smem + ASZ + BSZ : nullptr;
    u16* sBL = SPLIT ? smem + 2 * ASZ + BSZ : nullptr;

    const int z = blockIdx.z;
    const long zA = (long)z * strA, zB = (long)z * strB, zC = (long)z * strC;

    const int tileM = blockIdx.y * BM, tileN = blockIdx.x * BROWS;
    const int t = threadIdx.x;
    const int sr = t >> 2;
    const int sc = (t & 3) << 3;
    const u16* pA = AH + zA + (long)(tileM + sr) * lda + sc;
    const u16* pB = BH + zB + (long)(tileN + sr) * ldb + sc;
    const u16* pAl = nullptr; const u16* pBl = nullptr;
    if constexpr (SPLIT) {
        pAl = AL + zA + (long)(tileM + sr) * lda + sc;
        pBl = BL + zB + (long)(tileN + sr) * ldb + sc;
    }
    const long hA = 64L * lda, hB = 64L * ldb;

    const int lane = t & 63;
    const int wv = t >> 6;
    const int wr = (BROWS == 64) ? (wv << 5) : ((wv >> 1) << 6);
    const int wc = (BROWS == 64) ? 0 : ((wv & 1) << 6);
    const int fr = lane & 15, kg = lane >> 4;

    f32x4 acc[WM][4];
    const f32x4 vzero = {0.f, 0.f, 0.f, 0.f};
#pragma unroll
    for (int m = 0; m < WM; ++m)
#pragma unroll
        for (int n = 0; n < 4; ++n) acc[m][n] = vzero;

    for (int k0 = 0; k0 < K; k0 += BK) {
        gld16(pA + k0,      sAH + t * 8);
        gld16(pA + k0 + hA, sAH + 2048 + t * 8);
        gld16(pB + k0,      sBH + t * 8);
        if constexpr (BROWS == 128) gld16(pB + k0 + hB, sBH + 2048 + t * 8);
        if constexpr (SPLIT) {
            gld16(pAl + k0,      sAL + t * 8);
            gld16(pAl + k0 + hA, sAL + 2048 + t * 8);
            gld16(pBl + k0,      sBL + t * 8);
            if constexpr (BROWS == 128) gld16(pBl + k0 + hB, sBL + 2048 + t * 8);
        }
        __syncthreads();

        bf16x8 fa[WM], fb[4], fal[WM], fbl[4];
#pragma unroll
        for (int m = 0; m < WM; ++m) {
            fa[m] = *(const bf16x8*)&sAH[(wr + m * 16 + fr) * BK + (kg << 3)];
            if constexpr (SPLIT) fal[m] = *(const bf16x8*)&sAL[(wr + m * 16 + fr) * BK + (kg << 3)];
        }
#pragma unroll
        for (int n = 0; n < 4; ++n) {
            fb[n] = *(const bf16x8*)&sBH[(wc + n * 16 + fr) * BK + (kg << 3)];
            if constexpr (SPLIT) fbl[n] = *(const bf16x8*)&sBL[(wc + n * 16 + fr) * BK + (kg << 3)];
        }
#pragma unroll
        for (int m = 0; m < WM; ++m)
#pragma unroll
            for (int n = 0; n < 4; ++n) {
                acc[m][n] = __builtin_amdgcn_mfma_f32_16x16x32_bf16(fa[m], fb[n], acc[m][n], 0, 0, 0);
                if constexpr (SPLIT) {
                    acc[m][n] = __builtin_amdgcn_mfma_f32_16x16x32_bf16(fa[m],  fbl[n], acc[m][n], 0, 0, 0);
                    acc[m][n] = __builtin_amdgcn_mfma_f32_16x16x32_bf16(fal[m], fb[n],  acc[m][n], 0, 0, 0);
                }
            }
        __syncthreads();
    }

#pragma unroll
    for (int m = 0; m < WM; ++m) {
        const int r0 = tileM + wr + m * 16 + (kg << 2);
#pragma unroll
        for (int n = 0; n < 4; ++n) {
            const int col = tileN + wc + n * 16 + fr;
            if (col >= N) continue;
#pragma unroll
            for (int i = 0; i < 4; ++i) {
                const int r = r0 + i;
                if (r >= M) continue;
                const float v = acc[m][n][i];
                const long off = zC + (long)r * ldc + col;
                if constexpr (EPI == 0) {
                    Cf[off] = v;
                } else if constexpr (EPI == 1) {
                    const u16 h = f2bf(v);
                    CH[off] = h;
                    CL[off] = f2bf(v - bf2f(h));
                } else {
                    CH[off] = f2bf(fmaxf(v, 0.f));
                }
            }
        }
    }
}

// ---------------------------------------------------------------------------
// PV GEMM with split-K=4: O_part[kq] = P[M,Skv/4-slice] * vT[64,Skv/4-slice]^T.
// 3-pass split. grid (4, M/128, NH). Deterministic exclusive partial stores.
// Op layout [4][NH][1024][64] f32.
// ---------------------------------------------------------------------------
__global__ __launch_bounds__(256) void pv_gemm(
    const u16* __restrict__ PHp, const u16* __restrict__ PLp,
    const u16* __restrict__ VTH, const u16* __restrict__ VTL,
    float* __restrict__ Op, int Skv)
{
    __shared__ u16 smem[12288];   // A H/L 8K+8K B H/L 4K+4K bytes
    u16* sAH = smem;
    u16* sAL = smem + 4096;
    u16* sBH = smem + 8192;
    u16* sBL = smem + 10240;

    const int kq = blockIdx.x;
    const int tileM = blockIdx.y * 128;
    const int z = blockIdx.z;
    const int kbase = kq * (Skv >> 2);
    const int nks = Skv >> 7;   // (Skv/4)/32

    const int t = threadIdx.x;
    const int sr = t >> 2, sc = (t & 3) << 3;
    const u16* pA  = PHp + (long)z * 1024 * Skv + (long)(tileM + sr) * Skv + kbase + sc;
    const u16* pAl = PLp + (long)z * 1024 * Skv + (long)(tileM + sr) * Skv + kbase + sc;
    const u16* pB  = VTH + (long)z * 64 * Skv + (long)sr * Skv + kbase + sc;
    const u16* pBl = VTL + (long)z * 64 * Skv + (long)sr * Skv + kbase + sc;
    const long hA = 64L * Skv;

    const int lane = t & 63, wv = t >> 6;
    const int wr = wv << 5;   // 4 waves x 32 rows
    const int fr = lane & 15, kg = lane >> 4;

    f32x4 acc[2][4];
    const f32x4 vzero = {0.f, 0.f, 0.f, 0.f};
#pragma unroll
    for (int m = 0; m < 2; ++m)
#pragma unroll
        for (int n = 0; n < 4; ++n) acc[m][n] = vzero;

    for (int ks = 0; ks < nks; ++ks) {
        const long k0 = (long)ks << 5;
        gld16(pA + k0,       sAH + t * 8);
        gld16(pA + k0 + hA,  sAH + 2048 + t * 8);
        gld16(pAl + k0,      sAL + t * 8);
        gld16(pAl + k0 + hA, sAL + 2048 + t * 8);
        gld16(pB + k0,       sBH + t * 8);
        gld16(pBl + k0,      sBL + t * 8);
        __syncthreads();
        bf16x8 fa[2], fb[4], fal[2], fbl[4];
#pragma unroll
        for (int m = 0; m < 2; ++m) {
            fa[m]  = *(const bf16x8*)&sAH[(wr + m * 16 + fr) * 32 + (kg << 3)];
            fal[m] = *(const bf16x8*)&sAL[(wr + m * 16 + fr) * 32 + (kg << 3)];
        }
#pragma unroll
        for (int n = 0; n < 4; ++n) {
            fb[n]  = *(const bf16x8*)&sBH[(n * 16 + fr) * 32 + (kg << 3)];
            fbl[n] = *(const bf16x8*)&sBL[(n * 16 + fr) * 32 + (kg << 3)];
        }
#pragma unroll
        for (int m = 0; m < 2; ++m)
#pragma unroll
            for (int n = 0; n < 4; ++n) {
                acc[m][n] = __builtin_amdgcn_mfma_f32_16x16x32_bf16(fa[m],  fb[n],  acc[m][n], 0, 0, 0);
                acc[m][n] = __builtin_amdgcn_mfma_f32_16x16x32_bf16(fa[m],  fbl[n], acc[m][n], 0, 0, 0);
                acc[m][n] = __builtin_amdgcn_mfma_f32_16x16x32_bf16(fal[m], fb[n],  acc[m][n], 0, 0, 0);
            }
        __syncthreads();
    }

    const long base = ((long)kq * NH + z) * 65536;   // 1024*64
#pragma unroll
    for (int m = 0; m < 2; ++m) {
        const int r0 = tileM + wr + m * 16 + (kg << 2);
#pragma unroll
        for (int n = 0; n < 4; ++n) {
            const int col = n * 16 + fr;
#pragma unroll
            for (int i = 0; i < 4; ++i)
                Op[base + (long)(r0 + i) * 64 + col] = acc[m][n][i];
        }
    }
}

// ---------------------------------------------------------------------------
// Sum 4 PV partials, split to aoH/aoL. Op [4][NH][1024][64]; out row-major [1024][D_].
// ---------------------------------------------------------------------------
__global__ __launch_bounds__(256) void pv_combine(
    const float* __restrict__ Op, u16* __restrict__ aoH, u16* __restrict__ aoL)
{
    const long i = ((long)blockIdx.x * 256 + threadIdx.x) * 4;   // over NH*1024*64
    const int z = (int)(i >> 16);
    const int rem = (int)(i & 65535);
    const int r = rem >> 6, c = rem & 63;
    float4 v = *(const float4*)(Op + i);
    const float4 v1 = *(const float4*)(Op + 1048576 + i);
    const float4 v2 = *(const float4*)(Op + 2097152 + i);
    const float4 v3 = *(const float4*)(Op + 3145728 + i);
    v.x += v1.x + v2.x + v3.x;
    v.y += v1.y + v2.y + v3.y;
    v.z += v1.z + v2.z + v3.z;
    v.w += v1.w + v2.w + v3.w;
    const long dst = (long)r * D_ + z * 64 + c;
    u16 h0 = f2bf(v.x), h1 = f2bf(v.y), h2 = f2bf(v.z), h3 = f2bf(v.w);
    uint2 hh;
    hh.x = (unsigned)h0 | ((unsigned)h1 << 16);
    hh.y = (unsigned)h2 | ((unsigned)h3 << 16);
    *(uint2*)(aoH + dst) = hh;
    u16 l0 = f2bf(v.x - bf2f(h0)), l1 = f2bf(v.y - bf2f(h1));
    u16 l2 = f2bf(v.z - bf2f(h2)), l3 = f2bf(v.w - bf2f(h3));
    uint2 ll;
    ll.x = (unsigned)l0 | ((unsigned)l1 << 16);
    ll.y = (unsigned)l2 | ((unsigned)l3 << 16);
    *(uint2*)(aoL + dst) = ll;
}

// ---------------------------------------------------------------------------
// MoE persistent GEMM, 3-slot counted-vmcnt ring (T3/T4).
//   - 256 threads = 4 waves (2x2), 128x128 tile, BK=32.
//   - LDS: 3 slots x 16KB = 48KB -> 3 blocks/CU.
//   - Pipeline: iter ks: stage slot ks+2; ds_read+MFMA ks; vmcnt(4) (only the
//     newest slot in flight) + barrier. Prefetch distance 2 hides HBM latency
//     under ~2 MFMA phases.
//   - XOR swizzle (both-sides): staged global col chunk = (t&3)^((t>>3)&3);
//     read chunk = kg^((row>>1)&3). Verified 0 bank conflicts (round 5).
// ---------------------------------------------------------------------------
template<int EPI>
__global__ __launch_bounds__(256, 3) void moe_gemm2(
    const u16* __restrict__ Ag, int lda,
    const u16* __restrict__ BTbase, int ldb, long btStride,
    float* __restrict__ Cf0, float* __restrict__ Cf1, u16* __restrict__ CH, int ldc,
    const int4* __restrict__ desc, int ndesc, int Kiter)
{
    __shared__ u16 smem[24576];   // 48 KB: 3 slots x [A 4096 | B 4096] elems
    const int t = threadIdx.x;
    const int lane = t & 63, wv = t >> 6;
    const int wr = (wv >> 1) << 6, wc = (wv & 1) << 6;
    const int fr = lane & 15, kg = lane >> 4;
    const int nks = Kiter >> 5;

    const int rS = t >> 2;
    const int cS = ((t & 3) ^ ((t >> 3) & 3)) << 3;

    int ldsA[4], ldsB[4];
#pragma unroll
    for (int m = 0; m < 4; ++m) {
        const int ra = wr + m * 16 + fr;
        ldsA[m] = ra * 32 + ((kg ^ ((ra >> 1) & 3)) << 3);
        const int rb = wc + m * 16 + fr;
        ldsB[m] = rb * 32 + ((kg ^ ((rb >> 1) & 3)) << 3);
    }

    for (int p = blockIdx.x; p < ndesc; p += MOEGRID) {
        const int4 d = desc[p];
        if (d.x < 0) continue;
        const int rowbase = d.x, colbase = d.y & 0xFFFF, e = d.y >> 16;
        const int kbase = d.z, s1 = d.w;
        const u16* paS = Ag + (long)(rowbase + rS) * lda + kbase + cS;
        const u16* pbS = BTbase + (long)e * btStride + (long)(colbase + rS) * ldb + kbase + cS;
        const long hA = 64L * lda, hB = 64L * ldb;

        f32x4 acc[4][4];
        const f32x4 vzero = {0.f, 0.f, 0.f, 0.f};
#pragma unroll
        for (int m = 0; m < 4; ++m)
#pragma unroll
            for (int n = 0; n < 4; ++n) acc[m][n] = vzero;

#define STG(ks) { const int s_ = (ks) % 3; const long k0_ = (long)(ks) << 5; \
        u16* b_ = smem + s_ * 8192; \
        gld16(paS + k0_,      b_ + t * 8); \
        gld16(paS + k0_ + hA, b_ + 2048 + t * 8); \
        gld16(pbS + k0_,      b_ + 4096 + t * 8); \
        gld16(pbS + k0_ + hB, b_ + 6144 + t * 8); }

        STG(0); STG(1);
        asm volatile("s_waitcnt vmcnt(4)" ::: "memory");
        __builtin_amdgcn_s_barrier();
        __builtin_amdgcn_sched_barrier(0);

        for (int ks = 0; ks < nks; ++ks) {
            if (ks + 2 < nks) STG(ks + 2);
            const u16* sA = smem + (ks % 3) * 8192;
            const u16* sB = sA + 4096;
            bf16x8 fa[4], fb[4];
#pragma unroll
            for (int m = 0; m < 4; ++m) fa[m] = *(const bf16x8*)&sA[ldsA[m]];
#pragma unroll
            for (int n = 0; n < 4; ++n) fb[n] = *(const bf16x8*)&sB[ldsB[n]];
            __builtin_amdgcn_s_setprio(1);
#pragma unroll
            for (int m = 0; m < 4; ++m)
#pragma unroll
                for (int n = 0; n < 4; ++n)
                    acc[m][n] = __builtin_amdgcn_mfma_f32_16x16x32_bf16(fa[m], fb[n], acc[m][n], 0, 0, 0);
            __builtin_amdgcn_s_setprio(0);
            if (ks + 2 < nks) { asm volatile("s_waitcnt vmcnt(4)" ::: "memory"); }
            else              { asm volatile("s_waitcnt vmcnt(0)" ::: "memory"); }
            __builtin_amdgcn_s_barrier();
            __builtin_amdgcn_sched_barrier(0);
        }
#undef STG

        float* __restrict__ C = (EPI == 0) ? ((kbase == 0) ? Cf0 : Cf1) : nullptr;
#pragma unroll
        for (int m = 0; m < 4; ++m) {
            const int r0 = rowbase + wr + m * 16 + (kg << 2);
#pragma unroll
            for (int n = 0; n < 4; ++n) {
                const int col = colbase + wc + n * 16 + fr;
#pragma unroll
                for (int i = 0; i < 4; ++i) {
                    const int r = r0 + i;
                    if (r >= s1) continue;
                    const float v = acc[m][n][i];
                    const long off = (long)r * ldc + col;
                    if constexpr (EPI == 0) C[off] = v;
                    else                    CH[off] = f2bf(fmaxf(v, 0.f));
                }
            }
        }
    }
}

// ---------------------------------------------------------------------------
__global__ __launch_bounds__(256) void split2k(const float* __restrict__ in,
                                               u16* __restrict__ oh, u16* __restrict__ ol, long n)
{
    long i = ((long)blockIdx.x * 256 + threadIdx.x) * 4;
    if (i >= n) return;
    float4 v = *(const float4*)(in + i);
    u16 h0 = f2bf(v.x), h1 = f2bf(v.y), h2 = f2bf(v.z), h3 = f2bf(v.w);
    uint2 oo;
    oo.x = (unsigned)h0 | ((unsigned)h1 << 16);
    oo.y = (unsigned)h2 | ((unsigned)h3 << 16);
    *(uint2*)(oh + i) = oo;
    if (ol) {
        u16 l0 = f2bf(v.x - bf2f(h0)), l1 = f2bf(v.y - bf2f(h1));
        u16 l2 = f2bf(v.z - bf2f(h2)), l3 = f2bf(v.w - bf2f(h3));
        uint2 ll;
        ll.x = (unsigned)l0 | ((unsigned)l1 << 16);
        ll.y = (unsigned)l2 | ((unsigned)l3 << 16);
        *(uint2*)(ol + i) = ll;
    }
}

// ---------------------------------------------------------------------------
__global__ __launch_bounds__(256) void transpose_split(
    const float* __restrict__ in, u16* __restrict__ oh, u16* __restrict__ ol,
    int R, int C, int ild, long ibs1, long ibs2, int nb2, int old_, long obs)
{
    __shared__ float tile[32][33];
    const int z = blockIdx.z;
    const float* ip = in + (long)(z / nb2) * ibs1 + (long)(z % nb2) * ibs2;
    u16* ohp = oh + (long)z * obs;
    u16* olp = ol ? ol + (long)z * obs : nullptr;
    const int c0 = blockIdx.x * 32, r0 = blockIdx.y * 32;
    const int tx = threadIdx.x & 31, ty = threadIdx.x >> 5;
    for (int i = ty; i < 32; i += 8) {
        int r = r0 + i, c = c0 + tx;
        tile[i][tx] = (r < R && c < C) ? ip[(long)r * ild + c] : 0.f;
    }
    __syncthreads();
    for (int i = ty; i < 32; i += 8) {
        int oc = c0 + i, orr = r0 + tx;
        if (oc < C && orr < R) {
            float v = tile[tx][i];
            u16 h = f2bf(v);
            ohp[(long)oc * old_ + orr] = h;
            if (olp) olp[(long)oc * old_ + orr] = f2bf(v - bf2f(h));
        }
    }
}

// ---------------------------------------------------------------------------
__global__ __launch_bounds__(256) void transpose_split_hl(
    const u16* __restrict__ inH, const u16* __restrict__ inL,
    u16* __restrict__ oh, u16* __restrict__ ol,
    int R, int C, int ild, long ibs1, long ibs2, int nb2, int old_, long obs)
{
    __shared__ float tile[32][33];
    const int z = blockIdx.z;
    const long base = (long)(z / nb2) * ibs1 + (long)(z % nb2) * ibs2;
    u16* ohp = oh + (long)z * obs;
    u16* olp = ol + (long)z * obs;
    const int c0 = blockIdx.x * 32, r0 = blockIdx.y * 32;
    const int tx = threadIdx.x & 31, ty = threadIdx.x >> 5;
    for (int i = ty; i < 32; i += 8) {
        int r = r0 + i, c = c0 + tx;
        float v = 0.f;
        if (r < R && c < C) {
            const long o = base + (long)r * ild + c;
            v = bf2f(inH[o]) + bf2f(inL[o]);
        }
        tile[i][tx] = v;
    }
    __syncthreads();
    for (int i = ty; i < 32; i += 8) {
        int oc = c0 + i, orr = r0 + tx;
        if (oc < C && orr < R) {
            float v = tile[tx][i];
            u16 h = f2bf(v);
            ohp[(long)oc * old_ + orr] = h;
            olp[(long)oc * old_ + orr] = f2bf(v - bf2f(h));
        }
    }
}

// ---------------------------------------------------------------------------
__global__ __launch_bounds__(256) void softmax_split(
    const float* __restrict__ s, u16* __restrict__ ph, u16* __restrict__ pl,
    int cols, float scale)
{
    const float* p = s + (long)blockIdx.x * cols;
    u16* php = ph + (long)blockIdx.x * cols;
    u16* plp = pl + (long)blockIdx.x * cols;
    const int t = threadIdx.x;
    float v[4];
    int vpt;
    if (cols == 1024) {
        vpt = 4;
        float4 x = ((const float4*)p)[t];
        v[0] = x.x * scale; v[1] = x.y * scale; v[2] = x.z * scale; v[3] = x.w * scale;
    } else {
        vpt = 2;
        float2 x = ((const float2*)p)[t];
        v[0] = x.x * scale; v[1] = x.y * scale; v[2] = -3.4e38f; v[3] = -3.4e38f;
    }
    float mx = fmaxf(fmaxf(v[0], v[1]), fmaxf(v[2], v[3]));
#pragma unroll
    for (int o = 32; o; o >>= 1) mx = fmaxf(mx, __shfl_xor(mx, o));
    __shared__ float sm[4];
    const int wv = t >> 6, ln = t & 63;
    if (ln == 0) sm[wv] = mx;
    __syncthreads();
    mx = fmaxf(fmaxf(sm[0], sm[1]), fmaxf(sm[2], sm[3]));
    float sum = 0.f;
    for (int i = 0; i < vpt; ++i) { v[i] = expf(v[i] - mx); sum += v[i]; }
#pragma unroll
    for (int o = 32; o; o >>= 1) sum += __shfl_xor(sum, o);
    __shared__ float ss[4];
    if (ln == 0) ss[wv] = sum;
    __syncthreads();
    sum = ss[0] + ss[1] + ss[2] + ss[3];
    const float inv = 1.f / sum;
    if (cols == 1024) {
        float q0 = v[0] * inv, q1 = v[1] * inv, q2 = v[2] * inv, q3 = v[3] * inv;
        u16 h0 = f2bf(q0), h1 = f2bf(q1), h2 = f2bf(q2), h3 = f2bf(q3);
        uint2 hh; hh.x = (unsigned)h0 | ((unsigned)h1 << 16); hh.y = (unsigned)h2 | ((unsigned)h3 << 16);
        ((uint2*)php)[t] = hh;
        u16 l0 = f2bf(q0 - bf2f(h0)), l1 = f2bf(q1 - bf2f(h1));
        u16 l2 = f2bf(q2 - bf2f(h2)), l3 = f2bf(q3 - bf2f(h3));
        uint2 ll; ll.x = (unsigned)l0 | ((unsigned)l1 << 16); ll.y = (unsigned)l2 | ((unsigned)l3 << 16);
        ((uint2*)plp)[t] = ll;
    } else {
        float q0 = v[0] * inv, q1 = v[1] * inv;
        u16 h0 = f2bf(q0), h1 = f2bf(q1);
        ((unsigned*)php)[t] = (unsigned)h0 | ((unsigned)h1 << 16);
        u16 l0 = f2bf(q0 - bf2f(h0)), l1 = f2bf(q1 - bf2f(h1));
        ((unsigned*)plp)[t] = (unsigned)l0 | ((unsigned)l1 << 16);
    }
}

// ---------------------------------------------------------------------------
__global__ __launch_bounds__(256) void add_rmsnorm(
    const float* __restrict__ a, const float* __restrict__ b, const float* __restrict__ g,
    float* __restrict__ xo, u16* __restrict__ xh, u16* __restrict__ xl)
{
    const long row = blockIdx.x;
    const int t = threadIdx.x;
    const float* pa = a + row * D_;
    const float* pb = b + row * D_;
    float v[4]; double ssq = 0.0;
#pragma unroll
    for (int i = 0; i < 4; ++i) {
        int c = t + (i << 8);
        v[i] = pa[c] + pb[c];
        ssq += (double)v[i] * v[i];
    }
#pragma unroll
    for (int o = 32; o; o >>= 1) ssq += __shfl_xor(ssq, o);
    __shared__ double sd[4];
    if ((t & 63) == 0) sd[t >> 6] = ssq;
    __syncthreads();
    ssq = sd[0] + sd[1] + sd[2] + sd[3];
    const float rs = (float)(1.0 / sqrt(ssq * (1.0 / 1024.0) + 1e-6));
#pragma unroll
    for (int i = 0; i < 4; ++i) {
        int c = t + (i << 8);
        float o = v[i] * rs * g[c];
        xo[row * D_ + c] = o;
        if (xh) {
            u16 h = f2bf(o);
            xh[row * D_ + c] = h;
            if (xl) xl[row * D_ + c] = f2bf(o - bf2f(h));
        }
    }
}

// ---------------------------------------------------------------------------
__global__ __launch_bounds__(256) void router_topk(
    const float* __restrict__ x2, const float* __restrict__ Wg,
    float* __restrict__ outw, float* __restrict__ outi,
    int* __restrict__ idx, float* __restrict__ tokw, int* __restrict__ counts, int T)
{
    const int wid = (int)((blockIdx.x * 256 + threadIdx.x) >> 6);
    const int lane = threadIdx.x & 63;
    if (wid >= T) return;
    float acc[NE];
#pragma unroll
    for (int e = 0; e < NE; ++e) acc[e] = 0.f;
    const float* xr = x2 + (long)wid * D_;
    for (int i = 0; i < 16; ++i) {
        float xv = xr[i * 64 + lane];
        const float* wr = Wg + (long)(i * 64 + lane) * NE;
#pragma unroll
        for (int e = 0; e < NE; ++e) acc[e] += xv * wr[e];
    }
#pragma unroll
    for (int e = 0; e < NE; ++e)
#pragma unroll
        for (int o = 32; o; o >>= 1) acc[e] += __shfl_xor(acc[e], o);
    if (lane == 0) {
        float m = acc[0];
#pragma unroll
        for (int e = 1; e < NE; ++e) m = fmaxf(m, acc[e]);
        float p[NE], s = 0.f;
#pragma unroll
        for (int e = 0; e < NE; ++e) { p[e] = expf(acc[e] - m); s += p[e]; }
        const float invs = 1.f / s;
#pragma unroll
        for (int e = 0; e < NE; ++e) p[e] *= invs;
        int e0 = 0;
#pragma unroll
        for (int e = 1; e < NE; ++e) if (p[e] > p[e0]) e0 = e;
        int e1 = (e0 == 0) ? 1 : 0;
#pragma unroll
        for (int e = 0; e < NE; ++e) if (e != e0 && e != e1 && p[e] > p[e1]) e1 = e;
        float w0 = p[e0], w1 = p[e1];
        const float sw = 1.f / (w0 + w1);
        w0 *= sw; w1 *= sw;
        outw[2 * wid] = w0;      outw[2 * wid + 1] = w1;
        outi[2 * wid] = (float)e0; outi[2 * wid + 1] = (float)e1;
        idx[2 * wid] = e0;       idx[2 * wid + 1] = e1;
        tokw[2 * wid] = w0;      tokw[2 * wid + 1] = w1;
        atomicAdd(&counts[e0], 1);
        atomicAdd(&counts[e1], 1);
    }
}

// ---------------------------------------------------------------------------
__global__ void scan_desc(const int* __restrict__ counts, int* __restrict__ cursor,
                          int4* __restrict__ d1, int4* __restrict__ d2)
{
    __shared__ int sseg[NE + 1];
    if (threadIdx.x == 0) {
        int a = 0;
        for (int e = 0; e < NE; ++e) { sseg[e] = a; cursor[e] = a; a += counts[e]; }
        sseg[NE] = a;
    }
    __syncthreads();
    const int e = threadIdx.x;
    if (e < NE) {
        const int s0 = sseg[e], s1 = sseg[e + 1];
        const int nyt = (s1 - s0 + 127) >> 7;
        for (int xt = 0; xt < 32; ++xt)
            for (int yt = 0; yt < nyt; ++yt)
                d1[e + 8 * (xt * nyt + yt)] =
                    make_int4(s0 + yt * 128, (xt * 128) | (e << 16), 0, s1);
        for (int kh = 0; kh < 2; ++kh)
            for (int xt = 0; xt < 8; ++xt)
                for (int yt = 0; yt < nyt; ++yt)
                    d2[e + 8 * ((kh * 8 + xt) * nyt + yt)] =
                        make_int4(s0 + yt * 128, (xt * 128) | (e << 16), kh * 2048, s1);
    }
}

__global__ __launch_bounds__(256) void scatter_slots(
    const int* __restrict__ idx, int* __restrict__ cursor,
    int* __restrict__ row_token, int* __restrict__ slot_of, int T)
{
    const int t = blockIdx.x * 256 + threadIdx.x;
    if (t >= T) return;
#pragma unroll
    for (int k = 0; k < 2; ++k) {
        const int e = idx[2 * t + k];
        const int pos = atomicAdd(&cursor[e], 1);
        row_token[pos] = t;
        slot_of[2 * t + k] = pos;
    }
}

__global__ __launch_bounds__(256) void gather_bf16(
    const float* __restrict__ x2, const int* __restrict__ row_token, u16* __restrict__ Xg)
{
    const int r = blockIdx.x;
    const int t = threadIdx.x;
    const float* src = x2 + (long)row_token[r] * D_ + t * 4;
    float4 v = *(const float4*)src;
    uint2 oo;
    oo.x = (unsigned)f2bf(v.x) | ((unsigned)f2bf(v.y) << 16);
    oo.y = (unsigned)f2bf(v.z) | ((unsigned)f2bf(v.w) << 16);
    *(uint2*)(Xg + (long)r * D_ + t * 4) = oo;
}

// ---------------------------------------------------------------------------
__global__ __launch_bounds__(256) void combine_rmsnorm(
    const float* __restrict__ Y0, const float* __restrict__ Y1,
    const int* __restrict__ slot_of, const float* __restrict__ tokw,
    const float* __restrict__ x2, const float* __restrict__ g, float* __restrict__ out)
{
    const long tr = blockIdx.x;
    const int t = threadIdx.x;
    const int s0 = slot_of[2 * tr], s1 = slot_of[2 * tr + 1];
    const float w0 = tokw[2 * tr], w1 = tokw[2 * tr + 1];
    const float* ya0 = Y0 + (long)s0 * D_;
    const float* yb0 = Y1 + (long)s0 * D_;
    const float* ya1 = Y0 + (long)s1 * D_;
    const float* yb1 = Y1 + (long)s1 * D_;
    const float* xr = x2 + tr * D_;
    float v[4]; double ssq = 0.0;
#pragma unroll
    for (int i = 0; i < 4; ++i) {
        int c = t + (i << 8);
        v[i] = w0 * (ya0[c] + yb0[c]) + w1 * (ya1[c] + yb1[c]) + xr[c];
        ssq += (double)v[i] * v[i];
    }
#pragma unroll
    for (int o = 32; o; o >>= 1) ssq += __shfl_xor(ssq, o);
    __shared__ double sd[4];
    if ((t & 63) == 0) sd[t >> 6] = ssq;
    __syncthreads();
    ssq = sd[0] + sd[1] + sd[2] + sd[3];
    const float rs = (float)(1.0 / sqrt(ssq * (1.0 / 1024.0) + 1e-6));
#pragma unroll
    for (int i = 0; i < 4; ++i) {
        int c = t + (i << 8);
        out[tr * D_ + c] = v[i] * rs * g[c];
    }
}

__global__ void sentinel(float* o) { o[0] = 12345.0f; }

// ---------------------------------------------------------------------------
extern "C" void kernel_launch(void* const* d_in, const int* in_sizes, int n_in,
                              void* d_out, int out_size, void* d_ws, size_t ws_size,
                              hipStream_t stream)
{
    const float* dec = (const float*)d_in[0];
    const float* te  = (const float*)d_in[1];
    const float* Win[8] = { (const float*)d_in[2], (const float*)d_in[3], (const float*)d_in[4],
                            (const float*)d_in[5], (const float*)d_in[6], (const float*)d_in[7],
                            (const float*)d_in[8], (const float*)d_in[9] };
    const float* g  = (const float*)d_in[10];
    const float* Wg = (const float*)d_in[11];
    const float* W1 = (const float*)d_in[12];
    const float* W2 = (const float*)d_in[13];
    float* outw = (float*)d_out;
    float* outi = outw + 2 * TDEC;
    float* outx = outw + 4 * TDEC;

    char* ws = (char*)d_ws;
    size_t off = 0;
    auto A = [&](size_t bytes) -> char* {
        char* p = ws + off;
        off += (bytes + 255) & ~(size_t)255;
        return p;
    };

    // ---- persistent region ----
    u16* decH = (u16*)A((size_t)TDEC * D_ * 2);
    u16* decL = (u16*)A((size_t)TDEC * D_ * 2);
    u16* teH  = (u16*)A((size_t)TTXT * D_ * 2);
    u16* teL  = (u16*)A((size_t)TTXT * D_ * 2);
    u16* wtHall = (u16*)A((size_t)8 * D_ * D_ * 2);
    u16* wtLall = (u16*)A((size_t)8 * D_ * D_ * 2);
    float* x1f = (float*)A((size_t)TDEC * D_ * 4);
    float* x2f = (float*)A((size_t)TDEC * D_ * 4);
    float* tokw = (float*)A(NSLOT * 4);
    int* idx    = (int*)A(NSLOT * 4);
    int* counts = (int*)A(256);
    int* cursor = (int*)A(256);
    int* row_token = (int*)A(NSLOT * 4);
    int* slot_of   = (int*)A(NSLOT * 4);
    int4* desc1 = (int4*)A((size_t)ND1 * 16);
    int4* desc2 = (int4*)A((size_t)ND2 * 16);

    // ---- shared region R: attention view ----
    const size_t Rbase = off;
    float* scores = (float*)A((size_t)NH * SDEC * SDEC * 4);
    u16* PH = (u16*)A((size_t)NH * SDEC * SDEC * 2);
    u16* PL = (u16*)A((size_t)NH * SDEC * SDEC * 2);
    u16* qkvH = (u16*)A((size_t)TDEC * 3 * D_ * 2);
    u16* qkvL = (u16*)A((size_t)TDEC * 3 * D_ * 2);
    u16* q2H  = (u16*)A((size_t)TDEC * D_ * 2);
    u16* q2L  = (u16*)A((size_t)TDEC * D_ * 2);
    u16* kv2H = (u16*)A((size_t)TTXT * 2 * D_ * 2);
    u16* kv2L = (u16*)A((size_t)TTXT * 2 * D_ * 2);
    u16* vTH = (u16*)A((size_t)TDEC * D_ * 2);
    u16* vTL = (u16*)A((size_t)TDEC * D_ * 2);
    u16* aoH = (u16*)A((size_t)TDEC * D_ * 2);
    u16* aoL = (u16*)A((size_t)TDEC * D_ * 2);
    u16* x1H = (u16*)A((size_t)TDEC * D_ * 2);
    u16* x1L = (u16*)A((size_t)TDEC * D_ * 2);
    float* of = (float*)A((size_t)TDEC * D_ * 4);
    float* Opart = (float*)A((size_t)4 * NH * SDEC * DHD * 4);   // 16.8 MB PV split-K partials
    const size_t attnEnd = off;

    // ---- shared region R: MoE view (overlays attention view) ----
    off = Rbase;
    u16* W1T  = (u16*)A((size_t)NE * DFF * D_ * 2);   // dead after FFN1; reused as Ypart1
    u16* W2T  = (u16*)A((size_t)NE * D_ * DFF * 2);
    u16* Xg   = (u16*)A((size_t)(NSLOT + 256) * D_ * 2);
    u16* Hb   = (u16*)A((size_t)(NSLOT + 256) * DFF * 2);
    float* Yseg = (float*)A((size_t)NSLOT * D_ * 4);
    float* Ypart1 = (float*)W1T;
    const size_t needed = (off > attnEnd ? off : attnEnd);

    if (ws_size < needed) {
        sentinel<<<1, 1, 0, stream>>>(outw);
        return;
    }

    const dim3 blk(256);

    // ---- phase 0: input splits + attention weight transposes ----
    split2k<<<dim3((TDEC * D_) / 1024), blk, 0, stream>>>(dec, decH, decL, (long)TDEC * D_);
    split2k<<<dim3((TTXT * D_) / 1024), blk, 0, stream>>>(te, teH, teL, (long)TTXT * D_);
    for (int i = 0; i < 8; ++i)
        transpose_split<<<dim3(32, 32, 1), blk, 0, stream>>>(Win[i],
            wtHall + (size_t)i * D_ * D_, wtLall + (size_t)i * D_ * D_,
            D_, D_, D_, 0, 0, 1, D_, 0);

    // ---- phase 1: self-attention ----
    gemm_bt<1, 1, 128><<<dim3(24, 32, 1), blk, 0, stream>>>(decH, decL, wtHall, wtLall,
        nullptr, qkvH, qkvL, TDEC, 3 * D_, D_, D_, D_, 3 * D_, 0, 0, 0);
    transpose_split_hl<<<dim3(2, 32, BB * NH), blk, 0, stream>>>(qkvH + 2 * D_, qkvL + 2 * D_,
        vTH, vTL, SDEC, DHD, 3 * D_, (long)SDEC * 3 * D_, DHD, NH, SDEC, (long)DHD * SDEC);

    for (int b = 0; b < BB; ++b) {
        const long qo3 = (long)b * SDEC * 3 * D_;
        const long qo  = (long)b * SDEC * D_;
        gemm_bt<1, 0, 128><<<dim3(8, 8, NH), blk, 0, stream>>>(
            qkvH + qo3, qkvL + qo3, qkvH + qo3 + D_, qkvL + qo3 + D_,
            scores, nullptr, nullptr, SDEC, SDEC, DHD, 3 * D_, 3 * D_, SDEC,
            DHD, DHD, (long)SDEC * SDEC);
        softmax_split<<<dim3(NH * SDEC), blk, 0, stream>>>(scores, PH, PL, SDEC, 0.125f);
        pv_gemm<<<dim3(4, 8, NH), blk, 0, stream>>>(PH, PL,
            vTH + (long)b * NH * DHD * SDEC, vTL + (long)b * NH * DHD * SDEC, Opart, SDEC);
        pv_combine<<<dim3(1024), blk, 0, stream>>>(Opart, aoH + qo, aoL + qo);
    }
    gemm_bt<1, 0, 128><<<dim3(8, 32, 1), blk, 0, stream>>>(aoH, aoL,
        wtHall + (size_t)3 * D_ * D_, wtLall + (size_t)3 * D_ * D_,
        of, nullptr, nullptr, TDEC, D_, D_, D_, D_, D_, 0, 0, 0);
    add_rmsnorm<<<dim3(TDEC), blk, 0, stream>>>(of, dec, g, x1f, x1H, x1L);

    // ---- phase 2: cross-attention ----
    gemm_bt<1, 1, 128><<<dim3(8, 32, 1), blk, 0, stream>>>(x1H, x1L,
        wtHall + (size_t)4 * D_ * D_, wtLall + (size_t)4 * D_ * D_,
        nullptr, q2H, q2L, TDEC, D_, D_, D_, D_, D_, 0, 0, 0);
    gemm_bt<1, 1, 128><<<dim3(16, 16, 1), blk, 0, stream>>>(teH, teL,
        wtHall + (size_t)5 * D_ * D_, wtLall + (size_t)5 * D_ * D_,
        nullptr, kv2H, kv2L, TTXT, 2 * D_, D_, D_, D_, 2 * D_, 0, 0, 0);
    transpose_split_hl<<<dim3(2, 16, BB * NH), blk, 0, stream>>>(kv2H + D_, kv2L + D_,
        vTH, vTL, STXT, DHD, 2 * D_, (long)STXT * 2 * D_, DHD, NH, STXT, (long)DHD * STXT);

    for (int b = 0; b < BB; ++b) {
        const long qo  = (long)b * SDEC * D_;
        const long ko2 = (long)b * STXT * 2 * D_;
        gemm_bt<1, 0, 128><<<dim3(4, 8, NH), blk, 0, stream>>>(
            q2H + qo, q2L + qo, kv2H + ko2, kv2L + ko2,
            scores, nullptr, nullptr, SDEC, STXT, DHD, D_, 2 * D_, STXT,
            DHD, DHD, (long)SDEC * STXT);
        softmax_split<<<dim3(NH * SDEC), blk, 0, stream>>>(scores, PH, PL, STXT, 0.125f);
        pv_gemm<<<dim3(4, 8, NH), blk, 0, stream>>>(PH, PL,
            vTH + (long)b * NH * DHD * STXT, vTL + (long)b * NH * DHD * STXT, Opart, STXT);
        pv_combine<<<dim3(1024), blk, 0, stream>>>(Opart, aoH + qo, aoL + qo);
    }
    gemm_bt<1, 0, 128><<<dim3(8, 32, 1), blk, 0, stream>>>(aoH, aoL,
        wtHall + (size_t)7 * D_ * D_, wtLall + (size_t)7 * D_ * D_,
        of, nullptr, nullptr, TDEC, D_, D_, D_, D_, D_, 0, 0, 0);
    add_rmsnorm<<<dim3(TDEC), blk, 0, stream>>>(of, x1f, g, x2f, nullptr, nullptr);

    // ---- phase 3: router + expert bucketing + work lists ----
    hipMemsetAsync(counts, 0, 32, stream);
    hipMemsetAsync(desc1, 0xFF, (size_t)ND1 * 16, stream);
    hipMemsetAsync(desc2, 0xFF, (size_t)ND2 * 16, stream);
    router_topk<<<dim3(TDEC / 4), blk, 0, stream>>>(x2f, Wg, outw, outi, idx, tokw, counts, TDEC);
    scan_desc<<<1, 64, 0, stream>>>(counts, cursor, desc1, desc2);
    scatter_slots<<<dim3(TDEC / 256), blk, 0, stream>>>(idx, cursor, row_token, slot_of, TDEC);
    gather_bf16<<<dim3(NSLOT), blk, 0, stream>>>(x2f, row_token, Xg);

    // ---- phase 4: MoE FFN (persistent 128x128, 3-slot counted ring) ----
    transpose_split<<<dim3(DFF / 32, D_ / 32, NE), blk, 0, stream>>>(W1, W1T, nullptr,
        D_, DFF, DFF, (long)D_ * DFF, 0, 1, D_, (long)DFF * D_);
    transpose_split<<<dim3(D_ / 32, DFF / 32, NE), blk, 0, stream>>>(W2, W2T, nullptr,
        DFF, D_, D_, (long)D_ * DFF, 0, 1, DFF, (long)D_ * DFF);
    moe_gemm2<2><<<dim3(MOEGRID), blk, 0, stream>>>(Xg, D_, W1T, D_, (long)DFF * D_,
        nullptr, nullptr, Hb, DFF, desc1, ND1, 1024);
    moe_gemm2<0><<<dim3(MOEGRID), blk, 0, stream>>>(Hb, DFF, W2T, DFF, (long)D_ * DFF,
        Yseg, Ypart1, nullptr, D_, desc2, ND2, 2048);
    combine_rmsnorm<<<dim3(TDEC), blk, 0, stream>>>(Yseg, Ypart1, slot_of, tokw, x2f, g, outx);

    (void)in_sizes; (void)n_in; (void)out_size;
}

// Round 7
// 1380.455 us; speedup vs baseline: 1.5041x; 1.0146x over previous
//
#include <hip/hip_runtime.h>
#include <stdint.h>

#define D_    1024
#define BB    4
#define SDEC  1024
#define STXT  512
#define TDEC  4096
#define TTXT  2048
#define NH    16
#define DHD   64
#define NE    8
#define DFF   4096
#define NSLOT 8192
#define ND1   8192
#define ND2   4096
#define MOEGRID 512

using u16 = unsigned short;
typedef __attribute__((ext_vector_type(8))) short bf16x8;
typedef __attribute__((ext_vector_type(4))) float f32x4;

__device__ __forceinline__ float bf2f(u16 h) {
    union { unsigned int u; float f; } x; x.u = ((unsigned int)h) << 16; return x.f;
}
__device__ __forceinline__ u16 f2bf(float f) {
    union { float f; unsigned int u; } x; x.f = f;
    unsigned int lsb = (x.u >> 16) & 1u;
    return (u16)((x.u + 0x7fffu + lsb) >> 16);
}

// async global->LDS, 16B per lane, linear LDS dest (wave-uniform base + lane*16)
__device__ __forceinline__ void gld16(const u16* g, u16* l) {
    __builtin_amdgcn_global_load_lds((const __attribute__((address_space(1))) void*)g,
                                     (__attribute__((address_space(3))) void*)l,
                                     16, 0, 0);
}

constexpr int BM = 128, BK = 32;

// ---------------------------------------------------------------------------
// Generic tiled GEMM (128-tile, 2-barrier): C[M,N] = A[M,K] * BT[N,K]^T.
// SPLIT=1: 3-pass split emulation. EPI: 0=f32, 1=split store, 2=relu+bf16.
// ---------------------------------------------------------------------------
template<int SPLIT, int EPI, int BROWS>
__global__ __launch_bounds__(256) void gemm_bt(
    const u16* __restrict__ AH, const u16* __restrict__ AL,
    const u16* __restrict__ BH, const u16* __restrict__ BL,
    float* __restrict__ Cf, u16* __restrict__ CH, u16* __restrict__ CL,
    int M, int N, int K, int lda, int ldb, int ldc,
    long strA, long strB, long strC)
{
    constexpr int WM = (BROWS == 64) ? 2 : 4;
    constexpr int ASZ = BM * BK, BSZ = BROWS * BK;
    __shared__ u16 smem[(SPLIT ? 2 : 1) * (ASZ + BSZ)];
    u16* sAH = smem;
    u16* sBH = smem + ASZ;
    u16* sAL = SPLIT ? smem + ASZ + BSZ : nullptr;
    u16* sBL = SPLIT ? smem + 2 * ASZ + BSZ : nullptr;

    const int z = blockIdx.z;
    const long zA = (long)z * strA, zB = (long)z * strB, zC = (long)z * strC;

    const int tileM = blockIdx.y * BM, tileN = blockIdx.x * BROWS;
    const int t = threadIdx.x;
    const int sr = t >> 2;
    const int sc = (t & 3) << 3;
    const u16* pA = AH + zA + (long)(tileM + sr) * lda + sc;
    const u16* pB = BH + zB + (long)(tileN + sr) * ldb + sc;
    const u16* pAl = nullptr; const u16* pBl = nullptr;
    if constexpr (SPLIT) {
        pAl = AL + zA + (long)(tileM + sr) * lda + sc;
        pBl = BL + zB + (long)(tileN + sr) * ldb + sc;
    }
    const long hA = 64L * lda, hB = 64L * ldb;

    const int lane = t & 63;
    const int wv = t >> 6;
    const int wr = (BROWS == 64) ? (wv << 5) : ((wv >> 1) << 6);
    const int wc = (BROWS == 64) ? 0 : ((wv & 1) << 6);
    const int fr = lane & 15, kg = lane >> 4;

    f32x4 acc[WM][4];
    const f32x4 vzero = {0.f, 0.f, 0.f, 0.f};
#pragma unroll
    for (int m = 0; m < WM; ++m)
#pragma unroll
        for (int n = 0; n < 4; ++n) acc[m][n] = vzero;

    for (int k0 = 0; k0 < K; k0 += BK) {
        gld16(pA + k0,      sAH + t * 8);
        gld16(pA + k0 + hA, sAH + 2048 + t * 8);
        gld16(pB + k0,      sBH + t * 8);
        if constexpr (BROWS == 128) gld16(pB + k0 + hB, sBH + 2048 + t * 8);
        if constexpr (SPLIT) {
            gld16(pAl + k0,      sAL + t * 8);
            gld16(pAl + k0 + hA, sAL + 2048 + t * 8);
            gld16(pBl + k0,      sBL + t * 8);
            if constexpr (BROWS == 128) gld16(pBl + k0 + hB, sBL + 2048 + t * 8);
        }
        __syncthreads();

        bf16x8 fa[WM], fb[4], fal[WM], fbl[4];
#pragma unroll
        for (int m = 0; m < WM; ++m) {
            fa[m] = *(const bf16x8*)&sAH[(wr + m * 16 + fr) * BK + (kg << 3)];
            if constexpr (SPLIT) fal[m] = *(const bf16x8*)&sAL[(wr + m * 16 + fr) * BK + (kg << 3)];
        }
#pragma unroll
        for (int n = 0; n < 4; ++n) {
            fb[n] = *(const bf16x8*)&sBH[(wc + n * 16 + fr) * BK + (kg << 3)];
            if constexpr (SPLIT) fbl[n] = *(const bf16x8*)&sBL[(wc + n * 16 + fr) * BK + (kg << 3)];
        }
#pragma unroll
        for (int m = 0; m < WM; ++m)
#pragma unroll
            for (int n = 0; n < 4; ++n) {
                acc[m][n] = __builtin_amdgcn_mfma_f32_16x16x32_bf16(fa[m], fb[n], acc[m][n], 0, 0, 0);
                if constexpr (SPLIT) {
                    acc[m][n] = __builtin_amdgcn_mfma_f32_16x16x32_bf16(fa[m],  fbl[n], acc[m][n], 0, 0, 0);
                    acc[m][n] = __builtin_amdgcn_mfma_f32_16x16x32_bf16(fal[m], fb[n],  acc[m][n], 0, 0, 0);
                }
            }
        __syncthreads();
    }

#pragma unroll
    for (int m = 0; m < WM; ++m) {
        const int r0 = tileM + wr + m * 16 + (kg << 2);
#pragma unroll
        for (int n = 0; n < 4; ++n) {
            const int col = tileN + wc + n * 16 + fr;
            if (col >= N) continue;
#pragma unroll
            for (int i = 0; i < 4; ++i) {
                const int r = r0 + i;
                if (r >= M) continue;
                const float v = acc[m][n][i];
                const long off = zC + (long)r * ldc + col;
                if constexpr (EPI == 0) {
                    Cf[off] = v;
                } else if constexpr (EPI == 1) {
                    const u16 h = f2bf(v);
                    CH[off] = h;
                    CL[off] = f2bf(v - bf2f(h));
                } else {
                    CH[off] = f2bf(fmaxf(v, 0.f));
                }
            }
        }
    }
}

// ---------------------------------------------------------------------------
// PV GEMM with split-K=4. 3-pass split. grid (4, M/128, NH).
// Op layout [4][NH][1024][64] f32.
// ---------------------------------------------------------------------------
__global__ __launch_bounds__(256) void pv_gemm(
    const u16* __restrict__ PHp, const u16* __restrict__ PLp,
    const u16* __restrict__ VTH, const u16* __restrict__ VTL,
    float* __restrict__ Op, int Skv)
{
    __shared__ u16 smem[12288];
    u16* sAH = smem;
    u16* sAL = smem + 4096;
    u16* sBH = smem + 8192;
    u16* sBL = smem + 10240;

    const int kq = blockIdx.x;
    const int tileM = blockIdx.y * 128;
    const int z = blockIdx.z;
    const int kbase = kq * (Skv >> 2);
    const int nks = Skv >> 7;

    const int t = threadIdx.x;
    const int sr = t >> 2, sc = (t & 3) << 3;
    const u16* pA  = PHp + (long)z * 1024 * Skv + (long)(tileM + sr) * Skv + kbase + sc;
    const u16* pAl = PLp + (long)z * 1024 * Skv + (long)(tileM + sr) * Skv + kbase + sc;
    const u16* pB  = VTH + (long)z * 64 * Skv + (long)sr * Skv + kbase + sc;
    const u16* pBl = VTL + (long)z * 64 * Skv + (long)sr * Skv + kbase + sc;
    const long hA = 64L * Skv;

    const int lane = t & 63, wv = t >> 6;
    const int wr = wv << 5;
    const int fr = lane & 15, kg = lane >> 4;

    f32x4 acc[2][4];
    const f32x4 vzero = {0.f, 0.f, 0.f, 0.f};
#pragma unroll
    for (int m = 0; m < 2; ++m)
#pragma unroll
        for (int n = 0; n < 4; ++n) acc[m][n] = vzero;

    for (int ks = 0; ks < nks; ++ks) {
        const long k0 = (long)ks << 5;
        gld16(pA + k0,       sAH + t * 8);
        gld16(pA + k0 + hA,  sAH + 2048 + t * 8);
        gld16(pAl + k0,      sAL + t * 8);
        gld16(pAl + k0 + hA, sAL + 2048 + t * 8);
        gld16(pB + k0,       sBH + t * 8);
        gld16(pBl + k0,      sBL + t * 8);
        __syncthreads();
        bf16x8 fa[2], fb[4], fal[2], fbl[4];
#pragma unroll
        for (int m = 0; m < 2; ++m) {
            fa[m]  = *(const bf16x8*)&sAH[(wr + m * 16 + fr) * 32 + (kg << 3)];
            fal[m] = *(const bf16x8*)&sAL[(wr + m * 16 + fr) * 32 + (kg << 3)];
        }
#pragma unroll
        for (int n = 0; n < 4; ++n) {
            fb[n]  = *(const bf16x8*)&sBH[(n * 16 + fr) * 32 + (kg << 3)];
            fbl[n] = *(const bf16x8*)&sBL[(n * 16 + fr) * 32 + (kg << 3)];
        }
#pragma unroll
        for (int m = 0; m < 2; ++m)
#pragma unroll
            for (int n = 0; n < 4; ++n) {
                acc[m][n] = __builtin_amdgcn_mfma_f32_16x16x32_bf16(fa[m],  fb[n],  acc[m][n], 0, 0, 0);
                acc[m][n] = __builtin_amdgcn_mfma_f32_16x16x32_bf16(fa[m],  fbl[n], acc[m][n], 0, 0, 0);
                acc[m][n] = __builtin_amdgcn_mfma_f32_16x16x32_bf16(fal[m], fb[n],  acc[m][n], 0, 0, 0);
            }
        __syncthreads();
    }

    const long base = ((long)kq * NH + z) * 65536;
#pragma unroll
    for (int m = 0; m < 2; ++m) {
        const int r0 = tileM + wr + m * 16 + (kg << 2);
#pragma unroll
        for (int n = 0; n < 4; ++n) {
            const int col = n * 16 + fr;
#pragma unroll
            for (int i = 0; i < 4; ++i)
                Op[base + (long)(r0 + i) * 64 + col] = acc[m][n][i];
        }
    }
}

// ---------------------------------------------------------------------------
__global__ __launch_bounds__(256) void pv_combine(
    const float* __restrict__ Op, u16* __restrict__ aoH, u16* __restrict__ aoL)
{
    const long i = ((long)blockIdx.x * 256 + threadIdx.x) * 4;
    const int z = (int)(i >> 16);
    const int rem = (int)(i & 65535);
    const int r = rem >> 6, c = rem & 63;
    float4 v = *(const float4*)(Op + i);
    const float4 v1 = *(const float4*)(Op + 1048576 + i);
    const float4 v2 = *(const float4*)(Op + 2097152 + i);
    const float4 v3 = *(const float4*)(Op + 3145728 + i);
    v.x += v1.x + v2.x + v3.x;
    v.y += v1.y + v2.y + v3.y;
    v.z += v1.z + v2.z + v3.z;
    v.w += v1.w + v2.w + v3.w;
    const long dst = (long)r * D_ + z * 64 + c;
    u16 h0 = f2bf(v.x), h1 = f2bf(v.y), h2 = f2bf(v.z), h3 = f2bf(v.w);
    uint2 hh;
    hh.x = (unsigned)h0 | ((unsigned)h1 << 16);
    hh.y = (unsigned)h2 | ((unsigned)h3 << 16);
    *(uint2*)(aoH + dst) = hh;
    u16 l0 = f2bf(v.x - bf2f(h0)), l1 = f2bf(v.y - bf2f(h1));
    u16 l2 = f2bf(v.z - bf2f(h2)), l3 = f2bf(v.w - bf2f(h3));
    uint2 ll;
    ll.x = (unsigned)l0 | ((unsigned)l1 << 16);
    ll.y = (unsigned)l2 | ((unsigned)l3 << 16);
    *(uint2*)(aoL + dst) = ll;
}

// ---------------------------------------------------------------------------
// MoE persistent GEMM, 4-slot counted-vmcnt ring, prefetch distance 3.
//   - 256 threads = 4 waves (2x2), 128x128 tile, BK=32.
//   - LDS: 4 slots x 16KB = 64KB -> 2 blocks/CU; grid = 512 = exactly resident.
//   - At end of iter ks we need slot ks+1: it was staged at iter ks-2, giving
//     ~2 full iterations of latency cover (vs 1 for distance-2 -> was stalling).
//   - vmcnt(8): leave slots ks+2, ks+3 (8 loads) in flight across the barrier.
// ---------------------------------------------------------------------------
template<int EPI>
__global__ __launch_bounds__(256, 2) void moe_gemm2(
    const u16* __restrict__ Ag, int lda,
    const u16* __restrict__ BTbase, int ldb, long btStride,
    float* __restrict__ Cf0, float* __restrict__ Cf1, u16* __restrict__ CH, int ldc,
    const int4* __restrict__ desc, int ndesc, int Kiter)
{
    __shared__ u16 smem[32768];   // 64 KB: 4 slots x [A 4096 | B 4096] elems
    const int t = threadIdx.x;
    const int lane = t & 63, wv = t >> 6;
    const int wr = (wv >> 1) << 6, wc = (wv & 1) << 6;
    const int fr = lane & 15, kg = lane >> 4;
    const int nks = Kiter >> 5;   // >= 4

    const int rS = t >> 2;
    const int cS = ((t & 3) ^ ((t >> 3) & 3)) << 3;

    int ldsA[4], ldsB[4];
#pragma unroll
    for (int m = 0; m < 4; ++m) {
        const int ra = wr + m * 16 + fr;
        ldsA[m] = ra * 32 + ((kg ^ ((ra >> 1) & 3)) << 3);
        const int rb = wc + m * 16 + fr;
        ldsB[m] = rb * 32 + ((kg ^ ((rb >> 1) & 3)) << 3);
    }

    for (int p = blockIdx.x; p < ndesc; p += MOEGRID) {
        const int4 d = desc[p];
        if (d.x < 0) continue;
        const int rowbase = d.x, colbase = d.y & 0xFFFF, e = d.y >> 16;
        const int kbase = d.z, s1 = d.w;
        const u16* paS = Ag + (long)(rowbase + rS) * lda + kbase + cS;
        const u16* pbS = BTbase + (long)e * btStride + (long)(colbase + rS) * ldb + kbase + cS;
        const long hA = 64L * lda, hB = 64L * ldb;

        f32x4 acc[4][4];
        const f32x4 vzero = {0.f, 0.f, 0.f, 0.f};
#pragma unroll
        for (int m = 0; m < 4; ++m)
#pragma unroll
            for (int n = 0; n < 4; ++n) acc[m][n] = vzero;

#define STG(ks) { const int s_ = (ks) & 3; const long k0_ = (long)(ks) << 5; \
        u16* b_ = smem + s_ * 8192; \
        gld16(paS + k0_,      b_ + t * 8); \
        gld16(paS + k0_ + hA, b_ + 2048 + t * 8); \
        gld16(pbS + k0_,      b_ + 4096 + t * 8); \
        gld16(pbS + k0_ + hB, b_ + 6144 + t * 8); }

        STG(0); STG(1); STG(2);
        asm volatile("s_waitcnt vmcnt(8)" ::: "memory");   // slot 0 resident
        __builtin_amdgcn_s_barrier();
        __builtin_amdgcn_sched_barrier(0);

        for (int ks = 0; ks < nks; ++ks) {
            if (ks + 3 < nks) STG(ks + 3);
            const u16* sA = smem + (ks & 3) * 8192;
            const u16* sB = sA + 4096;
            bf16x8 fa[4], fb[4];
#pragma unroll
            for (int m = 0; m < 4; ++m) fa[m] = *(const bf16x8*)&sA[ldsA[m]];
#pragma unroll
            for (int n = 0; n < 4; ++n) fb[n] = *(const bf16x8*)&sB[ldsB[n]];
            __builtin_amdgcn_s_setprio(1);
#pragma unroll
            for (int m = 0; m < 4; ++m)
#pragma unroll
                for (int n = 0; n < 4; ++n)
                    acc[m][n] = __builtin_amdgcn_mfma_f32_16x16x32_bf16(fa[m], fb[n], acc[m][n], 0, 0, 0);
            __builtin_amdgcn_s_setprio(0);
            // need slot ks+1 resident after this wait; slots ks+2,ks+3 may stay in flight
            if (ks + 3 < nks)      { asm volatile("s_waitcnt vmcnt(8)" ::: "memory"); }
            else if (ks + 2 < nks) { asm volatile("s_waitcnt vmcnt(4)" ::: "memory"); }
            else                   { asm volatile("s_waitcnt vmcnt(0)" ::: "memory"); }
            __builtin_amdgcn_s_barrier();
            __builtin_amdgcn_sched_barrier(0);
        }
#undef STG

        float* __restrict__ C = (EPI == 0) ? ((kbase == 0) ? Cf0 : Cf1) : nullptr;
#pragma unroll
        for (int m = 0; m < 4; ++m) {
            const int r0 = rowbase + wr + m * 16 + (kg << 2);
#pragma unroll
            for (int n = 0; n < 4; ++n) {
                const int col = colbase + wc + n * 16 + fr;
#pragma unroll
                for (int i = 0; i < 4; ++i) {
                    const int r = r0 + i;
                    if (r >= s1) continue;
                    const float v = acc[m][n][i];
                    const long off = (long)r * ldc + col;
                    if constexpr (EPI == 0) C[off] = v;
                    else                    CH[off] = f2bf(fmaxf(v, 0.f));
                }
            }
        }
    }
}

// ---------------------------------------------------------------------------
__global__ __launch_bounds__(256) void split2k(const float* __restrict__ in,
                                               u16* __restrict__ oh, u16* __restrict__ ol, long n)
{
    long i = ((long)blockIdx.x * 256 + threadIdx.x) * 4;
    if (i >= n) return;
    float4 v = *(const float4*)(in + i);
    u16 h0 = f2bf(v.x), h1 = f2bf(v.y), h2 = f2bf(v.z), h3 = f2bf(v.w);
    uint2 oo;
    oo.x = (unsigned)h0 | ((unsigned)h1 << 16);
    oo.y = (unsigned)h2 | ((unsigned)h3 << 16);
    *(uint2*)(oh + i) = oo;
    if (ol) {
        u16 l0 = f2bf(v.x - bf2f(h0)), l1 = f2bf(v.y - bf2f(h1));
        u16 l2 = f2bf(v.z - bf2f(h2)), l3 = f2bf(v.w - bf2f(h3));
        uint2 ll;
        ll.x = (unsigned)l0 | ((unsigned)l1 << 16);
        ll.y = (unsigned)l2 | ((unsigned)l3 << 16);
        *(uint2*)(ol + i) = ll;
    }
}

// ---------------------------------------------------------------------------
// Batched square weight transpose+split: z picks one of 8 [1024][1024] f32 inputs.
// ---------------------------------------------------------------------------
struct Ptr8 { const float* p[8]; };
__global__ __launch_bounds__(256) void transpose_split_w(
    Ptr8 in, u16* __restrict__ oh, u16* __restrict__ ol)
{
    __shared__ float tile[32][33];
    const int z = blockIdx.z;
    const float* ip = in.p[z];
    u16* ohp = oh + (long)z * D_ * D_;
    u16* olp = ol + (long)z * D_ * D_;
    const int c0 = blockIdx.x * 32, r0 = blockIdx.y * 32;
    const int tx = threadIdx.x & 31, ty = threadIdx.x >> 5;
    for (int i = ty; i < 32; i += 8)
        tile[i][tx] = ip[(long)(r0 + i) * D_ + c0 + tx];
    __syncthreads();
    for (int i = ty; i < 32; i += 8) {
        int oc = c0 + i, orr = r0 + tx;
        float v = tile[tx][i];
        u16 h = f2bf(v);
        ohp[(long)oc * D_ + orr] = h;
        olp[(long)oc * D_ + orr] = f2bf(v - bf2f(h));
    }
}

// ---------------------------------------------------------------------------
__global__ __launch_bounds__(256) void transpose_split(
    const float* __restrict__ in, u16* __restrict__ oh, u16* __restrict__ ol,
    int R, int C, int ild, long ibs1, long ibs2, int nb2, int old_, long obs)
{
    __shared__ float tile[32][33];
    const int z = blockIdx.z;
    const float* ip = in + (long)(z / nb2) * ibs1 + (long)(z % nb2) * ibs2;
    u16* ohp = oh + (long)z * obs;
    u16* olp = ol ? ol + (long)z * obs : nullptr;
    const int c0 = blockIdx.x * 32, r0 = blockIdx.y * 32;
    const int tx = threadIdx.x & 31, ty = threadIdx.x >> 5;
    for (int i = ty; i < 32; i += 8) {
        int r = r0 + i, c = c0 + tx;
        tile[i][tx] = (r < R && c < C) ? ip[(long)r * ild + c] : 0.f;
    }
    __syncthreads();
    for (int i = ty; i < 32; i += 8) {
        int oc = c0 + i, orr = r0 + tx;
        if (oc < C && orr < R) {
            float v = tile[tx][i];
            u16 h = f2bf(v);
            ohp[(long)oc * old_ + orr] = h;
            if (olp) olp[(long)oc * old_ + orr] = f2bf(v - bf2f(h));
        }
    }
}

// ---------------------------------------------------------------------------
__global__ __launch_bounds__(256) void transpose_split_hl(
    const u16* __restrict__ inH, const u16* __restrict__ inL,
    u16* __restrict__ oh, u16* __restrict__ ol,
    int R, int C, int ild, long ibs1, long ibs2, int nb2, int old_, long obs)
{
    __shared__ float tile[32][33];
    const int z = blockIdx.z;
    const long base = (long)(z / nb2) * ibs1 + (long)(z % nb2) * ibs2;
    u16* ohp = oh + (long)z * obs;
    u16* olp = ol + (long)z * obs;
    const int c0 = blockIdx.x * 32, r0 = blockIdx.y * 32;
    const int tx = threadIdx.x & 31, ty = threadIdx.x >> 5;
    for (int i = ty; i < 32; i += 8) {
        int r = r0 + i, c = c0 + tx;
        float v = 0.f;
        if (r < R && c < C) {
            const long o = base + (long)r * ild + c;
            v = bf2f(inH[o]) + bf2f(inL[o]);
        }
        tile[i][tx] = v;
    }
    __syncthreads();
    for (int i = ty; i < 32; i += 8) {
        int oc = c0 + i, orr = r0 + tx;
        if (oc < C && orr < R) {
            float v = tile[tx][i];
            u16 h = f2bf(v);
            ohp[(long)oc * old_ + orr] = h;
            olp[(long)oc * old_ + orr] = f2bf(v - bf2f(h));
        }
    }
}

// ---------------------------------------------------------------------------
__global__ __launch_bounds__(256) void softmax_split(
    const float* __restrict__ s, u16* __restrict__ ph, u16* __restrict__ pl,
    int cols, float scale)
{
    const float* p = s + (long)blockIdx.x * cols;
    u16* php = ph + (long)blockIdx.x * cols;
    u16* plp = pl + (long)blockIdx.x * cols;
    const int t = threadIdx.x;
    float v[4];
    int vpt;
    if (cols == 1024) {
        vpt = 4;
        float4 x = ((const float4*)p)[t];
        v[0] = x.x * scale; v[1] = x.y * scale; v[2] = x.z * scale; v[3] = x.w * scale;
    } else {
        vpt = 2;
        float2 x = ((const float2*)p)[t];
        v[0] = x.x * scale; v[1] = x.y * scale; v[2] = -3.4e38f; v[3] = -3.4e38f;
    }
    float mx = fmaxf(fmaxf(v[0], v[1]), fmaxf(v[2], v[3]));
#pragma unroll
    for (int o = 32; o; o >>= 1) mx = fmaxf(mx, __shfl_xor(mx, o));
    __shared__ float sm[4];
    const int wv = t >> 6, ln = t & 63;
    if (ln == 0) sm[wv] = mx;
    __syncthreads();
    mx = fmaxf(fmaxf(sm[0], sm[1]), fmaxf(sm[2], sm[3]));
    float sum = 0.f;
    for (int i = 0; i < vpt; ++i) { v[i] = expf(v[i] - mx); sum += v[i]; }
#pragma unroll
    for (int o = 32; o; o >>= 1) sum += __shfl_xor(sum, o);
    __shared__ float ss[4];
    if (ln == 0) ss[wv] = sum;
    __syncthreads();
    sum = ss[0] + ss[1] + ss[2] + ss[3];
    const float inv = 1.f / sum;
    if (cols == 1024) {
        float q0 = v[0] * inv, q1 = v[1] * inv, q2 = v[2] * inv, q3 = v[3] * inv;
        u16 h0 = f2bf(q0), h1 = f2bf(q1), h2 = f2bf(q2), h3 = f2bf(q3);
        uint2 hh; hh.x = (unsigned)h0 | ((unsigned)h1 << 16); hh.y = (unsigned)h2 | ((unsigned)h3 << 16);
        ((uint2*)php)[t] = hh;
        u16 l0 = f2bf(q0 - bf2f(h0)), l1 = f2bf(q1 - bf2f(h1));
        u16 l2 = f2bf(q2 - bf2f(h2)), l3 = f2bf(q3 - bf2f(h3));
        uint2 ll; ll.x = (unsigned)l0 | ((unsigned)l1 << 16); ll.y = (unsigned)l2 | ((unsigned)l3 << 16);
        ((uint2*)plp)[t] = ll;
    } else {
        float q0 = v[0] * inv, q1 = v[1] * inv;
        u16 h0 = f2bf(q0), h1 = f2bf(q1);
        ((unsigned*)php)[t] = (unsigned)h0 | ((unsigned)h1 << 16);
        u16 l0 = f2bf(q0 - bf2f(h0)), l1 = f2bf(q1 - bf2f(h1));
        ((unsigned*)plp)[t] = (unsigned)l0 | ((unsigned)l1 << 16);
    }
}

// ---------------------------------------------------------------------------
__global__ __launch_bounds__(256) void add_rmsnorm(
    const float* __restrict__ a, const float* __restrict__ b, const float* __restrict__ g,
    float* __restrict__ xo, u16* __restrict__ xh, u16* __restrict__ xl)
{
    const long row = blockIdx.x;
    const int t = threadIdx.x;
    const float* pa = a + row * D_;
    const float* pb = b + row * D_;
    float v[4]; double ssq = 0.0;
#pragma unroll
    for (int i = 0; i < 4; ++i) {
        int c = t + (i << 8);
        v[i] = pa[c] + pb[c];
        ssq += (double)v[i] * v[i];
    }
#pragma unroll
    for (int o = 32; o; o >>= 1) ssq += __shfl_xor(ssq, o);
    __shared__ double sd[4];
    if ((t & 63) == 0) sd[t >> 6] = ssq;
    __syncthreads();
    ssq = sd[0] + sd[1] + sd[2] + sd[3];
    const float rs = (float)(1.0 / sqrt(ssq * (1.0 / 1024.0) + 1e-6));
#pragma unroll
    for (int i = 0; i < 4; ++i) {
        int c = t + (i << 8);
        float o = v[i] * rs * g[c];
        xo[row * D_ + c] = o;
        if (xh) {
            u16 h = f2bf(o);
            xh[row * D_ + c] = h;
            if (xl) xl[row * D_ + c] = f2bf(o - bf2f(h));
        }
    }
}

// ---------------------------------------------------------------------------
__global__ __launch_bounds__(256) void router_topk(
    const float* __restrict__ x2, const float* __restrict__ Wg,
    float* __restrict__ outw, float* __restrict__ outi,
    int* __restrict__ idx, float* __restrict__ tokw, int* __restrict__ counts, int T)
{
    const int wid = (int)((blockIdx.x * 256 + threadIdx.x) >> 6);
    const int lane = threadIdx.x & 63;
    if (wid >= T) return;
    float acc[NE];
#pragma unroll
    for (int e = 0; e < NE; ++e) acc[e] = 0.f;
    const float* xr = x2 + (long)wid * D_;
    for (int i = 0; i < 16; ++i) {
        float xv = xr[i * 64 + lane];
        const float* wr = Wg + (long)(i * 64 + lane) * NE;
#pragma unroll
        for (int e = 0; e < NE; ++e) acc[e] += xv * wr[e];
    }
#pragma unroll
    for (int e = 0; e < NE; ++e)
#pragma unroll
        for (int o = 32; o; o >>= 1) acc[e] += __shfl_xor(acc[e], o);
    if (lane == 0) {
        float m = acc[0];
#pragma unroll
        for (int e = 1; e < NE; ++e) m = fmaxf(m, acc[e]);
        float p[NE], s = 0.f;
#pragma unroll
        for (int e = 0; e < NE; ++e) { p[e] = expf(acc[e] - m); s += p[e]; }
        const float invs = 1.f / s;
#pragma unroll
        for (int e = 0; e < NE; ++e) p[e] *= invs;
        int e0 = 0;
#pragma unroll
        for (int e = 1; e < NE; ++e) if (p[e] > p[e0]) e0 = e;
        int e1 = (e0 == 0) ? 1 : 0;
#pragma unroll
        for (int e = 0; e < NE; ++e) if (e != e0 && e != e1 && p[e] > p[e1]) e1 = e;
        float w0 = p[e0], w1 = p[e1];
        const float sw = 1.f / (w0 + w1);
        w0 *= sw; w1 *= sw;
        outw[2 * wid] = w0;      outw[2 * wid + 1] = w1;
        outi[2 * wid] = (float)e0; outi[2 * wid + 1] = (float)e1;
        idx[2 * wid] = e0;       idx[2 * wid + 1] = e1;
        tokw[2 * wid] = w0;      tokw[2 * wid + 1] = w1;
        atomicAdd(&counts[e0], 1);
        atomicAdd(&counts[e1], 1);
    }
}

// ---------------------------------------------------------------------------
__global__ void scan_desc(const int* __restrict__ counts, int* __restrict__ cursor,
                          int4* __restrict__ d1, int4* __restrict__ d2)
{
    __shared__ int sseg[NE + 1];
    if (threadIdx.x == 0) {
        int a = 0;
        for (int e = 0; e < NE; ++e) { sseg[e] = a; cursor[e] = a; a += counts[e]; }
        sseg[NE] = a;
    }
    __syncthreads();
    const int e = threadIdx.x;
    if (e < NE) {
        const int s0 = sseg[e], s1 = sseg[e + 1];
        const int nyt = (s1 - s0 + 127) >> 7;
        for (int xt = 0; xt < 32; ++xt)
            for (int yt = 0; yt < nyt; ++yt)
                d1[e + 8 * (xt * nyt + yt)] =
                    make_int4(s0 + yt * 128, (xt * 128) | (e << 16), 0, s1);
        for (int kh = 0; kh < 2; ++kh)
            for (int xt = 0; xt < 8; ++xt)
                for (int yt = 0; yt < nyt; ++yt)
                    d2[e + 8 * ((kh * 8 + xt) * nyt + yt)] =
                        make_int4(s0 + yt * 128, (xt * 128) | (e << 16), kh * 2048, s1);
    }
}

__global__ __launch_bounds__(256) void scatter_slots(
    const int* __restrict__ idx, int* __restrict__ cursor,
    int* __restrict__ row_token, int* __restrict__ slot_of, int T)
{
    const int t = blockIdx.x * 256 + threadIdx.x;
    if (t >= T) return;
#pragma unroll
    for (int k = 0; k < 2; ++k) {
        const int e = idx[2 * t + k];
        const int pos = atomicAdd(&cursor[e], 1);
        row_token[pos] = t;
        slot_of[2 * t + k] = pos;
    }
}

__global__ __launch_bounds__(256) void gather_bf16(
    const float* __restrict__ x2, const int* __restrict__ row_token, u16* __restrict__ Xg)
{
    const int r = blockIdx.x;
    const int t = threadIdx.x;
    const float* src = x2 + (long)row_token[r] * D_ + t * 4;
    float4 v = *(const float4*)src;
    uint2 oo;
    oo.x = (unsigned)f2bf(v.x) | ((unsigned)f2bf(v.y) << 16);
    oo.y = (unsigned)f2bf(v.z) | ((unsigned)f2bf(v.w) << 16);
    *(uint2*)(Xg + (long)r * D_ + t * 4) = oo;
}

// ---------------------------------------------------------------------------
__global__ __launch_bounds__(256) void combine_rmsnorm(
    const float* __restrict__ Y0, const float* __restrict__ Y1,
    const int* __restrict__ slot_of, const float* __restrict__ tokw,
    const float* __restrict__ x2, const float* __restrict__ g, float* __restrict__ out)
{
    const long tr = blockIdx.x;
    const int t = threadIdx.x;
    const int s0 = slot_of[2 * tr], s1 = slot_of[2 * tr + 1];
    const float w0 = tokw[2 * tr], w1 = tokw[2 * tr + 1];
    const float* ya0 = Y0 + (long)s0 * D_;
    const float* yb0 = Y1 + (long)s0 * D_;
    const float* ya1 = Y0 + (long)s1 * D_;
    const float* yb1 = Y1 + (long)s1 * D_;
    const float* xr = x2 + tr * D_;
    float v[4]; double ssq = 0.0;
#pragma unroll
    for (int i = 0; i < 4; ++i) {
        int c = t + (i << 8);
        v[i] = w0 * (ya0[c] + yb0[c]) + w1 * (ya1[c] + yb1[c]) + xr[c];
        ssq += (double)v[i] * v[i];
    }
#pragma unroll
    for (int o = 32; o; o >>= 1) ssq += __shfl_xor(ssq, o);
    __shared__ double sd[4];
    if ((t & 63) == 0) sd[t >> 6] = ssq;
    __syncthreads();
    ssq = sd[0] + sd[1] + sd[2] + sd[3];
    const float rs = (float)(1.0 / sqrt(ssq * (1.0 / 1024.0) + 1e-6));
#pragma unroll
    for (int i = 0; i < 4; ++i) {
        int c = t + (i << 8);
        out[tr * D_ + c] = v[i] * rs * g[c];
    }
}

__global__ void sentinel(float* o) { o[0] = 12345.0f; }

// ---------------------------------------------------------------------------
extern "C" void kernel_launch(void* const* d_in, const int* in_sizes, int n_in,
                              void* d_out, int out_size, void* d_ws, size_t ws_size,
                              hipStream_t stream)
{
    const float* dec = (const float*)d_in[0];
    const float* te  = (const float*)d_in[1];
    const float* g  = (const float*)d_in[10];
    const float* Wg = (const float*)d_in[11];
    const float* W1 = (const float*)d_in[12];
    const float* W2 = (const float*)d_in[13];
    float* outw = (float*)d_out;
    float* outi = outw + 2 * TDEC;
    float* outx = outw + 4 * TDEC;

    char* ws = (char*)d_ws;
    size_t off = 0;
    auto A = [&](size_t bytes) -> char* {
        char* p = ws + off;
        off += (bytes + 255) & ~(size_t)255;
        return p;
    };

    // ---- persistent region ----
    u16* decH = (u16*)A((size_t)TDEC * D_ * 2);
    u16* decL = (u16*)A((size_t)TDEC * D_ * 2);
    u16* teH  = (u16*)A((size_t)TTXT * D_ * 2);
    u16* teL  = (u16*)A((size_t)TTXT * D_ * 2);
    u16* wtHall = (u16*)A((size_t)8 * D_ * D_ * 2);
    u16* wtLall = (u16*)A((size_t)8 * D_ * D_ * 2);
    float* x1f = (float*)A((size_t)TDEC * D_ * 4);
    float* x2f = (float*)A((size_t)TDEC * D_ * 4);
    float* tokw = (float*)A(NSLOT * 4);
    int* idx    = (int*)A(NSLOT * 4);
    int* counts = (int*)A(256);
    int* cursor = (int*)A(256);
    int* row_token = (int*)A(NSLOT * 4);
    int* slot_of   = (int*)A(NSLOT * 4);
    int4* desc1 = (int4*)A((size_t)ND1 * 16);
    int4* desc2 = (int4*)A((size_t)ND2 * 16);

    // ---- shared region R: attention view ----
    const size_t Rbase = off;
    float* scores = (float*)A((size_t)NH * SDEC * SDEC * 4);
    u16* PH = (u16*)A((size_t)NH * SDEC * SDEC * 2);
    u16* PL = (u16*)A((size_t)NH * SDEC * SDEC * 2);
    u16* qkvH = (u16*)A((size_t)TDEC * 3 * D_ * 2);
    u16* qkvL = (u16*)A((size_t)TDEC * 3 * D_ * 2);
    u16* q2H  = (u16*)A((size_t)TDEC * D_ * 2);
    u16* q2L  = (u16*)A((size_t)TDEC * D_ * 2);
    u16* kv2H = (u16*)A((size_t)TTXT * 2 * D_ * 2);
    u16* kv2L = (u16*)A((size_t)TTXT * 2 * D_ * 2);
    u16* vTH = (u16*)A((size_t)TDEC * D_ * 2);
    u16* vTL = (u16*)A((size_t)TDEC * D_ * 2);
    u16* aoH = (u16*)A((size_t)TDEC * D_ * 2);
    u16* aoL = (u16*)A((size_t)TDEC * D_ * 2);
    u16* x1H = (u16*)A((size_t)TDEC * D_ * 2);
    u16* x1L = (u16*)A((size_t)TDEC * D_ * 2);
    float* of = (float*)A((size_t)TDEC * D_ * 4);
    float* Opart = (float*)A((size_t)4 * NH * SDEC * DHD * 4);
    const size_t attnEnd = off;

    // ---- shared region R: MoE view (overlays attention view) ----
    off = Rbase;
    u16* W1T  = (u16*)A((size_t)NE * DFF * D_ * 2);
    u16* W2T  = (u16*)A((size_t)NE * D_ * DFF * 2);
    u16* Xg   = (u16*)A((size_t)(NSLOT + 256) * D_ * 2);
    u16* Hb   = (u16*)A((size_t)(NSLOT + 256) * DFF * 2);
    float* Yseg = (float*)A((size_t)NSLOT * D_ * 4);
    float* Ypart1 = (float*)W1T;
    const size_t needed = (off > attnEnd ? off : attnEnd);

    if (ws_size < needed) {
        sentinel<<<1, 1, 0, stream>>>(outw);
        return;
    }

    const dim3 blk(256);

    // ---- phase 0: input splits + batched attention weight transposes ----
    split2k<<<dim3((TDEC * D_) / 1024), blk, 0, stream>>>(dec, decH, decL, (long)TDEC * D_);
    split2k<<<dim3((TTXT * D_) / 1024), blk, 0, stream>>>(te, teH, teL, (long)TTXT * D_);
    Ptr8 wp;
    for (int i = 0; i < 8; ++i) wp.p[i] = (const float*)d_in[2 + i];
    transpose_split_w<<<dim3(32, 32, 8), blk, 0, stream>>>(wp, wtHall, wtLall);

    // ---- phase 1: self-attention ----
    gemm_bt<1, 1, 128><<<dim3(24, 32, 1), blk, 0, stream>>>(decH, decL, wtHall, wtLall,
        nullptr, qkvH, qkvL, TDEC, 3 * D_, D_, D_, D_, 3 * D_, 0, 0, 0);
    transpose_split_hl<<<dim3(2, 32, BB * NH), blk, 0, stream>>>(qkvH + 2 * D_, qkvL + 2 * D_,
        vTH, vTL, SDEC, DHD, 3 * D_, (long)SDEC * 3 * D_, DHD, NH, SDEC, (long)DHD * SDEC);

    for (int b = 0; b < BB; ++b) {
        const long qo3 = (long)b * SDEC * 3 * D_;
        const long qo  = (long)b * SDEC * D_;
        gemm_bt<1, 0, 128><<<dim3(8, 8, NH), blk, 0, stream>>>(
            qkvH + qo3, qkvL + qo3, qkvH + qo3 + D_, qkvL + qo3 + D_,
            scores, nullptr, nullptr, SDEC, SDEC, DHD, 3 * D_, 3 * D_, SDEC,
            DHD, DHD, (long)SDEC * SDEC);
        softmax_split<<<dim3(NH * SDEC), blk, 0, stream>>>(scores, PH, PL, SDEC, 0.125f);
        pv_gemm<<<dim3(4, 8, NH), blk, 0, stream>>>(PH, PL,
            vTH + (long)b * NH * DHD * SDEC, vTL + (long)b * NH * DHD * SDEC, Opart, SDEC);
        pv_combine<<<dim3(1024), blk, 0, stream>>>(Opart, aoH + qo, aoL + qo);
    }
    gemm_bt<1, 0, 128><<<dim3(8, 32, 1), blk, 0, stream>>>(aoH, aoL,
        wtHall + (size_t)3 * D_ * D_, wtLall + (size_t)3 * D_ * D_,
        of, nullptr, nullptr, TDEC, D_, D_, D_, D_, D_, 0, 0, 0);
    add_rmsnorm<<<dim3(TDEC), blk, 0, stream>>>(of, dec, g, x1f, x1H, x1L);

    // ---- phase 2: cross-attention ----
    gemm_bt<1, 1, 128><<<dim3(8, 32, 1), blk, 0, stream>>>(x1H, x1L,
        wtHall + (size_t)4 * D_ * D_, wtLall + (size_t)4 * D_ * D_,
        nullptr, q2H, q2L, TDEC, D_, D_, D_, D_, D_, 0, 0, 0);
    gemm_bt<1, 1, 128><<<dim3(16, 16, 1), blk, 0, stream>>>(teH, teL,
        wtHall + (size_t)5 * D_ * D_, wtLall + (size_t)5 * D_ * D_,
        nullptr, kv2H, kv2L, TTXT, 2 * D_, D_, D_, D_, 2 * D_, 0, 0, 0);
    transpose_split_hl<<<dim3(2, 16, BB * NH), blk, 0, stream>>>(kv2H + D_, kv2L + D_,
        vTH, vTL, STXT, DHD, 2 * D_, (long)STXT * 2 * D_, DHD, NH, STXT, (long)DHD * STXT);

    for (int b = 0; b < BB; ++b) {
        const long qo  = (long)b * SDEC * D_;
        const long ko2 = (long)b * STXT * 2 * D_;
        gemm_bt<1, 0, 128><<<dim3(4, 8, NH), blk, 0, stream>>>(
            q2H + qo, q2L + qo, kv2H + ko2, kv2L + ko2,
            scores, nullptr, nullptr, SDEC, STXT, DHD, D_, 2 * D_, STXT,
            DHD, DHD, (long)SDEC * STXT);
        softmax_split<<<dim3(NH * SDEC), blk, 0, stream>>>(scores, PH, PL, STXT, 0.125f);
        pv_gemm<<<dim3(4, 8, NH), blk, 0, stream>>>(PH, PL,
            vTH + (long)b * NH * DHD * STXT, vTL + (long)b * NH * DHD * STXT, Opart, STXT);
        pv_combine<<<dim3(1024), blk, 0, stream>>>(Opart, aoH + qo, aoL + qo);
    }
    gemm_bt<1, 0, 128><<<dim3(8, 32, 1), blk, 0, stream>>>(aoH, aoL,
        wtHall + (size_t)7 * D_ * D_, wtLall + (size_t)7 * D_ * D_,
        of, nullptr, nullptr, TDEC, D_, D_, D_, D_, D_, 0, 0, 0);
    add_rmsnorm<<<dim3(TDEC), blk, 0, stream>>>(of, x1f, g, x2f, nullptr, nullptr);

    // ---- phase 3: router + expert bucketing + work lists ----
    hipMemsetAsync(counts, 0, 32, stream);
    hipMemsetAsync(desc1, 0xFF, (size_t)ND1 * 16, stream);
    hipMemsetAsync(desc2, 0xFF, (size_t)ND2 * 16, stream);
    router_topk<<<dim3(TDEC / 4), blk, 0, stream>>>(x2f, Wg, outw, outi, idx, tokw, counts, TDEC);
    scan_desc<<<1, 64, 0, stream>>>(counts, cursor, desc1, desc2);
    scatter_slots<<<dim3(TDEC / 256), blk, 0, stream>>>(idx, cursor, row_token, slot_of, TDEC);
    gather_bf16<<<dim3(NSLOT), blk, 0, stream>>>(x2f, row_token, Xg);

    // ---- phase 4: MoE FFN (persistent 128x128, 4-slot distance-3 ring) ----
    transpose_split<<<dim3(DFF / 32, D_ / 32, NE), blk, 0, stream>>>(W1, W1T, nullptr,
        D_, DFF, DFF, (long)D_ * DFF, 0, 1, D_, (long)DFF * D_);
    transpose_split<<<dim3(D_ / 32, DFF / 32, NE), blk, 0, stream>>>(W2, W2T, nullptr,
        DFF, D_, D_, (long)D_ * DFF, 0, 1, DFF, (long)D_ * DFF);
    moe_gemm2<2><<<dim3(MOEGRID), blk, 0, stream>>>(Xg, D_, W1T, D_, (long)DFF * D_,
        nullptr, nullptr, Hb, DFF, desc1, ND1, 1024);
    moe_gemm2<0><<<dim3(MOEGRID), blk, 0, stream>>>(Hb, DFF, W2T, DFF, (long)D_ * DFF,
        Yseg, Ypart1, nullptr, D_, desc2, ND2, 2048);
    combine_rmsnorm<<<dim3(TDEC), blk, 0, stream>>>(Yseg, Ypart1, slot_of, tokw, x2f, g, outx);

    (void)in_sizes; (void)n_in; (void)out_size;
}